// Round 19
// baseline (1948.576 us; speedup 1.0000x reference)
//
#include <hip/hip_runtime.h>
#include <hip/hip_fp16.h>

// ALIGNN forward on MI355X. Round 19: EU linearity fold.
// cat(edge,edge,laggr)@W1 == edge@(W1top+W1mid) + laggr@W1bot -> fold the
// weight sum at conversion time. EU phase1 K: 384->256 (-33% MFMA), LDS
// 42->34KB (4 blocks/CU). Round-18 baseline 1908us (k_eu 117us x4 top).

#define NN 2048      // nodes
#define NE 131072    // edges
#define NL 524288    // line edges
#define DM 128       // feature dim

typedef unsigned short u16;
typedef unsigned int uint;
typedef __attribute__((ext_vector_type(8))) _Float16 f16x8;
typedef __attribute__((ext_vector_type(4))) float f32x4;

__device__ __forceinline__ float h2f(u16 u){ return __half2float(__ushort_as_half(u)); }
__device__ __forceinline__ u16 f2h(float f){ return __half_as_ushort(__float2half(f)); } // RNE
__device__ __forceinline__ uint pk2h(float a, float b){   // packed f32x2 -> f16x2 (RTZ)
  union { decltype(__builtin_amdgcn_cvt_pkrtz(0.f,0.f)) h2; uint u; } cv;
  cv.h2 = __builtin_amdgcn_cvt_pkrtz(a, b);
  return cv.u;
}
__device__ __forceinline__ float siluf(float x){ return x/(1.f+__expf(-x)); }
__device__ __forceinline__ float4 ld4(const float* p){ return *(const float4*)p; }
__device__ __forceinline__ void fma44(float (&a)[4], float4 x, float4 w0, float4 w1, float4 w2, float4 w3){
  a[0] += x.x*w0.x + x.y*w1.x + x.z*w2.x + x.w*w3.x;
  a[1] += x.x*w0.y + x.y*w1.y + x.z*w2.y + x.w*w3.y;
  a[2] += x.x*w0.z + x.y*w1.z + x.z*w2.z + x.w*w3.z;
  a[3] += x.x*w0.w + x.y*w1.w + x.z*w2.w + x.w*w3.w;
}

// ---------------- util ----------------

__global__ void k_zero2(int* __restrict__ a, int na, int* __restrict__ b, int nb){
  int i = blockIdx.x*256 + threadIdx.x;
  if (i < na) a[i] = 0;
  else if (i - na < nb) b[i - na] = 0;
}

__global__ void k_sentinel(float* out, float wsmb){ out[0] = 1000000.0f + wsmb; }

__global__ void k_einv(const int* __restrict__ perm2, int* __restrict__ einv, int n){
  int i = blockIdx.x*256 + threadIdx.x;
  if (i < n) einv[perm2[i]] = i;
}

__global__ void k_lidx2(const int* __restrict__ lsrc, const int* __restrict__ ldst,
                        const int* __restrict__ perm1, const int* __restrict__ einv,
                        int* __restrict__ lsrc2, int* __restrict__ ldst2, int n){
  int i = blockIdx.x*256 + threadIdx.x;
  if (i < n){
    int o = perm1[i];
    lsrc2[i] = einv[lsrc[o]];
    ldst2[i] = einv[ldst[o]];
  }
}

// ---------------- parallel 3-pass exclusive scan ----------------

__global__ __launch_bounds__(256) void k_scanp1(
    const int* __restrict__ inA, int* __restrict__ outA,
    const int* __restrict__ inB, int* __restrict__ outB,
    int* __restrict__ bsumA, int* __restrict__ bsumB){
  __shared__ int wsum[4];
  const int b = blockIdx.x, t = threadIdx.x;
  const int* in;  int* out;  int* bsum;  int base;
  if (b < 64){ in = inA; out = outA; bsum = bsumA + b; base = b*2048; }
  else       { in = inB; out = outB; bsum = bsumB;     base = 0; }
  int v[8];
  int s = 0;
  #pragma unroll
  for (int j=0;j<8;j++){ v[j] = in[base + t*8 + j]; s += v[j]; }
  const int lane = t & 63, wid = t >> 6;
  int x = s;
  #pragma unroll
  for (int off=1; off<64; off<<=1){
    int u = __shfl_up(x, off);
    if (lane >= off) x += u;
  }
  if (lane == 63) wsum[wid] = x;
  __syncthreads();
  int woff = 0;
  #pragma unroll
  for (int i=0;i<3;i++) if (i < wid) woff += wsum[i];
  int run = woff + x - s;
  #pragma unroll
  for (int j=0;j<8;j++){ out[base + t*8 + j] = run; run += v[j]; }
  if (t == 255) *bsum = woff + x;
}

__global__ void k_scanp2(int* __restrict__ bsumA, int* __restrict__ outA, int nA,
                         const int* __restrict__ bsumB, int* __restrict__ outB, int nB){
  __shared__ int sh[64];
  const int t = threadIdx.x;
  if (t < 64) sh[t] = bsumA[t];
  __syncthreads();
  if (t == 0){
    int run = 0;
    for (int i=0;i<64;i++){ int v = sh[i]; sh[i] = run; run += v; }
    outA[nA] = run;
    outB[nB] = bsumB[0];
  }
  __syncthreads();
  if (t < 64) bsumA[t] = sh[t];
}

__global__ __launch_bounds__(256) void k_scanp3(int* __restrict__ outA, const int* __restrict__ bsumA){
  const int b = blockIdx.x;
  const int off = bsumA[b];
  const int base = b*2048 + threadIdx.x*8;
  #pragma unroll
  for (int j=0;j<8;j++) outA[base+j] += off;
}

// all per-layer weight-fragment conversions in ONE dispatch (j-pair cols).
// EU W1 is FOLDED: effective [256][256] where row r<128 = W1[r]+W1[r+128],
// row r>=128 = W1[r+128] (laggr part). 72 blocks/layer.
__global__ void k_wfrag_all(const float* __restrict__ luw1, const float* __restrict__ luw2,
                            const float* __restrict__ euw1, const float* __restrict__ euw2,
                            u16* __restrict__ lw1h, u16* __restrict__ lw2h,
                            u16* __restrict__ ew1h, u16* __restrict__ ew2h){
  int l = blockIdx.x / 72, r = blockIdx.x % 72;
  const float* W; u16* out; int N, total, lb; bool fold = false;
  if (r < 16){      W = luw1 + (size_t)l*256*128; out = lw1h + (size_t)l*32768; N=128; total=4096;  lb = r; }
  else if (r < 24){ W = luw2 + (size_t)l*128*128; out = lw2h + (size_t)l*16384; N=128; total=2048;  lb = r-16; }
  else if (r < 56){ W = euw1 + (size_t)l*384*256; out = ew1h + (size_t)l*65536; N=256; total=8192;  lb = r-24; fold = true; }
  else {            W = euw2 + (size_t)l*256*128; out = ew2h + (size_t)l*32768; N=128; total=4096;  lb = r-56; }
  int i = lb*256 + threadIdx.x;
  if (i >= total) return;
  int lane = i & 63;
  int frag = i >> 6;
  int NT = N >> 4;
  int ntg = frag % NT;
  int kt = frag / NT;
  int half = NT >> 1;
  int colh = ntg / half, j = ntg % half;
  int col  = colh*(half<<4) + ((j>>1)<<5) + 2*(lane&15) + (j&1);
  int row0 = kt*32 + (lane>>4)*8;
  uint4 v; uint* vp = (uint*)&v;
  #pragma unroll
  for (int p=0;p<4;p++){
    int ra = row0+2*p, rb = row0+2*p+1;
    float fa, fb;
    if (fold){
      fa = (ra < 128) ? W[(size_t)ra*N + col] + W[(size_t)(ra+128)*N + col]
                      : W[(size_t)(ra+128)*N + col];
      fb = (rb < 128) ? W[(size_t)rb*N + col] + W[(size_t)(rb+128)*N + col]
                      : W[(size_t)(rb+128)*N + col];
    } else {
      fa = W[(size_t)ra*N + col];
      fb = W[(size_t)rb*N + col];
    }
    vp[p] = (uint)f2h(fa) | ((uint)f2h(fb)<<16);
  }
  *(uint4*)(out + (size_t)i*8) = v;
}

// rbf weights -> fragments: w1 [50][128] zero-padded to K=64; w2 [128][128].
__global__ void k_rbf_wfrag(const float* __restrict__ rw1, const float* __restrict__ rw2,
                            u16* __restrict__ w1p, u16* __restrict__ w2p){
  int r = blockIdx.x;
  const float* W; u16* out; int K, total;
  if (r < 4){ W = rw1; out = w1p; K = 50;  total = 1024; }
  else      { W = rw2; out = w2p; K = 128; total = 2048; r -= 4; }
  int i = r*256 + threadIdx.x;
  if (i >= total) return;
  int lane = i & 63, frag = i >> 6;
  int ntg = frag % 8, kt = frag / 8;
  int colh = ntg / 4, j = ntg % 4;
  int col  = colh*64 + ((j>>1)<<5) + 2*(lane&15) + (j&1);
  int row0 = kt*32 + (lane>>4)*8;
  uint4 v; uint* vp = (uint*)&v;
  #pragma unroll
  for (int p=0;p<4;p++){
    int ra = row0+2*p, rb = row0+2*p+1;
    u16 a = (ra < K) ? f2h(W[(size_t)ra*128 + col]) : (u16)0;
    u16 b = (rb < K) ? f2h(W[(size_t)rb*128 + col]) : (u16)0;
    vp[p] = (uint)a | ((uint)b<<16);
  }
  *(uint4*)(out + (size_t)i*8) = v;
}

// ---------------- init ----------------

__global__ void k_node_init(const int* __restrict__ an, const float* __restrict__ tab, float* __restrict__ node){
  int i = blockIdx.x*256 + threadIdx.x;          // NN*DM threads
  int n = i >> 7, d = i & 127;
  node[i] = tab[(an[n]-1)*DM + d];
}

__global__ void k_line_init(const float* __restrict__ ang, const float* __restrict__ w,
                            const float* __restrict__ b, const int* __restrict__ perm1,
                            u16* __restrict__ line){
  int i = blockIdx.x*256 + threadIdx.x;          // NL*64 threads (2 cols each)
  int r = i >> 6; int c2 = (i & 63)*2;
  float a = ang[perm1[r]];
  ushort2 v;
  v.x = f2h(a*w[c2  ] + b[c2  ]);
  v.y = f2h(a*w[c2+1] + b[c2+1]);
  ((ushort2*)line)[i] = v;
}

// MFMA edge embedding: 32 edges/block; rbf f16 [32][64-pad]; two MFMA GEMMs.
#define EB_RS 72    // 64+8 halves
#define EB_HS 136   // 128+8 halves

__global__ __launch_bounds__(256) void k_edge_embed2(
    const float* __restrict__ pos, const int* __restrict__ eidx,
    const int* __restrict__ eperm,
    const u16* __restrict__ W1p, const float* __restrict__ B1,
    const u16* __restrict__ W2p, const float* __restrict__ B2,
    u16* __restrict__ edge){
  __shared__ __align__(16) u16 rs[32*EB_RS];
  __shared__ __align__(16) u16 hs[32*EB_HS];
  __shared__ float dsh[32];
  const int t = threadIdx.x;
  const int e0 = blockIdx.x*32;
  if (t < 32){
    int eo = eperm[e0 + t];
    int s = eidx[eo], d = eidx[NE + eo];
    float dx = pos[d*3+0]-pos[s*3+0];
    float dy = pos[d*3+1]-pos[s*3+1];
    float dz = pos[d*3+2]-pos[s*3+2];
    dsh[t] = sqrtf(dx*dx+dy*dy+dz*dz);
  }
  __syncthreads();
  for (int q = t; q < 32*64; q += 256){
    int m = q >> 6, k = q & 63;
    float d = dsh[m];
    float v = 0.f;
    if (k < 50){
      float c = 8.0f*(float)k/49.0f;
      float g = __expf(-(d-c)*(d-c)*19.53125f);
      float cut = (d < 8.0f) ? 0.5f*(__cosf(d*0.39269908169872414f)+1.0f) : 0.0f;
      v = g*cut;
    }
    rs[m*EB_RS + k] = f2h(v);
  }
  __syncthreads();

  const int lane = t & 63, w = t >> 6;
  const int band = w >> 1, colh = w & 1;
  const int arow = band*16 + (lane & 15);
  const int kgrp = (lane >> 4)*8;
  const int q2 = 2*(lane & 15);

  {
    f32x4 acc[4];
    #pragma unroll
    for (int nt=0; nt<4; ++nt){
      float bv = B1[colh*64 + (nt>>1)*32 + q2 + (nt&1)];
      acc[nt][0]=bv; acc[nt][1]=bv; acc[nt][2]=bv; acc[nt][3]=bv;
    }
    #pragma unroll
    for (int kt=0; kt<2; ++kt){
      f16x8 a = *(const f16x8*)(rs + arow*EB_RS + kt*32 + kgrp);
      #pragma unroll
      for (int nt=0; nt<4; ++nt){
        int ntg = colh*4 + nt;
        f16x8 b = *(const f16x8*)(W1p + ((size_t)(kt*8 + ntg)*64 + lane)*8);
        acc[nt] = __builtin_amdgcn_mfma_f32_16x16x32_f16(a, b, acc[nt], 0, 0, 0);
      }
    }
    #pragma unroll
    for (int p=0; p<2; ++p){
      int colb = colh*64 + p*32 + q2;
      #pragma unroll
      for (int r=0; r<4; ++r){
        int row = band*16 + (lane>>4)*4 + r;
        *(uint*)(hs + row*EB_HS + colb) = pk2h(siluf(acc[2*p][r]), siluf(acc[2*p+1][r]));
      }
    }
  }
  __syncthreads();
  {
    f32x4 acc[4];
    #pragma unroll
    for (int nt=0; nt<4; ++nt){
      float bv = B2[colh*64 + (nt>>1)*32 + q2 + (nt&1)];
      acc[nt][0]=bv; acc[nt][1]=bv; acc[nt][2]=bv; acc[nt][3]=bv;
    }
    #pragma unroll
    for (int kt=0; kt<4; ++kt){
      f16x8 a = *(const f16x8*)(hs + arow*EB_HS + kt*32 + kgrp);
      #pragma unroll
      for (int nt=0; nt<4; ++nt){
        int ntg = colh*4 + nt;
        f16x8 b = *(const f16x8*)(W2p + ((size_t)(kt*8 + ntg)*64 + lane)*8);
        acc[nt] = __builtin_amdgcn_mfma_f32_16x16x32_f16(a, b, acc[nt], 0, 0, 0);
      }
    }
    #pragma unroll
    for (int p=0; p<2; ++p){
      int colb = colh*64 + p*32 + q2;
      #pragma unroll
      for (int r=0; r<4; ++r){
        int row = band*16 + (lane>>4)*4 + r;
        *(uint*)(edge + (size_t)(e0+row)*DM + colb) = pk2h(acc[2*p][r], acc[2*p+1][r]);
      }
    }
  }
}

// ---------------- CSR build (merged dispatches) ----------------

__global__ void k_hist2(const int* __restrict__ idxA, int* __restrict__ histA,
                        const int* __restrict__ idxB, int* __restrict__ histB, int nblkA){
  int t = threadIdx.x;
  if ((int)blockIdx.x < nblkA){
    int i = blockIdx.x*256 + t;
    atomicAdd(&histA[idxA[i]], 1);
  } else {
    int i = (blockIdx.x - nblkA)*256 + t;
    atomicAdd(&histB[idxB[i]], 1);
  }
}

__global__ void k_perm2k(const int* __restrict__ idxA, const int* __restrict__ baseA,
                         int* __restrict__ curA, int* __restrict__ permA,
                         const int* __restrict__ idxB, const int* __restrict__ baseB,
                         int* __restrict__ curB, int* __restrict__ permB, int nblkA){
  int t = threadIdx.x;
  if ((int)blockIdx.x < nblkA){
    int i = blockIdx.x*256 + t;
    int e = idxA[i];
    int p = atomicAdd(&curA[e], 1);
    permA[baseA[e] + p] = i;
  } else {
    int i = (blockIdx.x - nblkA)*256 + t;
    int e = idxB[i];
    int p = atomicAdd(&curB[e], 1);
    permB[baseB[e] + p] = i;
  }
}

// ---------------- LU precompute: A = edge@W1top, Bm = edge@W1bot ----------------

#define PE_XS 136

__global__ __launch_bounds__(256) void k_pre_lu(
    const u16* __restrict__ edge, const u16* __restrict__ W1h,
    u16* __restrict__ A16, u16* __restrict__ Bm16){
  __shared__ __align__(16) u16 xs[32*PE_XS];
  const int t = threadIdx.x;
  const int r0 = blockIdx.x*32;
  #pragma unroll
  for (int it=0; it<2; ++it){
    int idx = it*256 + t;
    int m = idx >> 4, c = idx & 15;
    uint4 v = *(const uint4*)(edge + (size_t)(r0+m)*DM + c*8);
    *(uint4*)(xs + m*PE_XS + c*8) = v;
  }
  __syncthreads();
  const int lane = t & 63, w = t >> 6;
  const int band = w >> 1, colh = w & 1;
  const int arow = band*16 + (lane & 15);
  const int kgrp = (lane >> 4)*8;
  const int q2 = 2*(lane & 15);
  #pragma unroll
  for (int half=0; half<2; ++half){
    f32x4 acc[4];
    #pragma unroll
    for (int nt=0; nt<4; ++nt){ acc[nt][0]=0.f; acc[nt][1]=0.f; acc[nt][2]=0.f; acc[nt][3]=0.f; }
    #pragma unroll
    for (int kt=0; kt<4; ++kt){
      f16x8 a = *(const f16x8*)(xs + arow*PE_XS + kt*32 + kgrp);
      #pragma unroll
      for (int nt=0; nt<4; ++nt){
        int ntg = colh*4 + nt;
        f16x8 b = *(const f16x8*)(W1h + ((size_t)((kt + half*4)*8 + ntg)*64 + lane)*8);
        acc[nt] = __builtin_amdgcn_mfma_f32_16x16x32_f16(a, b, acc[nt], 0, 0, 0);
      }
    }
    u16* out = half ? Bm16 : A16;
    #pragma unroll
    for (int p=0; p<2; ++p){
      int colb = colh*64 + p*32 + q2;
      #pragma unroll
      for (int r=0; r<4; ++r){
        int row = band*16 + (lane>>4)*4 + r;
        *(uint*)(out + (size_t)(r0+row)*DM + colb) = pk2h(acc[2*p][r], acc[2*p+1][r]);
      }
    }
  }
}

// ---------------- LU: h = silu(A[src]+Bm[dst]+b1); line = LN(line + h@W2+b2) ----------------

#define LU_HS 136   // halves (H overlay in smem)
#define LU_OS 132   // floats

__global__ __launch_bounds__(256) void k_lu2(
    const u16* __restrict__ A16, const u16* __restrict__ Bm16,
    const int* __restrict__ lsrc2, const int* __restrict__ ldst2,
    const float* __restrict__ B1,
    const u16* __restrict__ W2h, const float* __restrict__ B2,
    const float* __restrict__ lg, const float* __restrict__ lb,
    u16* __restrict__ line){
  __shared__ __align__(16) float smem[32*LU_OS];
  u16* hs = (u16*)smem;
  const int t = threadIdx.x;
  const int r0 = blockIdx.x*32;

  {
    int m = t >> 3, c8 = t & 7;
    int r = r0 + m;
    const u16* ap = A16  + (size_t)lsrc2[r]*DM;
    const u16* bp = Bm16 + (size_t)ldst2[r]*DM;
    #pragma unroll
    for (int cc0=0; cc0<2; ++cc0){
      int cc = c8 + cc0*8;
      uint4 av = *(const uint4*)(ap + cc*8);
      uint4 bv = *(const uint4*)(bp + cc*8);
      const uint* au = (const uint*)&av;
      const uint* bu = (const uint*)&bv;
      uint outw[4];
      #pragma unroll
      for (int p=0;p<4;p++){
        int col = cc*8 + 2*p;
        float x0 = h2f((u16)(au[p]&0xffffu)) + h2f((u16)(bu[p]&0xffffu)) + B1[col];
        float x1 = h2f((u16)(au[p]>>16))     + h2f((u16)(bu[p]>>16))     + B1[col+1];
        outw[p] = pk2h(siluf(x0), siluf(x1));
      }
      *(uint4*)(hs + m*LU_HS + cc*8) = *(uint4*)outw;
    }
  }
  __syncthreads();

  const int lane = t & 63, w = t >> 6;
  const int band = w >> 1, colh = w & 1;
  const int arow = band*16 + (lane & 15);
  const int kgrp = (lane >> 4)*8;
  const int q2 = 2*(lane & 15);

  f32x4 acc[4];
  #pragma unroll
  for (int nt=0; nt<4; ++nt){
    float bv = B2[colh*64 + (nt>>1)*32 + q2 + (nt&1)];
    acc[nt][0]=bv; acc[nt][1]=bv; acc[nt][2]=bv; acc[nt][3]=bv;
  }
  #pragma unroll
  for (int kt=0; kt<4; ++kt){
    f16x8 a = *(const f16x8*)(hs + arow*LU_HS + kt*32 + kgrp);
    #pragma unroll
    for (int nt=0; nt<4; ++nt){
      int ntg = colh*4 + nt;
      f16x8 b = *(const f16x8*)(W2h + ((size_t)(kt*8 + ntg)*64 + lane)*8);
      acc[nt] = __builtin_amdgcn_mfma_f32_16x16x32_f16(a, b, acc[nt], 0, 0, 0);
    }
  }
  __syncthreads();
  #pragma unroll
  for (int p=0; p<2; ++p){
    int colb = colh*64 + p*32 + q2;
    #pragma unroll
    for (int r=0; r<4; ++r){
      int row = band*16 + (lane>>4)*4 + r;
      *(float2*)(smem + row*LU_OS + colb) = make_float2(acc[2*p][r], acc[2*p+1][r]);
    }
  }
  __syncthreads();
  {
    const float* outp = (const float*)smem;
    int row = t >> 3, li = t & 7;
    size_t rb = (size_t)(r0 + row)*DM;
    uint rw[8];
    *(uint4*)&rw[0] = *(const uint4*)(line + rb + li*16);
    *(uint4*)&rw[4] = *(const uint4*)(line + rb + li*16 + 8);
    float x[16];
    float s=0.f, q=0.f;
    #pragma unroll
    for (int j=0;j<16;j++){
      float res = h2f((u16)((j&1) ? (rw[j>>1]>>16) : (rw[j>>1]&0xffffu)));
      x[j] = outp[row*LU_OS + li*16 + j] + res;
      s += x[j]; q += x[j]*x[j];
    }
    #pragma unroll
    for (int off=1; off<8; off<<=1){ s += __shfl_xor(s,off); q += __shfl_xor(q,off); }
    float mean = s*(1.f/128.f);
    float rstd = rsqrtf(fmaxf(q*(1.f/128.f) - mean*mean, 0.f) + 1e-5f);
    #pragma unroll
    for (int half=0; half<2; ++half){
      uint4 wv; uint* wp = (uint*)&wv;
      #pragma unroll
      for (int p=0;p<4;p++){
        int j = half*8 + 2*p;
        int c0 = li*16 + j;
        wp[p] = pk2h((x[j  ]-mean)*rstd*lg[c0  ] + lb[c0  ],
                     (x[j+1]-mean)*rstd*lg[c0+1] + lb[c0+1]);
      }
      *(uint4*)(line + rb + li*16 + half*8) = wv;
    }
  }
}

// ---------------- MFMA edge update (FOLDED W1: K=256) ----------------

#define EU_XS 264   // 256+8 halves
#define EU_HS 264   // 256+8 halves
#define EU_OS 132   // 128+4 floats

__global__ __launch_bounds__(256) void k_eu_mfma(
    const u16* __restrict__ W1h, const float* __restrict__ B1,
    const u16* __restrict__ W2h, const float* __restrict__ B2,
    const float* __restrict__ g, const float* __restrict__ bb,
    u16* __restrict__ edge, const u16* __restrict__ line,
    const int* __restrict__ lbase, const int* __restrict__ eperm){
  __shared__ __align__(16) u16 xs[32*EU_XS];       // X=[edge|laggr] f16 [32][264]; later OUT f32
  __shared__ __align__(16) u16 hs[32*EU_HS];       // H f16 [32][264]
  const int t = threadIdx.x;
  const int r0 = blockIdx.x*32;

  for (int it=0; it<2; ++it){                    // edge -> cols [0,128)
    int idx = it*256 + t;
    int m = idx >> 4, c = idx & 15;
    uint4 v = *(const uint4*)(edge + (size_t)(r0+m)*DM + c*8);
    *(uint4*)(xs + m*EU_XS + c*8) = v;
  }
  {                                              // laggr -> cols [128,256)
    int m = t >> 3, c0 = (t & 7)*16;
    int eo = eperm[r0 + m];
    int b0 = lbase[eo], b1 = lbase[eo+1];
    float s[16];
    #pragma unroll
    for (int k=0;k<16;k++) s[k]=0.f;
    for (int j=b0;j<b1;++j){                     // contiguous line rows
      const u16* lp = line + (size_t)j*DM + c0;
      uint rw[8];
      *(uint4*)&rw[0] = *(const uint4*)lp;
      *(uint4*)&rw[4] = *(const uint4*)(lp + 8);
      #pragma unroll
      for (int k=0;k<16;k++)
        s[k] += h2f((u16)((k&1) ? (rw[k>>1]>>16) : (rw[k>>1]&0xffffu)));
    }
    int n = b1 - b0;
    float inv = 1.f/(float)(n > 0 ? n : 1);
    #pragma unroll
    for (int half=0; half<2; ++half){
      uint4 wv; uint* wp = (uint*)&wv;
      #pragma unroll
      for (int p=0;p<4;p++){
        int k = half*8 + 2*p;
        wp[p] = pk2h(s[k]*inv, s[k+1]*inv);
      }
      *(uint4*)(xs + m*EU_XS + 128 + c0 + half*8) = wv;
    }
  }
  __syncthreads();

  const int lane = t & 63, w = t >> 6;
  const int band = w >> 1, colh = w & 1;
  const int arow = band*16 + (lane & 15);
  const int kgrp = (lane >> 4)*8;
  const int q2 = 2*(lane & 15);

  {                                              // phase1: wave 16x128, K=256 (8 kts)
    f32x4 acc[8];
    #pragma unroll
    for (int nt=0; nt<8; ++nt){
      float bv = B1[colh*128 + (nt>>1)*32 + q2 + (nt&1)];
      acc[nt][0]=bv; acc[nt][1]=bv; acc[nt][2]=bv; acc[nt][3]=bv;
    }
    #pragma unroll
    for (int kt=0; kt<8; ++kt){
      f16x8 a = *(const f16x8*)(xs + arow*EU_XS + kt*32 + kgrp);
      #pragma unroll
      for (int nt=0; nt<8; ++nt){
        int ntg = colh*8 + nt;
        f16x8 b = *(const f16x8*)(W1h + ((size_t)(kt*16 + ntg)*64 + lane)*8);
        acc[nt] = __builtin_amdgcn_mfma_f32_16x16x32_f16(a, b, acc[nt], 0, 0, 0);
      }
    }
    #pragma unroll
    for (int p=0; p<4; ++p){
      int colb = colh*128 + p*32 + q2;
      #pragma unroll
      for (int r=0; r<4; ++r){
        int row = band*16 + (lane>>4)*4 + r;
        *(uint*)(hs + row*EU_HS + colb) = pk2h(siluf(acc[2*p][r]), siluf(acc[2*p+1][r]));
      }
    }
  }
  __syncthreads();
  {                                              // phase2: wave 16x64, K=256
    f32x4 acc[4];
    #pragma unroll
    for (int nt=0; nt<4; ++nt){
      float bv = B2[colh*64 + (nt>>1)*32 + q2 + (nt&1)];
      acc[nt][0]=bv; acc[nt][1]=bv; acc[nt][2]=bv; acc[nt][3]=bv;
    }
    #pragma unroll
    for (int kt=0; kt<8; ++kt){
      f16x8 a = *(const f16x8*)(hs + arow*EU_HS + kt*32 + kgrp);
      #pragma unroll
      for (int nt=0; nt<4; ++nt){
        int ntg = colh*4 + nt;
        f16x8 b = *(const f16x8*)(W2h + ((size_t)(kt*8 + ntg)*64 + lane)*8);
        acc[nt] = __builtin_amdgcn_mfma_f32_16x16x32_f16(a, b, acc[nt], 0, 0, 0);
      }
    }
    float* outp = (float*)xs;
    #pragma unroll
    for (int p=0; p<2; ++p){
      int colb = colh*64 + p*32 + q2;
      #pragma unroll
      for (int r=0; r<4; ++r){
        int row = band*16 + (lane>>4)*4 + r;
        *(float2*)(outp + row*EU_OS + colb) = make_float2(acc[2*p][r], acc[2*p+1][r]);
      }
    }
  }
  __syncthreads();
  {                                              // LN epilogue
    const float* outp = (const float*)xs;
    int row = t >> 3, li = t & 7;
    size_t rb = (size_t)(r0 + row)*DM;
    uint rw[8];
    *(uint4*)&rw[0] = *(const uint4*)(edge + rb + li*16);
    *(uint4*)&rw[4] = *(const uint4*)(edge + rb + li*16 + 8);
    float x[16];
    float s=0.f, q=0.f;
    #pragma unroll
    for (int j=0;j<16;j++){
      float res = h2f((u16)((j&1) ? (rw[j>>1]>>16) : (rw[j>>1]&0xffffu)));
      x[j] = outp[row*EU_OS + li*16 + j] + res;
      s += x[j]; q += x[j]*x[j];
    }
    #pragma unroll
    for (int off=1; off<8; off<<=1){ s += __shfl_xor(s,off); q += __shfl_xor(q,off); }
    float mean = s*(1.f/128.f);
    float rstd = rsqrtf(fmaxf(q*(1.f/128.f) - mean*mean, 0.f) + 1e-5f);
    #pragma unroll
    for (int half=0; half<2; ++half){
      uint4 wv; uint* wp = (uint*)&wv;
      #pragma unroll
      for (int p=0;p<4;p++){
        int j = half*8 + 2*p;
        int c0 = li*16 + j;
        wp[p] = pk2h((x[j  ]-mean)*rstd*g[c0  ] + bb[c0  ],
                     (x[j+1]-mean)*rstd*g[c0+1] + bb[c0+1]);
      }
      *(uint4*)(edge + rb + li*16 + half*8) = wv;
    }
  }
}

// ---------------- NU: fused 16-row MLP+LN (contiguous naggr walk) ----------------

template<int KIN>
__global__ __launch_bounds__(256) void k_nu(
    const float* __restrict__ W1, const float* __restrict__ B1,
    const float* __restrict__ W2, const float* __restrict__ B2,
    const float* __restrict__ g, const float* __restrict__ bb,
    float* __restrict__ node_io, const u16* __restrict__ edge,
    const int* __restrict__ nbase){
  __shared__ __align__(16) float xsf[16*KIN];
  __shared__ __align__(16) float hsf[16*256];
  const int t = threadIdx.x;
  const int r0 = blockIdx.x*16;

  {
    int m = t >> 4, c0 = (t & 15)*8;
    int n = r0 + m;
    float4 a = ld4(node_io + (size_t)n*DM + c0);
    float4 b = ld4(node_io + (size_t)n*DM + c0 + 4);
    float* xd = &xsf[m*KIN + c0];
    xd[0]=a.x; xd[1]=a.y; xd[2]=a.z; xd[3]=a.w;
    xd[4]=b.x; xd[5]=b.y; xd[6]=b.z; xd[7]=b.w;
    int b0 = nbase[n], b1e = nbase[n+1];
    float s[8];
    #pragma unroll
    for (int k=0;k<8;k++) s[k]=0.f;
    for (int j=b0;j<b1e;++j){
      uint4 v = *(const uint4*)(edge + (size_t)j*DM + c0);
      s[0]+=h2f((u16)(v.x&0xffff)); s[1]+=h2f((u16)(v.x>>16));
      s[2]+=h2f((u16)(v.y&0xffff)); s[3]+=h2f((u16)(v.y>>16));
      s[4]+=h2f((u16)(v.z&0xffff)); s[5]+=h2f((u16)(v.z>>16));
      s[6]+=h2f((u16)(v.w&0xffff)); s[7]+=h2f((u16)(v.w>>16));
    }
    int nn = b1e - b0;
    float inv = 1.f/(float)(nn > 0 ? nn : 1);
    #pragma unroll
    for (int k=0;k<8;k++) xsf[m*KIN + 128 + c0 + k] = s[k]*inv;
  }
  __syncthreads();
  {
    const int c4 = (t & 63)*4, mg = t >> 6;
    float acc[4][4];
    float4 bv = ld4(B1 + c4);
    #pragma unroll
    for (int i=0;i<4;i++){ acc[i][0]=bv.x; acc[i][1]=bv.y; acc[i][2]=bv.z; acc[i][3]=bv.w; }
    for (int k=0;k<KIN;k+=4){
      float4 w0 = ld4(W1 + (k  )*256 + c4);
      float4 w1 = ld4(W1 + (k+1)*256 + c4);
      float4 w2 = ld4(W1 + (k+2)*256 + c4);
      float4 w3 = ld4(W1 + (k+3)*256 + c4);
      #pragma unroll
      for (int i=0;i<4;i++){
        float4 x = *(const float4*)&xsf[(mg*4+i)*KIN + k];
        fma44(acc[i], x, w0, w1, w2, w3);
      }
    }
    #pragma unroll
    for (int i=0;i<4;i++)
      #pragma unroll
      for (int j=0;j<4;j++)
        hsf[(mg*4+i)*256 + c4 + j] = siluf(acc[i][j]);
  }
  __syncthreads();
  const int c4b = (t & 31)*4, mgb = t >> 5;
  float acc2[2][4];
  {
    float4 bv = ld4(B2 + c4b);
    #pragma unroll
    for (int i=0;i<2;i++){ acc2[i][0]=bv.x; acc2[i][1]=bv.y; acc2[i][2]=bv.z; acc2[i][3]=bv.w; }
    for (int k=0;k<256;k+=4){
      float4 w0 = ld4(W2 + (k  )*128 + c4b);
      float4 w1 = ld4(W2 + (k+1)*128 + c4b);
      float4 w2 = ld4(W2 + (k+2)*128 + c4b);
      float4 w3 = ld4(W2 + (k+3)*128 + c4b);
      #pragma unroll
      for (int i=0;i<2;i++){
        float4 x = *(const float4*)&hsf[(mgb*2+i)*256 + k];
        fma44(acc2[i], x, w0, w1, w2, w3);
      }
    }
  }
  __syncthreads();
  #pragma unroll
  for (int i=0;i<2;i++){
    int m = mgb*2 + i;
    #pragma unroll
    for (int j=0;j<4;j++)
      hsf[m*128 + c4b + j] = acc2[i][j] + xsf[m*KIN + c4b + j];
  }
  __syncthreads();
  {
    int row = t >> 4, li = t & 15;
    const float* o = &hsf[row*128];
    float s=0.f, q=0.f;
    #pragma unroll
    for (int j=0;j<8;j++){ float x = o[li*8+j]; s += x; q += x*x; }
    #pragma unroll
    for (int off=1; off<16; off<<=1){ s += __shfl_xor(s,off); q += __shfl_xor(q,off); }
    float mean = s*(1.f/128.f);
    float rstd = rsqrtf(fmaxf(q*(1.f/128.f) - mean*mean, 0.f) + 1e-5f);
    size_t rb = (size_t)(r0 + row)*DM;
    #pragma unroll
    for (int j=0;j<8;j++){
      int c = li*8 + j;
      node_io[rb + c] = (o[c]-mean)*rstd*g[c] + bb[c];
    }
  }
}

// ---------------- attention ----------------

__global__ void k_qkv_split(const float* __restrict__ node, const float* __restrict__ W,
                            const float* __restrict__ B, float* __restrict__ Q,
                            u16* __restrict__ K4, u16* __restrict__ V4){
  int i = blockIdx.x*256 + threadIdx.x;          // NN*384 threads
  int n = i / 384, c = i % 384;
  float acc = B[c];
  const float* nr = node + (size_t)n*DM;
  for (int k=0;k<128;k+=4){
    acc += nr[k  ]*W[(k  )*384+c];
    acc += nr[k+1]*W[(k+1)*384+c];
    acc += nr[k+2]*W[(k+2)*384+c];
    acc += nr[k+3]*W[(k+3)*384+c];
  }
  if (c < 128){
    Q[(size_t)n*128 + c] = acc;
  } else if (c < 256){
    int h = (c-128) >> 5, d = (c-128) & 31;
    K4[((size_t)h*NN + n)*32 + d] = f2h(acc);
  } else {
    int h = (c-256) >> 5, d = (c-256) & 31;
    V4[((size_t)h*NN + n)*32 + d] = f2h(acc);
  }
}

// 4 waves = 8 queries x 1 head; 128-key f16 tiles, double-buffered LDS
#define AT_TK 128
#define AT_RU 17

__global__ __launch_bounds__(256) void k_attn3(
    const float* __restrict__ Q, const u16* __restrict__ K4,
    const u16* __restrict__ V4, float* __restrict__ attno){
  __shared__ uint kls[2][AT_TK*AT_RU];
  __shared__ uint vls[2][AT_TK*AT_RU];
  const int t = threadIdx.x, lane = t & 63;
  const int h = blockIdx.x >> 8;
  const int q0 = (blockIdx.x & 255)*8 + (t >> 6)*2;
  const float scale = 0.17677669529663687f;
  const uint* Kg = (const uint*)(K4 + (size_t)h*NN*32);
  const uint* Vg = (const uint*)(V4 + (size_t)h*NN*32);
  const int ca = t*2, cb = t*2+1;
  const int ka_ = ca>>2, pa_ = (ca&3)*4;
  const int kb_ = cb>>2, pb_ = (cb&3)*4;
  uint4 kr0, kr1, vr0, vr1;

  float q[2][32];
  #pragma unroll
  for (int j=0;j<2;j++){
    const float* qr = Q + (size_t)(q0+j)*128 + h*32;
    #pragma unroll
    for (int d=0;d<32;d+=4){
      float4 v = *(const float4*)(qr + d);
      q[j][d]=v.x*scale; q[j][d+1]=v.y*scale; q[j][d+2]=v.z*scale; q[j][d+3]=v.w*scale;
    }
  }
  float mx = -1e30f, s0 = 0.f, s1 = 0.f;
  float o0[32], o1[32];
  #pragma unroll
  for (int d=0;d<32;d++){ o0[d]=0.f; o1[d]=0.f; }

  {
    const uint* kg = Kg; const uint* vg = Vg;
    kr0 = *(const uint4*)(kg + ca*4); kr1 = *(const uint4*)(kg + cb*4);
    vr0 = *(const uint4*)(vg + ca*4); vr1 = *(const uint4*)(vg + cb*4);
    uint* kd = kls[0]; uint* vd = vls[0];
    kd[ka_*AT_RU+pa_  ]=kr0.x; kd[ka_*AT_RU+pa_+1]=kr0.y; kd[ka_*AT_RU+pa_+2]=kr0.z; kd[ka_*AT_RU+pa_+3]=kr0.w;
    kd[kb_*AT_RU+pb_  ]=kr1.x; kd[kb_*AT_RU+pb_+1]=kr1.y; kd[kb_*AT_RU+pb_+2]=kr1.z; kd[kb_*AT_RU+pb_+3]=kr1.w;
    vd[ka_*AT_RU+pa_  ]=vr0.x; vd[ka_*AT_RU+pa_+1]=vr0.y; vd[ka_*AT_RU+pa_+2]=vr0.z; vd[ka_*AT_RU+pa_+3]=vr0.w;
    vd[kb_*AT_RU+pb_  ]=vr1.x; vd[kb_*AT_RU+pb_+1]=vr1.y; vd[kb_*AT_RU+pb_+2]=vr1.z; vd[kb_*AT_RU+pb_+3]=vr1.w;
  }
  __syncthreads();

  const int NT = NN / AT_TK;
  for (int kt=0; kt<NT; ++kt){
    if (kt+1 < NT){
      const uint* kg = Kg + (size_t)(kt+1)*AT_TK*16;
      const uint* vg = Vg + (size_t)(kt+1)*AT_TK*16;
      kr0 = *(const uint4*)(kg + ca*4); kr1 = *(const uint4*)(kg + cb*4);
      vr0 = *(const uint4*)(vg + ca*4); vr1 = *(const uint4*)(vg + cb*4);
    }
    {
      const uint* kb = kls[kt&1];
      const uint* vb = vls[kt&1];
      #pragma unroll
      for (int half=0; half<2; ++half){
        int key = lane + half*64;
        const uint* kr = kb + key*AT_RU;
        float d0=0.f, d1=0.f;
        #pragma unroll
        for (int u=0;u<16;u++){
          uint w = kr[u];
          float a = h2f((u16)(w&0xffffu)), b2 = h2f((u16)(w>>16));
          d0 += q[0][2*u]*a + q[0][2*u+1]*b2;
          d1 += q[1][2*u]*a + q[1][2*u+1]*b2;
        }
        float nm = fmaxf(mx, fmaxf(d0,d1));
        float r  = __expf(mx - nm);
        float e0 = __expf(d0 - nm), e1 = __expf(d1 - nm);
        s0 = s0*r + e0;
        s1 = s1*r + e1;
        mx = nm;
        const uint* vr = vb + key*AT_RU;
        #pragma unroll
        for (int u=0;u<16;u++){
          uint w = vr[u];
          float a = h2f((u16)(w&0xffffu)), b2 = h2f((u16)(w>>16));
          o0[2*u  ] = o0[2*u  ]*r + e0*a;  o1[2*u  ] = o1[2*u  ]*r + e1*a;
          o0[2*u+1] = o0[2*u+1]*r + e0*b2; o1[2*u+1] = o1[2*u+1]*r + e1*b2;
        }
      }
    }
    __syncthreads();
    if (kt+1 < NT){
      uint* kd = kls[(kt+1)&1]; uint* vd = vls[(kt+1)&1];
      kd[ka_*AT_RU+pa_  ]=kr0.x; kd[ka_*AT_RU+pa_+1]=kr0.y; kd[ka_*AT_RU+pa_+2]=kr0.z; kd[ka_*AT_RU+pa_+3]=kr0.w;
      kd[kb_*AT_RU+pb_  ]=kr1.x; kd[kb_*AT_RU+pb_+1]=kr1.y; kd[kb_*AT_RU+pb_+2]=kr1.z; kd[kb_*AT_RU+pb_+3]=kr1.w;
      vd[ka_*AT_RU+pa_  ]=vr0.x; vd[ka_*AT_RU+pa_+1]=vr0.y; vd[ka_*AT_RU+pa_+2]=vr0.z; vd[ka_*AT_RU+pa_+3]=vr0.w;
      vd[kb_*AT_RU+pb_  ]=vr1.x; vd[kb_*AT_RU+pb_+1]=vr1.y; vd[kb_*AT_RU+pb_+2]=vr1.z; vd[kb_*AT_RU+pb_+3]=vr1.w;
      __syncthreads();
    }
  }

  #pragma unroll
  for (int off=1; off<64; off<<=1){
    float m2  = __shfl_xor(mx, off);
    float s02 = __shfl_xor(s0, off);
    float s12 = __shfl_xor(s1, off);
    float nm = fmaxf(mx, m2);
    float ra = __expf(mx - nm), rb = __expf(m2 - nm);
    s0 = s0*ra + s02*rb;
    s1 = s1*ra + s12*rb;
    #pragma unroll
    for (int d=0;d<32;d++){
      float a0 = __shfl_xor(o0[d], off);
      float a1 = __shfl_xor(o1[d], off);
      o0[d] = o0[d]*ra + a0*rb;
      o1[d] = o1[d]*ra + a1*rb;
    }
    mx = nm;
  }
  float inv0 = 1.f/s0, inv1 = 1.f/s1;
  if (lane == 0){
    #pragma unroll
    for (int d=0;d<32;d++){
      attno[(size_t)(q0  )*DM + h*32 + d] = o0[d]*inv0;
      attno[(size_t)(q0+1)*DM + h*32 + d] = o1[d]*inv1;
    }
  }
}

__global__ void k_wo(const float* __restrict__ attno, const float* __restrict__ W,
                     const float* __restrict__ B, float* __restrict__ node){
  int i = blockIdx.x*256 + threadIdx.x;          // NN*DM
  int n = i >> 7, c = i & 127;
  float acc = B[c];
  const float* ar = attno + (size_t)n*DM;
  for (int k=0;k<128;k+=4){
    acc += ar[k  ]*W[(k  )*128+c];
    acc += ar[k+1]*W[(k+1)*128+c];
    acc += ar[k+2]*W[(k+2)*128+c];
    acc += ar[k+3]*W[(k+3)*128+c];
  }
  node[i] = acc;
}

// ---------------- readout ----------------

__global__ __launch_bounds__(256) void k_readout(
    const float* __restrict__ node,
    const float* __restrict__ w1, const float* __restrict__ b1,
    const float* __restrict__ w2, const float* __restrict__ b2,
    const float* __restrict__ w3, const float* __restrict__ b3,
    float* __restrict__ out){
  __shared__ float gs[128], h1[128], h2[64];
  const int t = threadIdx.x;
  if (t < 128){
    float s = 0.f;
    for (int r=0;r<NN;r++) s += node[(size_t)r*DM + t];
    gs[t] = s*(1.f/2048.f);
  }
  __syncthreads();
  if (t < 128){
    float acc = b1[t];
    for (int k=0;k<128;k++) acc += gs[k]*w1[k*128+t];
    h1[t] = siluf(acc);
  }
  __syncthreads();
  if (t < 64){
    float acc = b2[t];
    for (int k=0;k<128;k++) acc += h1[k]*w2[k*64+t];
    h2[t] = siluf(acc);
  }
  __syncthreads();
  if (t == 0){
    float acc = b3[0];
    for (int k=0;k<64;k++) acc += h2[k]*w3[k];
    out[0] = acc;                                // f32 output
  }
}

// ---------------- host launch ----------------

extern "C" void kernel_launch(void* const* d_in, const int* in_sizes, int n_in,
                              void* d_out, int out_size, void* d_ws, size_t ws_size,
                              hipStream_t stream) {
  (void)in_sizes; (void)n_in; (void)out_size;
  const int*   an    = (const int*)  d_in[0];
  const float* pos   = (const float*)d_in[1];
  const int*   eidx  = (const int*)  d_in[2];
  const int*   lidx  = (const int*)  d_in[3];
  const float* lang  = (const float*)d_in[4];
  const float* atab  = (const float*)d_in[5];
  const float* rw1   = (const float*)d_in[6];
  const float* rb1   = (const float*)d_in[7];
  const float* rw2   = (const float*)d_in[8];
  const float* rb2   = (const float*)d_in[9];
  const float* lew   = (const float*)d_in[10];
  const float* leb   = (const float*)d_in[11];
  const float* euw1  = (const float*)d_in[12];
  const float* eub1  = (const float*)d_in[13];
  const float* euw2  = (const float*)d_in[14];
  const float* eub2  = (const float*)d_in[15];
  const float* luw1  = (const float*)d_in[16];
  const float* lub1  = (const float*)d_in[17];
  const float* luw2  = (const float*)d_in[18];
  const float* lub2  = (const float*)d_in[19];
  const float* nuw1  = (const float*)d_in[20];
  const float* nub1  = (const float*)d_in[21];
  const float* nuw2  = (const float*)d_in[22];
  const float* nub2  = (const float*)d_in[23];
  const float* wqkv  = (const float*)d_in[24];
  const float* bqkv  = (const float*)d_in[25];
  const float* wo    = (const float*)d_in[26];
  const float* bo    = (const float*)d_in[27];
  const float* nng   = (const float*)d_in[28];
  const float* nnb   = (const float*)d_in[29];
  const float* eng   = (const float*)d_in[30];
  const float* enb   = (const float*)d_in[31];
  const float* lng   = (const float*)d_in[32];
  const float* lnb   = (const float*)d_in[33];
  const float* row1  = (const float*)d_in[34];
  const float* rob1  = (const float*)d_in[35];
  const float* row2  = (const float*)d_in[36];
  const float* rob2  = (const float*)d_in[37];
  const float* row3  = (const float*)d_in[38];
  const float* rob3  = (const float*)d_in[39];

  // workspace layout (~247 MB; sentinel reveals ws_MB if short)
  char* p = (char*)d_ws;
  auto bump = [&](size_t bytes)->char*{ char* q = p; p += (bytes + 255) & ~(size_t)255; return q; };
  float* node  = (float*)bump((size_t)NN*DM*4);
  float* Q     = (float*)bump((size_t)NN*128*4);
  u16*   K4    = (u16*)  bump((size_t)4*NN*32*2);
  u16*   V4    = (u16*)  bump((size_t)4*NN*32*2);
  float* attno = (float*)bump((size_t)NN*DM*4);
  u16*   edge  = (u16*)  bump((size_t)NE*DM*2);     // perm2 (dst-sorted) order
  u16*   line  = (u16*)  bump((size_t)NL*DM*2);     // perm1 (ldst-sorted) order
  u16*   A16   = (u16*)  bump((size_t)NE*DM*2);
  u16*   Bm16  = (u16*)  bump((size_t)NE*DM*2);
  int*   base1 = (int*)  bump((size_t)(NE+1)*4);
  int*   base2 = (int*)  bump((size_t)(NN+1)*4);
  int*   cur1  = (int*)  bump((size_t)NE*4);
  int*   cur2  = (int*)  bump((size_t)NN*4);
  int*   perm1 = (int*)  bump((size_t)NL*4);
  int*   perm2 = (int*)  bump((size_t)NE*4);
  int*   einv  = (int*)  bump((size_t)NE*4);
  int*   lsrc2 = (int*)  bump((size_t)NL*4);
  int*   ldst2 = (int*)  bump((size_t)NL*4);
  int*   bsumA = (int*)  bump((size_t)64*4);
  int*   bsumB = (int*)  bump((size_t)4);
  u16*   lw1h  = (u16*)  bump((size_t)4*32768*2);
  u16*   lw2h  = (u16*)  bump((size_t)4*16384*2);
  u16*   ew1h  = (u16*)  bump((size_t)4*65536*2);   // FOLDED EU W1 (256x256)
  u16*   ew2h  = (u16*)  bump((size_t)4*32768*2);
  u16*   rw1p  = (u16*)  bump((size_t)8192*2);
  u16*   rw2p  = (u16*)  bump((size_t)16384*2);
  size_t needed = (size_t)(p - (char*)d_ws);
  if (needed > ws_size){
    k_sentinel<<<1, 1, 0, stream>>>((float*)d_out, (float)(ws_size >> 20));
    return;
  }

  const int* lsrc = lidx;
  const int* ldst = lidx + NL;
  const int* dst  = eidx + NE;

  // CSR builds (merged dispatches; index structure is layer-invariant)
  const int nblkA = NL/256, nblkB = NE/256;
  k_zero2<<<(NE+NN+255)/256, 256, 0, stream>>>(cur1, NE, cur2, NN);
  k_hist2<<<nblkA+nblkB, 256, 0, stream>>>(ldst, cur1, dst, cur2, nblkA);
  k_scanp1<<<65, 256, 0, stream>>>(cur1, base1, cur2, base2, bsumA, bsumB);
  k_scanp2<<<1, 64, 0, stream>>>(bsumA, base1, NE, bsumB, base2, NN);
  k_scanp3<<<64, 256, 0, stream>>>(base1, bsumA);
  k_zero2<<<(NE+NN+255)/256, 256, 0, stream>>>(cur1, NE, cur2, NN);
  k_perm2k<<<nblkA+nblkB, 256, 0, stream>>>(ldst, base1, cur1, perm1,
                                            dst,  base2, cur2, perm2, nblkA);
  k_einv<<<(NE+255)/256, 256, 0, stream>>>(perm2, einv, NE);
  k_lidx2<<<(NL+255)/256, 256, 0, stream>>>(lsrc, ldst, perm1, einv, lsrc2, ldst2, NL);

  // weight fragment conversion (72 blocks/layer; EU W1 folded)
  k_wfrag_all<<<4*72, 256, 0, stream>>>(luw1, luw2, euw1, euw2, lw1h, lw2h, ew1h, ew2h);
  k_rbf_wfrag<<<12, 256, 0, stream>>>(rw1, rw2, rw1p, rw2p);

  // embeddings (sorted storage orders)
  k_node_init<<<NN*DM/256, 256, 0, stream>>>(an, atab, node);
  k_line_init<<<NL*64/256, 256, 0, stream>>>(lang, lew, leb, perm1, line);
  k_edge_embed2<<<NE/32, 256, 0, stream>>>(pos, eidx, perm2, rw1p, rb1, rw2p, rb2, edge);

  for (int l=0; l<4; ++l){
    k_pre_lu<<<NE/32, 256, 0, stream>>>(edge, lw1h + (size_t)l*32768, A16, Bm16);
    k_lu2<<<NL/32, 256, 0, stream>>>(A16, Bm16, lsrc2, ldst2,
        lub1 + l*128, lw2h + (size_t)l*16384, lub2 + l*128,
        lng + l*128, lnb + l*128, line);
    k_eu_mfma<<<NE/32, 256, 0, stream>>>(
        ew1h + (size_t)l*65536, eub1 + l*256,
        ew2h + (size_t)l*32768, eub2 + l*128,
        eng + l*128, enb + l*128, edge, line, base1, perm2);
    k_nu<256><<<NN/16, 256, 0, stream>>>(
        nuw1 + (size_t)l*256*256, nub1 + l*256, nuw2 + (size_t)l*256*128, nub2 + l*128,
        nng + l*128, nnb + l*128, node, edge, base2);
    k_qkv_split<<<NN*384/256, 256, 0, stream>>>(node, wqkv + (size_t)l*128*384, bqkv + l*384,
        Q, K4, V4);
    k_attn3<<<1024, 256, 0, stream>>>(Q, K4, V4, attno);
    k_wo<<<NN*DM/256, 256, 0, stream>>>(attno, wo + (size_t)l*128*128, bo + l*128, node);
  }

  k_readout<<<1, 256, 0, stream>>>(node, row1, rob1, row2, rob2, row3, rob3, (float*)d_out);
}

// Round 20
// 1927.282 us; speedup vs baseline: 1.0110x; 1.0110x over previous
//
#include <hip/hip_runtime.h>
#include <hip/hip_fp16.h>

// ALIGNN forward on MI355X. Round 20: packed-f16 adds in LU2 gather-fuse
// (A[src]+Bm[dst]+b1 via __hadd2; f32 only for silu). Round-19 baseline
// 1949us; k_lu2 115us x4 top (VALU 55%). Everything else = round 19.

#define NN 2048      // nodes
#define NE 131072    // edges
#define NL 524288    // line edges
#define DM 128       // feature dim

typedef unsigned short u16;
typedef unsigned int uint;
typedef __attribute__((ext_vector_type(8))) _Float16 f16x8;
typedef __attribute__((ext_vector_type(4))) float f32x4;

__device__ __forceinline__ float h2f(u16 u){ return __half2float(__ushort_as_half(u)); }
__device__ __forceinline__ u16 f2h(float f){ return __half_as_ushort(__float2half(f)); } // RNE
__device__ __forceinline__ uint pk2h(float a, float b){   // packed f32x2 -> f16x2 (RTZ)
  union { decltype(__builtin_amdgcn_cvt_pkrtz(0.f,0.f)) h2; uint u; } cv;
  cv.h2 = __builtin_amdgcn_cvt_pkrtz(a, b);
  return cv.u;
}
__device__ __forceinline__ float siluf(float x){ return x/(1.f+__expf(-x)); }
__device__ __forceinline__ float4 ld4(const float* p){ return *(const float4*)p; }
__device__ __forceinline__ void fma44(float (&a)[4], float4 x, float4 w0, float4 w1, float4 w2, float4 w3){
  a[0] += x.x*w0.x + x.y*w1.x + x.z*w2.x + x.w*w3.x;
  a[1] += x.x*w0.y + x.y*w1.y + x.z*w2.y + x.w*w3.y;
  a[2] += x.x*w0.z + x.y*w1.z + x.z*w2.z + x.w*w3.z;
  a[3] += x.x*w0.w + x.y*w1.w + x.z*w2.w + x.w*w3.w;
}

// ---------------- util ----------------

__global__ void k_zero2(int* __restrict__ a, int na, int* __restrict__ b, int nb){
  int i = blockIdx.x*256 + threadIdx.x;
  if (i < na) a[i] = 0;
  else if (i - na < nb) b[i - na] = 0;
}

__global__ void k_sentinel(float* out, float wsmb){ out[0] = 1000000.0f + wsmb; }

__global__ void k_einv(const int* __restrict__ perm2, int* __restrict__ einv, int n){
  int i = blockIdx.x*256 + threadIdx.x;
  if (i < n) einv[perm2[i]] = i;
}

__global__ void k_lidx2(const int* __restrict__ lsrc, const int* __restrict__ ldst,
                        const int* __restrict__ perm1, const int* __restrict__ einv,
                        int* __restrict__ lsrc2, int* __restrict__ ldst2, int n){
  int i = blockIdx.x*256 + threadIdx.x;
  if (i < n){
    int o = perm1[i];
    lsrc2[i] = einv[lsrc[o]];
    ldst2[i] = einv[ldst[o]];
  }
}

// ---------------- parallel 3-pass exclusive scan ----------------

__global__ __launch_bounds__(256) void k_scanp1(
    const int* __restrict__ inA, int* __restrict__ outA,
    const int* __restrict__ inB, int* __restrict__ outB,
    int* __restrict__ bsumA, int* __restrict__ bsumB){
  __shared__ int wsum[4];
  const int b = blockIdx.x, t = threadIdx.x;
  const int* in;  int* out;  int* bsum;  int base;
  if (b < 64){ in = inA; out = outA; bsum = bsumA + b; base = b*2048; }
  else       { in = inB; out = outB; bsum = bsumB;     base = 0; }
  int v[8];
  int s = 0;
  #pragma unroll
  for (int j=0;j<8;j++){ v[j] = in[base + t*8 + j]; s += v[j]; }
  const int lane = t & 63, wid = t >> 6;
  int x = s;
  #pragma unroll
  for (int off=1; off<64; off<<=1){
    int u = __shfl_up(x, off);
    if (lane >= off) x += u;
  }
  if (lane == 63) wsum[wid] = x;
  __syncthreads();
  int woff = 0;
  #pragma unroll
  for (int i=0;i<3;i++) if (i < wid) woff += wsum[i];
  int run = woff + x - s;
  #pragma unroll
  for (int j=0;j<8;j++){ out[base + t*8 + j] = run; run += v[j]; }
  if (t == 255) *bsum = woff + x;
}

__global__ void k_scanp2(int* __restrict__ bsumA, int* __restrict__ outA, int nA,
                         const int* __restrict__ bsumB, int* __restrict__ outB, int nB){
  __shared__ int sh[64];
  const int t = threadIdx.x;
  if (t < 64) sh[t] = bsumA[t];
  __syncthreads();
  if (t == 0){
    int run = 0;
    for (int i=0;i<64;i++){ int v = sh[i]; sh[i] = run; run += v; }
    outA[nA] = run;
    outB[nB] = bsumB[0];
  }
  __syncthreads();
  if (t < 64) bsumA[t] = sh[t];
}

__global__ __launch_bounds__(256) void k_scanp3(int* __restrict__ outA, const int* __restrict__ bsumA){
  const int b = blockIdx.x;
  const int off = bsumA[b];
  const int base = b*2048 + threadIdx.x*8;
  #pragma unroll
  for (int j=0;j<8;j++) outA[base+j] += off;
}

// all per-layer weight-fragment conversions in ONE dispatch (j-pair cols).
// EU W1 FOLDED: row r<128 = W1[r]+W1[r+128]; row r>=128 = W1[r+128].
__global__ void k_wfrag_all(const float* __restrict__ luw1, const float* __restrict__ luw2,
                            const float* __restrict__ euw1, const float* __restrict__ euw2,
                            u16* __restrict__ lw1h, u16* __restrict__ lw2h,
                            u16* __restrict__ ew1h, u16* __restrict__ ew2h){
  int l = blockIdx.x / 72, r = blockIdx.x % 72;
  const float* W; u16* out; int N, total, lb; bool fold = false;
  if (r < 16){      W = luw1 + (size_t)l*256*128; out = lw1h + (size_t)l*32768; N=128; total=4096;  lb = r; }
  else if (r < 24){ W = luw2 + (size_t)l*128*128; out = lw2h + (size_t)l*16384; N=128; total=2048;  lb = r-16; }
  else if (r < 56){ W = euw1 + (size_t)l*384*256; out = ew1h + (size_t)l*65536; N=256; total=8192;  lb = r-24; fold = true; }
  else {            W = euw2 + (size_t)l*256*128; out = ew2h + (size_t)l*32768; N=128; total=4096;  lb = r-56; }
  int i = lb*256 + threadIdx.x;
  if (i >= total) return;
  int lane = i & 63;
  int frag = i >> 6;
  int NT = N >> 4;
  int ntg = frag % NT;
  int kt = frag / NT;
  int half = NT >> 1;
  int colh = ntg / half, j = ntg % half;
  int col  = colh*(half<<4) + ((j>>1)<<5) + 2*(lane&15) + (j&1);
  int row0 = kt*32 + (lane>>4)*8;
  uint4 v; uint* vp = (uint*)&v;
  #pragma unroll
  for (int p=0;p<4;p++){
    int ra = row0+2*p, rb = row0+2*p+1;
    float fa, fb;
    if (fold){
      fa = (ra < 128) ? W[(size_t)ra*N + col] + W[(size_t)(ra+128)*N + col]
                      : W[(size_t)(ra+128)*N + col];
      fb = (rb < 128) ? W[(size_t)rb*N + col] + W[(size_t)(rb+128)*N + col]
                      : W[(size_t)(rb+128)*N + col];
    } else {
      fa = W[(size_t)ra*N + col];
      fb = W[(size_t)rb*N + col];
    }
    vp[p] = (uint)f2h(fa) | ((uint)f2h(fb)<<16);
  }
  *(uint4*)(out + (size_t)i*8) = v;
}

// rbf weights -> fragments: w1 [50][128] zero-padded to K=64; w2 [128][128].
__global__ void k_rbf_wfrag(const float* __restrict__ rw1, const float* __restrict__ rw2,
                            u16* __restrict__ w1p, u16* __restrict__ w2p){
  int r = blockIdx.x;
  const float* W; u16* out; int K, total;
  if (r < 4){ W = rw1; out = w1p; K = 50;  total = 1024; }
  else      { W = rw2; out = w2p; K = 128; total = 2048; r -= 4; }
  int i = r*256 + threadIdx.x;
  if (i >= total) return;
  int lane = i & 63, frag = i >> 6;
  int ntg = frag % 8, kt = frag / 8;
  int colh = ntg / 4, j = ntg % 4;
  int col  = colh*64 + ((j>>1)<<5) + 2*(lane&15) + (j&1);
  int row0 = kt*32 + (lane>>4)*8;
  uint4 v; uint* vp = (uint*)&v;
  #pragma unroll
  for (int p=0;p<4;p++){
    int ra = row0+2*p, rb = row0+2*p+1;
    u16 a = (ra < K) ? f2h(W[(size_t)ra*128 + col]) : (u16)0;
    u16 b = (rb < K) ? f2h(W[(size_t)rb*128 + col]) : (u16)0;
    vp[p] = (uint)a | ((uint)b<<16);
  }
  *(uint4*)(out + (size_t)i*8) = v;
}

// ---------------- init ----------------

__global__ void k_node_init(const int* __restrict__ an, const float* __restrict__ tab, float* __restrict__ node){
  int i = blockIdx.x*256 + threadIdx.x;          // NN*DM threads
  int n = i >> 7, d = i & 127;
  node[i] = tab[(an[n]-1)*DM + d];
}

__global__ void k_line_init(const float* __restrict__ ang, const float* __restrict__ w,
                            const float* __restrict__ b, const int* __restrict__ perm1,
                            u16* __restrict__ line){
  int i = blockIdx.x*256 + threadIdx.x;          // NL*64 threads (2 cols each)
  int r = i >> 6; int c2 = (i & 63)*2;
  float a = ang[perm1[r]];
  ushort2 v;
  v.x = f2h(a*w[c2  ] + b[c2  ]);
  v.y = f2h(a*w[c2+1] + b[c2+1]);
  ((ushort2*)line)[i] = v;
}

// MFMA edge embedding: 32 edges/block; rbf f16 [32][64-pad]; two MFMA GEMMs.
#define EB_RS 72    // 64+8 halves
#define EB_HS 136   // 128+8 halves

__global__ __launch_bounds__(256) void k_edge_embed2(
    const float* __restrict__ pos, const int* __restrict__ eidx,
    const int* __restrict__ eperm,
    const u16* __restrict__ W1p, const float* __restrict__ B1,
    const u16* __restrict__ W2p, const float* __restrict__ B2,
    u16* __restrict__ edge){
  __shared__ __align__(16) u16 rs[32*EB_RS];
  __shared__ __align__(16) u16 hs[32*EB_HS];
  __shared__ float dsh[32];
  const int t = threadIdx.x;
  const int e0 = blockIdx.x*32;
  if (t < 32){
    int eo = eperm[e0 + t];
    int s = eidx[eo], d = eidx[NE + eo];
    float dx = pos[d*3+0]-pos[s*3+0];
    float dy = pos[d*3+1]-pos[s*3+1];
    float dz = pos[d*3+2]-pos[s*3+2];
    dsh[t] = sqrtf(dx*dx+dy*dy+dz*dz);
  }
  __syncthreads();
  for (int q = t; q < 32*64; q += 256){
    int m = q >> 6, k = q & 63;
    float d = dsh[m];
    float v = 0.f;
    if (k < 50){
      float c = 8.0f*(float)k/49.0f;
      float g = __expf(-(d-c)*(d-c)*19.53125f);
      float cut = (d < 8.0f) ? 0.5f*(__cosf(d*0.39269908169872414f)+1.0f) : 0.0f;
      v = g*cut;
    }
    rs[m*EB_RS + k] = f2h(v);
  }
  __syncthreads();

  const int lane = t & 63, w = t >> 6;
  const int band = w >> 1, colh = w & 1;
  const int arow = band*16 + (lane & 15);
  const int kgrp = (lane >> 4)*8;
  const int q2 = 2*(lane & 15);

  {
    f32x4 acc[4];
    #pragma unroll
    for (int nt=0; nt<4; ++nt){
      float bv = B1[colh*64 + (nt>>1)*32 + q2 + (nt&1)];
      acc[nt][0]=bv; acc[nt][1]=bv; acc[nt][2]=bv; acc[nt][3]=bv;
    }
    #pragma unroll
    for (int kt=0; kt<2; ++kt){
      f16x8 a = *(const f16x8*)(rs + arow*EB_RS + kt*32 + kgrp);
      #pragma unroll
      for (int nt=0; nt<4; ++nt){
        int ntg = colh*4 + nt;
        f16x8 b = *(const f16x8*)(W1p + ((size_t)(kt*8 + ntg)*64 + lane)*8);
        acc[nt] = __builtin_amdgcn_mfma_f32_16x16x32_f16(a, b, acc[nt], 0, 0, 0);
      }
    }
    #pragma unroll
    for (int p=0; p<2; ++p){
      int colb = colh*64 + p*32 + q2;
      #pragma unroll
      for (int r=0; r<4; ++r){
        int row = band*16 + (lane>>4)*4 + r;
        *(uint*)(hs + row*EB_HS + colb) = pk2h(siluf(acc[2*p][r]), siluf(acc[2*p+1][r]));
      }
    }
  }
  __syncthreads();
  {
    f32x4 acc[4];
    #pragma unroll
    for (int nt=0; nt<4; ++nt){
      float bv = B2[colh*64 + (nt>>1)*32 + q2 + (nt&1)];
      acc[nt][0]=bv; acc[nt][1]=bv; acc[nt][2]=bv; acc[nt][3]=bv;
    }
    #pragma unroll
    for (int kt=0; kt<4; ++kt){
      f16x8 a = *(const f16x8*)(hs + arow*EB_HS + kt*32 + kgrp);
      #pragma unroll
      for (int nt=0; nt<4; ++nt){
        int ntg = colh*4 + nt;
        f16x8 b = *(const f16x8*)(W2p + ((size_t)(kt*8 + ntg)*64 + lane)*8);
        acc[nt] = __builtin_amdgcn_mfma_f32_16x16x32_f16(a, b, acc[nt], 0, 0, 0);
      }
    }
    #pragma unroll
    for (int p=0; p<2; ++p){
      int colb = colh*64 + p*32 + q2;
      #pragma unroll
      for (int r=0; r<4; ++r){
        int row = band*16 + (lane>>4)*4 + r;
        *(uint*)(edge + (size_t)(e0+row)*DM + colb) = pk2h(acc[2*p][r], acc[2*p+1][r]);
      }
    }
  }
}

// ---------------- CSR build (merged dispatches) ----------------

__global__ void k_hist2(const int* __restrict__ idxA, int* __restrict__ histA,
                        const int* __restrict__ idxB, int* __restrict__ histB, int nblkA){
  int t = threadIdx.x;
  if ((int)blockIdx.x < nblkA){
    int i = blockIdx.x*256 + t;
    atomicAdd(&histA[idxA[i]], 1);
  } else {
    int i = (blockIdx.x - nblkA)*256 + t;
    atomicAdd(&histB[idxB[i]], 1);
  }
}

__global__ void k_perm2k(const int* __restrict__ idxA, const int* __restrict__ baseA,
                         int* __restrict__ curA, int* __restrict__ permA,
                         const int* __restrict__ idxB, const int* __restrict__ baseB,
                         int* __restrict__ curB, int* __restrict__ permB, int nblkA){
  int t = threadIdx.x;
  if ((int)blockIdx.x < nblkA){
    int i = blockIdx.x*256 + t;
    int e = idxA[i];
    int p = atomicAdd(&curA[e], 1);
    permA[baseA[e] + p] = i;
  } else {
    int i = (blockIdx.x - nblkA)*256 + t;
    int e = idxB[i];
    int p = atomicAdd(&curB[e], 1);
    permB[baseB[e] + p] = i;
  }
}

// ---------------- LU precompute: A = edge@W1top, Bm = edge@W1bot ----------------

#define PE_XS 136

__global__ __launch_bounds__(256) void k_pre_lu(
    const u16* __restrict__ edge, const u16* __restrict__ W1h,
    u16* __restrict__ A16, u16* __restrict__ Bm16){
  __shared__ __align__(16) u16 xs[32*PE_XS];
  const int t = threadIdx.x;
  const int r0 = blockIdx.x*32;
  #pragma unroll
  for (int it=0; it<2; ++it){
    int idx = it*256 + t;
    int m = idx >> 4, c = idx & 15;
    uint4 v = *(const uint4*)(edge + (size_t)(r0+m)*DM + c*8);
    *(uint4*)(xs + m*PE_XS + c*8) = v;
  }
  __syncthreads();
  const int lane = t & 63, w = t >> 6;
  const int band = w >> 1, colh = w & 1;
  const int arow = band*16 + (lane & 15);
  const int kgrp = (lane >> 4)*8;
  const int q2 = 2*(lane & 15);
  #pragma unroll
  for (int half=0; half<2; ++half){
    f32x4 acc[4];
    #pragma unroll
    for (int nt=0; nt<4; ++nt){ acc[nt][0]=0.f; acc[nt][1]=0.f; acc[nt][2]=0.f; acc[nt][3]=0.f; }
    #pragma unroll
    for (int kt=0; kt<4; ++kt){
      f16x8 a = *(const f16x8*)(xs + arow*PE_XS + kt*32 + kgrp);
      #pragma unroll
      for (int nt=0; nt<4; ++nt){
        int ntg = colh*4 + nt;
        f16x8 b = *(const f16x8*)(W1h + ((size_t)((kt + half*4)*8 + ntg)*64 + lane)*8);
        acc[nt] = __builtin_amdgcn_mfma_f32_16x16x32_f16(a, b, acc[nt], 0, 0, 0);
      }
    }
    u16* out = half ? Bm16 : A16;
    #pragma unroll
    for (int p=0; p<2; ++p){
      int colb = colh*64 + p*32 + q2;
      #pragma unroll
      for (int r=0; r<4; ++r){
        int row = band*16 + (lane>>4)*4 + r;
        *(uint*)(out + (size_t)(r0+row)*DM + colb) = pk2h(acc[2*p][r], acc[2*p+1][r]);
      }
    }
  }
}

// ---------------- LU: h = silu(A[src]+Bm[dst]+b1); line = LN(line + h@W2+b2) ----------------

#define LU_HS 136   // halves (H overlay in smem)
#define LU_OS 132   // floats

__global__ __launch_bounds__(256) void k_lu2(
    const u16* __restrict__ A16, const u16* __restrict__ Bm16,
    const int* __restrict__ lsrc2, const int* __restrict__ ldst2,
    const float* __restrict__ B1,
    const u16* __restrict__ W2h, const float* __restrict__ B2,
    const float* __restrict__ lg, const float* __restrict__ lb,
    u16* __restrict__ line){
  __shared__ __align__(16) float smem[32*LU_OS];
  u16* hs = (u16*)smem;
  const int t = threadIdx.x;
  const int r0 = blockIdx.x*32;

  {                                              // gather-fuse: packed f16 adds
    int m = t >> 3, c8 = t & 7;
    int r = r0 + m;
    const u16* ap = A16  + (size_t)lsrc2[r]*DM;
    const u16* bp = Bm16 + (size_t)ldst2[r]*DM;
    #pragma unroll
    for (int cc0=0; cc0<2; ++cc0){
      int cc = c8 + cc0*8;
      uint4 av = *(const uint4*)(ap + cc*8);
      uint4 bv = *(const uint4*)(bp + cc*8);
      const __half2* ah = (const __half2*)&av;
      const __half2* bh = (const __half2*)&bv;
      uint outw[4];
      #pragma unroll
      for (int p=0;p<4;p++){
        int col = cc*8 + 2*p;
        __half2 b1v = __floats2half2_rn(B1[col], B1[col+1]);   // uniform, hoisted
        __half2 x2 = __hadd2(__hadd2(ah[p], bh[p]), b1v);
        float x0 = __half2float(__low2half(x2));
        float x1 = __half2float(__high2half(x2));
        outw[p] = pk2h(siluf(x0), siluf(x1));
      }
      *(uint4*)(hs + m*LU_HS + cc*8) = *(uint4*)outw;
    }
  }
  __syncthreads();

  const int lane = t & 63, w = t >> 6;
  const int band = w >> 1, colh = w & 1;
  const int arow = band*16 + (lane & 15);
  const int kgrp = (lane >> 4)*8;
  const int q2 = 2*(lane & 15);

  f32x4 acc[4];
  #pragma unroll
  for (int nt=0; nt<4; ++nt){
    float bv = B2[colh*64 + (nt>>1)*32 + q2 + (nt&1)];
    acc[nt][0]=bv; acc[nt][1]=bv; acc[nt][2]=bv; acc[nt][3]=bv;
  }
  #pragma unroll
  for (int kt=0; kt<4; ++kt){
    f16x8 a = *(const f16x8*)(hs + arow*LU_HS + kt*32 + kgrp);
    #pragma unroll
    for (int nt=0; nt<4; ++nt){
      int ntg = colh*4 + nt;
      f16x8 b = *(const f16x8*)(W2h + ((size_t)(kt*8 + ntg)*64 + lane)*8);
      acc[nt] = __builtin_amdgcn_mfma_f32_16x16x32_f16(a, b, acc[nt], 0, 0, 0);
    }
  }
  __syncthreads();
  #pragma unroll
  for (int p=0; p<2; ++p){
    int colb = colh*64 + p*32 + q2;
    #pragma unroll
    for (int r=0; r<4; ++r){
      int row = band*16 + (lane>>4)*4 + r;
      *(float2*)(smem + row*LU_OS + colb) = make_float2(acc[2*p][r], acc[2*p+1][r]);
    }
  }
  __syncthreads();
  {
    const float* outp = (const float*)smem;
    int row = t >> 3, li = t & 7;
    size_t rb = (size_t)(r0 + row)*DM;
    uint rw[8];
    *(uint4*)&rw[0] = *(const uint4*)(line + rb + li*16);
    *(uint4*)&rw[4] = *(const uint4*)(line + rb + li*16 + 8);
    float x[16];
    float s=0.f, q=0.f;
    #pragma unroll
    for (int j=0;j<16;j++){
      float res = h2f((u16)((j&1) ? (rw[j>>1]>>16) : (rw[j>>1]&0xffffu)));
      x[j] = outp[row*LU_OS + li*16 + j] + res;
      s += x[j]; q += x[j]*x[j];
    }
    #pragma unroll
    for (int off=1; off<8; off<<=1){ s += __shfl_xor(s,off); q += __shfl_xor(q,off); }
    float mean = s*(1.f/128.f);
    float rstd = rsqrtf(fmaxf(q*(1.f/128.f) - mean*mean, 0.f) + 1e-5f);
    #pragma unroll
    for (int half=0; half<2; ++half){
      uint4 wv; uint* wp = (uint*)&wv;
      #pragma unroll
      for (int p=0;p<4;p++){
        int j = half*8 + 2*p;
        int c0 = li*16 + j;
        wp[p] = pk2h((x[j  ]-mean)*rstd*lg[c0  ] + lb[c0  ],
                     (x[j+1]-mean)*rstd*lg[c0+1] + lb[c0+1]);
      }
      *(uint4*)(line + rb + li*16 + half*8) = wv;
    }
  }
}

// ---------------- MFMA edge update (FOLDED W1: K=256) ----------------

#define EU_XS 264   // 256+8 halves
#define EU_HS 264   // 256+8 halves
#define EU_OS 132   // 128+4 floats

__global__ __launch_bounds__(256) void k_eu_mfma(
    const u16* __restrict__ W1h, const float* __restrict__ B1,
    const u16* __restrict__ W2h, const float* __restrict__ B2,
    const float* __restrict__ g, const float* __restrict__ bb,
    u16* __restrict__ edge, const u16* __restrict__ line,
    const int* __restrict__ lbase, const int* __restrict__ eperm){
  __shared__ __align__(16) u16 xs[32*EU_XS];
  __shared__ __align__(16) u16 hs[32*EU_HS];
  const int t = threadIdx.x;
  const int r0 = blockIdx.x*32;

  for (int it=0; it<2; ++it){
    int idx = it*256 + t;
    int m = idx >> 4, c = idx & 15;
    uint4 v = *(const uint4*)(edge + (size_t)(r0+m)*DM + c*8);
    *(uint4*)(xs + m*EU_XS + c*8) = v;
  }
  {
    int m = t >> 3, c0 = (t & 7)*16;
    int eo = eperm[r0 + m];
    int b0 = lbase[eo], b1 = lbase[eo+1];
    float s[16];
    #pragma unroll
    for (int k=0;k<16;k++) s[k]=0.f;
    for (int j=b0;j<b1;++j){
      const u16* lp = line + (size_t)j*DM + c0;
      uint rw[8];
      *(uint4*)&rw[0] = *(const uint4*)lp;
      *(uint4*)&rw[4] = *(const uint4*)(lp + 8);
      #pragma unroll
      for (int k=0;k<16;k++)
        s[k] += h2f((u16)((k&1) ? (rw[k>>1]>>16) : (rw[k>>1]&0xffffu)));
    }
    int n = b1 - b0;
    float inv = 1.f/(float)(n > 0 ? n : 1);
    #pragma unroll
    for (int half=0; half<2; ++half){
      uint4 wv; uint* wp = (uint*)&wv;
      #pragma unroll
      for (int p=0;p<4;p++){
        int k = half*8 + 2*p;
        wp[p] = pk2h(s[k]*inv, s[k+1]*inv);
      }
      *(uint4*)(xs + m*EU_XS + 128 + c0 + half*8) = wv;
    }
  }
  __syncthreads();

  const int lane = t & 63, w = t >> 6;
  const int band = w >> 1, colh = w & 1;
  const int arow = band*16 + (lane & 15);
  const int kgrp = (lane >> 4)*8;
  const int q2 = 2*(lane & 15);

  {
    f32x4 acc[8];
    #pragma unroll
    for (int nt=0; nt<8; ++nt){
      float bv = B1[colh*128 + (nt>>1)*32 + q2 + (nt&1)];
      acc[nt][0]=bv; acc[nt][1]=bv; acc[nt][2]=bv; acc[nt][3]=bv;
    }
    #pragma unroll
    for (int kt=0; kt<8; ++kt){
      f16x8 a = *(const f16x8*)(xs + arow*EU_XS + kt*32 + kgrp);
      #pragma unroll
      for (int nt=0; nt<8; ++nt){
        int ntg = colh*8 + nt;
        f16x8 b = *(const f16x8*)(W1h + ((size_t)(kt*16 + ntg)*64 + lane)*8);
        acc[nt] = __builtin_amdgcn_mfma_f32_16x16x32_f16(a, b, acc[nt], 0, 0, 0);
      }
    }
    #pragma unroll
    for (int p=0; p<4; ++p){
      int colb = colh*128 + p*32 + q2;
      #pragma unroll
      for (int r=0; r<4; ++r){
        int row = band*16 + (lane>>4)*4 + r;
        *(uint*)(hs + row*EU_HS + colb) = pk2h(siluf(acc[2*p][r]), siluf(acc[2*p+1][r]));
      }
    }
  }
  __syncthreads();
  {
    f32x4 acc[4];
    #pragma unroll
    for (int nt=0; nt<4; ++nt){
      float bv = B2[colh*64 + (nt>>1)*32 + q2 + (nt&1)];
      acc[nt][0]=bv; acc[nt][1]=bv; acc[nt][2]=bv; acc[nt][3]=bv;
    }
    #pragma unroll
    for (int kt=0; kt<8; ++kt){
      f16x8 a = *(const f16x8*)(hs + arow*EU_HS + kt*32 + kgrp);
      #pragma unroll
      for (int nt=0; nt<4; ++nt){
        int ntg = colh*4 + nt;
        f16x8 b = *(const f16x8*)(W2h + ((size_t)(kt*8 + ntg)*64 + lane)*8);
        acc[nt] = __builtin_amdgcn_mfma_f32_16x16x32_f16(a, b, acc[nt], 0, 0, 0);
      }
    }
    float* outp = (float*)xs;
    #pragma unroll
    for (int p=0; p<2; ++p){
      int colb = colh*64 + p*32 + q2;
      #pragma unroll
      for (int r=0; r<4; ++r){
        int row = band*16 + (lane>>4)*4 + r;
        *(float2*)(outp + row*EU_OS + colb) = make_float2(acc[2*p][r], acc[2*p+1][r]);
      }
    }
  }
  __syncthreads();
  {
    const float* outp = (const float*)xs;
    int row = t >> 3, li = t & 7;
    size_t rb = (size_t)(r0 + row)*DM;
    uint rw[8];
    *(uint4*)&rw[0] = *(const uint4*)(edge + rb + li*16);
    *(uint4*)&rw[4] = *(const uint4*)(edge + rb + li*16 + 8);
    float x[16];
    float s=0.f, q=0.f;
    #pragma unroll
    for (int j=0;j<16;j++){
      float res = h2f((u16)((j&1) ? (rw[j>>1]>>16) : (rw[j>>1]&0xffffu)));
      x[j] = outp[row*EU_OS + li*16 + j] + res;
      s += x[j]; q += x[j]*x[j];
    }
    #pragma unroll
    for (int off=1; off<8; off<<=1){ s += __shfl_xor(s,off); q += __shfl_xor(q,off); }
    float mean = s*(1.f/128.f);
    float rstd = rsqrtf(fmaxf(q*(1.f/128.f) - mean*mean, 0.f) + 1e-5f);
    #pragma unroll
    for (int half=0; half<2; ++half){
      uint4 wv; uint* wp = (uint*)&wv;
      #pragma unroll
      for (int p=0;p<4;p++){
        int j = half*8 + 2*p;
        int c0 = li*16 + j;
        wp[p] = pk2h((x[j  ]-mean)*rstd*g[c0  ] + bb[c0  ],
                     (x[j+1]-mean)*rstd*g[c0+1] + bb[c0+1]);
      }
      *(uint4*)(edge + rb + li*16 + half*8) = wv;
    }
  }
}

// ---------------- NU: fused 16-row MLP+LN (contiguous naggr walk) ----------------

template<int KIN>
__global__ __launch_bounds__(256) void k_nu(
    const float* __restrict__ W1, const float* __restrict__ B1,
    const float* __restrict__ W2, const float* __restrict__ B2,
    const float* __restrict__ g, const float* __restrict__ bb,
    float* __restrict__ node_io, const u16* __restrict__ edge,
    const int* __restrict__ nbase){
  __shared__ __align__(16) float xsf[16*KIN];
  __shared__ __align__(16) float hsf[16*256];
  const int t = threadIdx.x;
  const int r0 = blockIdx.x*16;

  {
    int m = t >> 4, c0 = (t & 15)*8;
    int n = r0 + m;
    float4 a = ld4(node_io + (size_t)n*DM + c0);
    float4 b = ld4(node_io + (size_t)n*DM + c0 + 4);
    float* xd = &xsf[m*KIN + c0];
    xd[0]=a.x; xd[1]=a.y; xd[2]=a.z; xd[3]=a.w;
    xd[4]=b.x; xd[5]=b.y; xd[6]=b.z; xd[7]=b.w;
    int b0 = nbase[n], b1e = nbase[n+1];
    float s[8];
    #pragma unroll
    for (int k=0;k<8;k++) s[k]=0.f;
    for (int j=b0;j<b1e;++j){
      uint4 v = *(const uint4*)(edge + (size_t)j*DM + c0);
      s[0]+=h2f((u16)(v.x&0xffff)); s[1]+=h2f((u16)(v.x>>16));
      s[2]+=h2f((u16)(v.y&0xffff)); s[3]+=h2f((u16)(v.y>>16));
      s[4]+=h2f((u16)(v.z&0xffff)); s[5]+=h2f((u16)(v.z>>16));
      s[6]+=h2f((u16)(v.w&0xffff)); s[7]+=h2f((u16)(v.w>>16));
    }
    int nn = b1e - b0;
    float inv = 1.f/(float)(nn > 0 ? nn : 1);
    #pragma unroll
    for (int k=0;k<8;k++) xsf[m*KIN + 128 + c0 + k] = s[k]*inv;
  }
  __syncthreads();
  {
    const int c4 = (t & 63)*4, mg = t >> 6;
    float acc[4][4];
    float4 bv = ld4(B1 + c4);
    #pragma unroll
    for (int i=0;i<4;i++){ acc[i][0]=bv.x; acc[i][1]=bv.y; acc[i][2]=bv.z; acc[i][3]=bv.w; }
    for (int k=0;k<KIN;k+=4){
      float4 w0 = ld4(W1 + (k  )*256 + c4);
      float4 w1 = ld4(W1 + (k+1)*256 + c4);
      float4 w2 = ld4(W1 + (k+2)*256 + c4);
      float4 w3 = ld4(W1 + (k+3)*256 + c4);
      #pragma unroll
      for (int i=0;i<4;i++){
        float4 x = *(const float4*)&xsf[(mg*4+i)*KIN + k];
        fma44(acc[i], x, w0, w1, w2, w3);
      }
    }
    #pragma unroll
    for (int i=0;i<4;i++)
      #pragma unroll
      for (int j=0;j<4;j++)
        hsf[(mg*4+i)*256 + c4 + j] = siluf(acc[i][j]);
  }
  __syncthreads();
  const int c4b = (t & 31)*4, mgb = t >> 5;
  float acc2[2][4];
  {
    float4 bv = ld4(B2 + c4b);
    #pragma unroll
    for (int i=0;i<2;i++){ acc2[i][0]=bv.x; acc2[i][1]=bv.y; acc2[i][2]=bv.z; acc2[i][3]=bv.w; }
    for (int k=0;k<256;k+=4){
      float4 w0 = ld4(W2 + (k  )*128 + c4b);
      float4 w1 = ld4(W2 + (k+1)*128 + c4b);
      float4 w2 = ld4(W2 + (k+2)*128 + c4b);
      float4 w3 = ld4(W2 + (k+3)*128 + c4b);
      #pragma unroll
      for (int i=0;i<2;i++){
        float4 x = *(const float4*)&hsf[(mgb*2+i)*256 + k];
        fma44(acc2[i], x, w0, w1, w2, w3);
      }
    }
  }
  __syncthreads();
  #pragma unroll
  for (int i=0;i<2;i++){
    int m = mgb*2 + i;
    #pragma unroll
    for (int j=0;j<4;j++)
      hsf[m*128 + c4b + j] = acc2[i][j] + xsf[m*KIN + c4b + j];
  }
  __syncthreads();
  {
    int row = t >> 4, li = t & 15;
    const float* o = &hsf[row*128];
    float s=0.f, q=0.f;
    #pragma unroll
    for (int j=0;j<8;j++){ float x = o[li*8+j]; s += x; q += x*x; }
    #pragma unroll
    for (int off=1; off<16; off<<=1){ s += __shfl_xor(s,off); q += __shfl_xor(q,off); }
    float mean = s*(1.f/128.f);
    float rstd = rsqrtf(fmaxf(q*(1.f/128.f) - mean*mean, 0.f) + 1e-5f);
    size_t rb = (size_t)(r0 + row)*DM;
    #pragma unroll
    for (int j=0;j<8;j++){
      int c = li*8 + j;
      node_io[rb + c] = (o[c]-mean)*rstd*g[c] + bb[c];
    }
  }
}

// ---------------- attention ----------------

__global__ void k_qkv_split(const float* __restrict__ node, const float* __restrict__ W,
                            const float* __restrict__ B, float* __restrict__ Q,
                            u16* __restrict__ K4, u16* __restrict__ V4){
  int i = blockIdx.x*256 + threadIdx.x;          // NN*384 threads
  int n = i / 384, c = i % 384;
  float acc = B[c];
  const float* nr = node + (size_t)n*DM;
  for (int k=0;k<128;k+=4){
    acc += nr[k  ]*W[(k  )*384+c];
    acc += nr[k+1]*W[(k+1)*384+c];
    acc += nr[k+2]*W[(k+2)*384+c];
    acc += nr[k+3]*W[(k+3)*384+c];
  }
  if (c < 128){
    Q[(size_t)n*128 + c] = acc;
  } else if (c < 256){
    int h = (c-128) >> 5, d = (c-128) & 31;
    K4[((size_t)h*NN + n)*32 + d] = f2h(acc);
  } else {
    int h = (c-256) >> 5, d = (c-256) & 31;
    V4[((size_t)h*NN + n)*32 + d] = f2h(acc);
  }
}

// 4 waves = 8 queries x 1 head; 128-key f16 tiles, double-buffered LDS
#define AT_TK 128
#define AT_RU 17

__global__ __launch_bounds__(256) void k_attn3(
    const float* __restrict__ Q, const u16* __restrict__ K4,
    const u16* __restrict__ V4, float* __restrict__ attno){
  __shared__ uint kls[2][AT_TK*AT_RU];
  __shared__ uint vls[2][AT_TK*AT_RU];
  const int t = threadIdx.x, lane = t & 63;
  const int h = blockIdx.x >> 8;
  const int q0 = (blockIdx.x & 255)*8 + (t >> 6)*2;
  const float scale = 0.17677669529663687f;
  const uint* Kg = (const uint*)(K4 + (size_t)h*NN*32);
  const uint* Vg = (const uint*)(V4 + (size_t)h*NN*32);
  const int ca = t*2, cb = t*2+1;
  const int ka_ = ca>>2, pa_ = (ca&3)*4;
  const int kb_ = cb>>2, pb_ = (cb&3)*4;
  uint4 kr0, kr1, vr0, vr1;

  float q[2][32];
  #pragma unroll
  for (int j=0;j<2;j++){
    const float* qr = Q + (size_t)(q0+j)*128 + h*32;
    #pragma unroll
    for (int d=0;d<32;d+=4){
      float4 v = *(const float4*)(qr + d);
      q[j][d]=v.x*scale; q[j][d+1]=v.y*scale; q[j][d+2]=v.z*scale; q[j][d+3]=v.w*scale;
    }
  }
  float mx = -1e30f, s0 = 0.f, s1 = 0.f;
  float o0[32], o1[32];
  #pragma unroll
  for (int d=0;d<32;d++){ o0[d]=0.f; o1[d]=0.f; }

  {
    const uint* kg = Kg; const uint* vg = Vg;
    kr0 = *(const uint4*)(kg + ca*4); kr1 = *(const uint4*)(kg + cb*4);
    vr0 = *(const uint4*)(vg + ca*4); vr1 = *(const uint4*)(vg + cb*4);
    uint* kd = kls[0]; uint* vd = vls[0];
    kd[ka_*AT_RU+pa_  ]=kr0.x; kd[ka_*AT_RU+pa_+1]=kr0.y; kd[ka_*AT_RU+pa_+2]=kr0.z; kd[ka_*AT_RU+pa_+3]=kr0.w;
    kd[kb_*AT_RU+pb_  ]=kr1.x; kd[kb_*AT_RU+pb_+1]=kr1.y; kd[kb_*AT_RU+pb_+2]=kr1.z; kd[kb_*AT_RU+pb_+3]=kr1.w;
    vd[ka_*AT_RU+pa_  ]=vr0.x; vd[ka_*AT_RU+pa_+1]=vr0.y; vd[ka_*AT_RU+pa_+2]=vr0.z; vd[ka_*AT_RU+pa_+3]=vr0.w;
    vd[kb_*AT_RU+pb_  ]=vr1.x; vd[kb_*AT_RU+pb_+1]=vr1.y; vd[kb_*AT_RU+pb_+2]=vr1.z; vd[kb_*AT_RU+pb_+3]=vr1.w;
  }
  __syncthreads();

  const int NT = NN / AT_TK;
  for (int kt=0; kt<NT; ++kt){
    if (kt+1 < NT){
      const uint* kg = Kg + (size_t)(kt+1)*AT_TK*16;
      const uint* vg = Vg + (size_t)(kt+1)*AT_TK*16;
      kr0 = *(const uint4*)(kg + ca*4); kr1 = *(const uint4*)(kg + cb*4);
      vr0 = *(const uint4*)(vg + ca*4); vr1 = *(const uint4*)(vg + cb*4);
    }
    {
      const uint* kb = kls[kt&1];
      const uint* vb = vls[kt&1];
      #pragma unroll
      for (int half=0; half<2; ++half){
        int key = lane + half*64;
        const uint* kr = kb + key*AT_RU;
        float d0=0.f, d1=0.f;
        #pragma unroll
        for (int u=0;u<16;u++){
          uint w = kr[u];
          float a = h2f((u16)(w&0xffffu)), b2 = h2f((u16)(w>>16));
          d0 += q[0][2*u]*a + q[0][2*u+1]*b2;
          d1 += q[1][2*u]*a + q[1][2*u+1]*b2;
        }
        float nm = fmaxf(mx, fmaxf(d0,d1));
        float r  = __expf(mx - nm);
        float e0 = __expf(d0 - nm), e1 = __expf(d1 - nm);
        s0 = s0*r + e0;
        s1 = s1*r + e1;
        mx = nm;
        const uint* vr = vb + key*AT_RU;
        #pragma unroll
        for (int u=0;u<16;u++){
          uint w = vr[u];
          float a = h2f((u16)(w&0xffffu)), b2 = h2f((u16)(w>>16));
          o0[2*u  ] = o0[2*u  ]*r + e0*a;  o1[2*u  ] = o1[2*u  ]*r + e1*a;
          o0[2*u+1] = o0[2*u+1]*r + e0*b2; o1[2*u+1] = o1[2*u+1]*r + e1*b2;
        }
      }
    }
    __syncthreads();
    if (kt+1 < NT){
      uint* kd = kls[(kt+1)&1]; uint* vd = vls[(kt+1)&1];
      kd[ka_*AT_RU+pa_  ]=kr0.x; kd[ka_*AT_RU+pa_+1]=kr0.y; kd[ka_*AT_RU+pa_+2]=kr0.z; kd[ka_*AT_RU+pa_+3]=kr0.w;
      kd[kb_*AT_RU+pb_  ]=kr1.x; kd[kb_*AT_RU+pb_+1]=kr1.y; kd[kb_*AT_RU+pb_+2]=kr1.z; kd[kb_*AT_RU+pb_+3]=kr1.w;
      vd[ka_*AT_RU+pa_  ]=vr0.x; vd[ka_*AT_RU+pa_+1]=vr0.y; vd[ka_*AT_RU+pa_+2]=vr0.z; vd[ka_*AT_RU+pa_+3]=vr0.w;
      vd[kb_*AT_RU+pb_  ]=vr1.x; vd[kb_*AT_RU+pb_+1]=vr1.y; vd[kb_*AT_RU+pb_+2]=vr1.z; vd[kb_*AT_RU+pb_+3]=vr1.w;
      __syncthreads();
    }
  }

  #pragma unroll
  for (int off=1; off<64; off<<=1){
    float m2  = __shfl_xor(mx, off);
    float s02 = __shfl_xor(s0, off);
    float s12 = __shfl_xor(s1, off);
    float nm = fmaxf(mx, m2);
    float ra = __expf(mx - nm), rb = __expf(m2 - nm);
    s0 = s0*ra + s02*rb;
    s1 = s1*ra + s12*rb;
    #pragma unroll
    for (int d=0;d<32;d++){
      float a0 = __shfl_xor(o0[d], off);
      float a1 = __shfl_xor(o1[d], off);
      o0[d] = o0[d]*ra + a0*rb;
      o1[d] = o1[d]*ra + a1*rb;
    }
    mx = nm;
  }
  float inv0 = 1.f/s0, inv1 = 1.f/s1;
  if (lane == 0){
    #pragma unroll
    for (int d=0;d<32;d++){
      attno[(size_t)(q0  )*DM + h*32 + d] = o0[d]*inv0;
      attno[(size_t)(q0+1)*DM + h*32 + d] = o1[d]*inv1;
    }
  }
}

__global__ void k_wo(const float* __restrict__ attno, const float* __restrict__ W,
                     const float* __restrict__ B, float* __restrict__ node){
  int i = blockIdx.x*256 + threadIdx.x;          // NN*DM
  int n = i >> 7, c = i & 127;
  float acc = B[c];
  const float* ar = attno + (size_t)n*DM;
  for (int k=0;k<128;k+=4){
    acc += ar[k  ]*W[(k  )*128+c];
    acc += ar[k+1]*W[(k+1)*128+c];
    acc += ar[k+2]*W[(k+2)*128+c];
    acc += ar[k+3]*W[(k+3)*128+c];
  }
  node[i] = acc;
}

// ---------------- readout ----------------

__global__ __launch_bounds__(256) void k_readout(
    const float* __restrict__ node,
    const float* __restrict__ w1, const float* __restrict__ b1,
    const float* __restrict__ w2, const float* __restrict__ b2,
    const float* __restrict__ w3, const float* __restrict__ b3,
    float* __restrict__ out){
  __shared__ float gs[128], h1[128], h2[64];
  const int t = threadIdx.x;
  if (t < 128){
    float s = 0.f;
    for (int r=0;r<NN;r++) s += node[(size_t)r*DM + t];
    gs[t] = s*(1.f/2048.f);
  }
  __syncthreads();
  if (t < 128){
    float acc = b1[t];
    for (int k=0;k<128;k++) acc += gs[k]*w1[k*128+t];
    h1[t] = siluf(acc);
  }
  __syncthreads();
  if (t < 64){
    float acc = b2[t];
    for (int k=0;k<128;k++) acc += h1[k]*w2[k*64+t];
    h2[t] = siluf(acc);
  }
  __syncthreads();
  if (t == 0){
    float acc = b3[0];
    for (int k=0;k<64;k++) acc += h2[k]*w3[k];
    out[0] = acc;                                // f32 output
  }
}

// ---------------- host launch ----------------

extern "C" void kernel_launch(void* const* d_in, const int* in_sizes, int n_in,
                              void* d_out, int out_size, void* d_ws, size_t ws_size,
                              hipStream_t stream) {
  (void)in_sizes; (void)n_in; (void)out_size;
  const int*   an    = (const int*)  d_in[0];
  const float* pos   = (const float*)d_in[1];
  const int*   eidx  = (const int*)  d_in[2];
  const int*   lidx  = (const int*)  d_in[3];
  const float* lang  = (const float*)d_in[4];
  const float* atab  = (const float*)d_in[5];
  const float* rw1   = (const float*)d_in[6];
  const float* rb1   = (const float*)d_in[7];
  const float* rw2   = (const float*)d_in[8];
  const float* rb2   = (const float*)d_in[9];
  const float* lew   = (const float*)d_in[10];
  const float* leb   = (const float*)d_in[11];
  const float* euw1  = (const float*)d_in[12];
  const float* eub1  = (const float*)d_in[13];
  const float* euw2  = (const float*)d_in[14];
  const float* eub2  = (const float*)d_in[15];
  const float* luw1  = (const float*)d_in[16];
  const float* lub1  = (const float*)d_in[17];
  const float* luw2  = (const float*)d_in[18];
  const float* lub2  = (const float*)d_in[19];
  const float* nuw1  = (const float*)d_in[20];
  const float* nub1  = (const float*)d_in[21];
  const float* nuw2  = (const float*)d_in[22];
  const float* nub2  = (const float*)d_in[23];
  const float* wqkv  = (const float*)d_in[24];
  const float* bqkv  = (const float*)d_in[25];
  const float* wo    = (const float*)d_in[26];
  const float* bo    = (const float*)d_in[27];
  const float* nng   = (const float*)d_in[28];
  const float* nnb   = (const float*)d_in[29];
  const float* eng   = (const float*)d_in[30];
  const float* enb   = (const float*)d_in[31];
  const float* lng   = (const float*)d_in[32];
  const float* lnb   = (const float*)d_in[33];
  const float* row1  = (const float*)d_in[34];
  const float* rob1  = (const float*)d_in[35];
  const float* row2  = (const float*)d_in[36];
  const float* rob2  = (const float*)d_in[37];
  const float* row3  = (const float*)d_in[38];
  const float* rob3  = (const float*)d_in[39];

  // workspace layout (~247 MB; sentinel reveals ws_MB if short)
  char* p = (char*)d_ws;
  auto bump = [&](size_t bytes)->char*{ char* q = p; p += (bytes + 255) & ~(size_t)255; return q; };
  float* node  = (float*)bump((size_t)NN*DM*4);
  float* Q     = (float*)bump((size_t)NN*128*4);
  u16*   K4    = (u16*)  bump((size_t)4*NN*32*2);
  u16*   V4    = (u16*)  bump((size_t)4*NN*32*2);
  float* attno = (float*)bump((size_t)NN*DM*4);
  u16*   edge  = (u16*)  bump((size_t)NE*DM*2);     // perm2 (dst-sorted) order
  u16*   line  = (u16*)  bump((size_t)NL*DM*2);     // perm1 (ldst-sorted) order
  u16*   A16   = (u16*)  bump((size_t)NE*DM*2);
  u16*   Bm16  = (u16*)  bump((size_t)NE*DM*2);
  int*   base1 = (int*)  bump((size_t)(NE+1)*4);
  int*   base2 = (int*)  bump((size_t)(NN+1)*4);
  int*   cur1  = (int*)  bump((size_t)NE*4);
  int*   cur2  = (int*)  bump((size_t)NN*4);
  int*   perm1 = (int*)  bump((size_t)NL*4);
  int*   perm2 = (int*)  bump((size_t)NE*4);
  int*   einv  = (int*)  bump((size_t)NE*4);
  int*   lsrc2 = (int*)  bump((size_t)NL*4);
  int*   ldst2 = (int*)  bump((size_t)NL*4);
  int*   bsumA = (int*)  bump((size_t)64*4);
  int*   bsumB = (int*)  bump((size_t)4);
  u16*   lw1h  = (u16*)  bump((size_t)4*32768*2);
  u16*   lw2h  = (u16*)  bump((size_t)4*16384*2);
  u16*   ew1h  = (u16*)  bump((size_t)4*65536*2);   // FOLDED EU W1 (256x256)
  u16*   ew2h  = (u16*)  bump((size_t)4*32768*2);
  u16*   rw1p  = (u16*)  bump((size_t)8192*2);
  u16*   rw2p  = (u16*)  bump((size_t)16384*2);
  size_t needed = (size_t)(p - (char*)d_ws);
  if (needed > ws_size){
    k_sentinel<<<1, 1, 0, stream>>>((float*)d_out, (float)(ws_size >> 20));
    return;
  }

  const int* lsrc = lidx;
  const int* ldst = lidx + NL;
  const int* dst  = eidx + NE;

  // CSR builds (merged dispatches; index structure is layer-invariant)
  const int nblkA = NL/256, nblkB = NE/256;
  k_zero2<<<(NE+NN+255)/256, 256, 0, stream>>>(cur1, NE, cur2, NN);
  k_hist2<<<nblkA+nblkB, 256, 0, stream>>>(ldst, cur1, dst, cur2, nblkA);
  k_scanp1<<<65, 256, 0, stream>>>(cur1, base1, cur2, base2, bsumA, bsumB);
  k_scanp2<<<1, 64, 0, stream>>>(bsumA, base1, NE, bsumB, base2, NN);
  k_scanp3<<<64, 256, 0, stream>>>(base1, bsumA);
  k_zero2<<<(NE+NN+255)/256, 256, 0, stream>>>(cur1, NE, cur2, NN);
  k_perm2k<<<nblkA+nblkB, 256, 0, stream>>>(ldst, base1, cur1, perm1,
                                            dst,  base2, cur2, perm2, nblkA);
  k_einv<<<(NE+255)/256, 256, 0, stream>>>(perm2, einv, NE);
  k_lidx2<<<(NL+255)/256, 256, 0, stream>>>(lsrc, ldst, perm1, einv, lsrc2, ldst2, NL);

  // weight fragment conversion (72 blocks/layer; EU W1 folded)
  k_wfrag_all<<<4*72, 256, 0, stream>>>(luw1, luw2, euw1, euw2, lw1h, lw2h, ew1h, ew2h);
  k_rbf_wfrag<<<12, 256, 0, stream>>>(rw1, rw2, rw1p, rw2p);

  // embeddings (sorted storage orders)
  k_node_init<<<NN*DM/256, 256, 0, stream>>>(an, atab, node);
  k_line_init<<<NL*64/256, 256, 0, stream>>>(lang, lew, leb, perm1, line);
  k_edge_embed2<<<NE/32, 256, 0, stream>>>(pos, eidx, perm2, rw1p, rb1, rw2p, rb2, edge);

  for (int l=0; l<4; ++l){
    k_pre_lu<<<NE/32, 256, 0, stream>>>(edge, lw1h + (size_t)l*32768, A16, Bm16);
    k_lu2<<<NL/32, 256, 0, stream>>>(A16, Bm16, lsrc2, ldst2,
        lub1 + l*128, lw2h + (size_t)l*16384, lub2 + l*128,
        lng + l*128, lnb + l*128, line);
    k_eu_mfma<<<NE/32, 256, 0, stream>>>(
        ew1h + (size_t)l*65536, eub1 + l*256,
        ew2h + (size_t)l*32768, eub2 + l*128,
        eng + l*128, enb + l*128, edge, line, base1, perm2);
    k_nu<256><<<NN/16, 256, 0, stream>>>(
        nuw1 + (size_t)l*256*256, nub1 + l*256, nuw2 + (size_t)l*256*128, nub2 + l*128,
        nng + l*128, nnb + l*128, node, edge, base2);
    k_qkv_split<<<NN*384/256, 256, 0, stream>>>(node, wqkv + (size_t)l*128*384, bqkv + l*384,
        Q, K4, V4);
    k_attn3<<<1024, 256, 0, stream>>>(Q, K4, V4, attno);
    k_wo<<<NN*DM/256, 256, 0, stream>>>(attno, wo + (size_t)l*128*128, bo + l*128, node);
  }

  k_readout<<<1, 256, 0, stream>>>(node, row1, rob1, row2, rob2, row3, rob3, (float*)d_out);
}

// Round 21
// 1833.750 us; speedup vs baseline: 1.0626x; 1.0510x over previous
//
#include <hip/hip_runtime.h>
#include <hip/hip_fp16.h>

// ALIGNN forward on MI355X. Round 21: attn3 VALU diet — fdot2 (v_dot2_f32_f16)
// for QK^T with pre-packed f16 Q, and merged-half rescale (one exp/rescale per
// 2 keys, fused PV). Round-20 baseline 1927us; k_attn3 112us x4 (VALU 55%,
// Mfma 0, HBM 0.7%). Everything else identical to round 20.

#define NN 2048      // nodes
#define NE 131072    // edges
#define NL 524288    // line edges
#define DM 128       // feature dim

typedef unsigned short u16;
typedef unsigned int uint;
typedef __attribute__((ext_vector_type(8))) _Float16 f16x8;
typedef __attribute__((ext_vector_type(2))) _Float16 f16x2;
typedef __attribute__((ext_vector_type(4))) float f32x4;

__device__ __forceinline__ float h2f(u16 u){ return __half2float(__ushort_as_half(u)); }
__device__ __forceinline__ u16 f2h(float f){ return __half_as_ushort(__float2half(f)); } // RNE
__device__ __forceinline__ uint pk2h(float a, float b){   // packed f32x2 -> f16x2 (RTZ)
  union { decltype(__builtin_amdgcn_cvt_pkrtz(0.f,0.f)) h2; uint u; } cv;
  cv.h2 = __builtin_amdgcn_cvt_pkrtz(a, b);
  return cv.u;
}
__device__ __forceinline__ float siluf(float x){ return x/(1.f+__expf(-x)); }
__device__ __forceinline__ float4 ld4(const float* p){ return *(const float4*)p; }
__device__ __forceinline__ void fma44(float (&a)[4], float4 x, float4 w0, float4 w1, float4 w2, float4 w3){
  a[0] += x.x*w0.x + x.y*w1.x + x.z*w2.x + x.w*w3.x;
  a[1] += x.x*w0.y + x.y*w1.y + x.z*w2.y + x.w*w3.y;
  a[2] += x.x*w0.z + x.y*w1.z + x.z*w2.z + x.w*w3.z;
  a[3] += x.x*w0.w + x.y*w1.w + x.z*w2.w + x.w*w3.w;
}

// ---------------- util ----------------

__global__ void k_zero2(int* __restrict__ a, int na, int* __restrict__ b, int nb){
  int i = blockIdx.x*256 + threadIdx.x;
  if (i < na) a[i] = 0;
  else if (i - na < nb) b[i - na] = 0;
}

__global__ void k_sentinel(float* out, float wsmb){ out[0] = 1000000.0f + wsmb; }

__global__ void k_einv(const int* __restrict__ perm2, int* __restrict__ einv, int n){
  int i = blockIdx.x*256 + threadIdx.x;
  if (i < n) einv[perm2[i]] = i;
}

__global__ void k_lidx2(const int* __restrict__ lsrc, const int* __restrict__ ldst,
                        const int* __restrict__ perm1, const int* __restrict__ einv,
                        int* __restrict__ lsrc2, int* __restrict__ ldst2, int n){
  int i = blockIdx.x*256 + threadIdx.x;
  if (i < n){
    int o = perm1[i];
    lsrc2[i] = einv[lsrc[o]];
    ldst2[i] = einv[ldst[o]];
  }
}

// ---------------- parallel 3-pass exclusive scan ----------------

__global__ __launch_bounds__(256) void k_scanp1(
    const int* __restrict__ inA, int* __restrict__ outA,
    const int* __restrict__ inB, int* __restrict__ outB,
    int* __restrict__ bsumA, int* __restrict__ bsumB){
  __shared__ int wsum[4];
  const int b = blockIdx.x, t = threadIdx.x;
  const int* in;  int* out;  int* bsum;  int base;
  if (b < 64){ in = inA; out = outA; bsum = bsumA + b; base = b*2048; }
  else       { in = inB; out = outB; bsum = bsumB;     base = 0; }
  int v[8];
  int s = 0;
  #pragma unroll
  for (int j=0;j<8;j++){ v[j] = in[base + t*8 + j]; s += v[j]; }
  const int lane = t & 63, wid = t >> 6;
  int x = s;
  #pragma unroll
  for (int off=1; off<64; off<<=1){
    int u = __shfl_up(x, off);
    if (lane >= off) x += u;
  }
  if (lane == 63) wsum[wid] = x;
  __syncthreads();
  int woff = 0;
  #pragma unroll
  for (int i=0;i<3;i++) if (i < wid) woff += wsum[i];
  int run = woff + x - s;
  #pragma unroll
  for (int j=0;j<8;j++){ out[base + t*8 + j] = run; run += v[j]; }
  if (t == 255) *bsum = woff + x;
}

__global__ void k_scanp2(int* __restrict__ bsumA, int* __restrict__ outA, int nA,
                         const int* __restrict__ bsumB, int* __restrict__ outB, int nB){
  __shared__ int sh[64];
  const int t = threadIdx.x;
  if (t < 64) sh[t] = bsumA[t];
  __syncthreads();
  if (t == 0){
    int run = 0;
    for (int i=0;i<64;i++){ int v = sh[i]; sh[i] = run; run += v; }
    outA[nA] = run;
    outB[nB] = bsumB[0];
  }
  __syncthreads();
  if (t < 64) bsumA[t] = sh[t];
}

__global__ __launch_bounds__(256) void k_scanp3(int* __restrict__ outA, const int* __restrict__ bsumA){
  const int b = blockIdx.x;
  const int off = bsumA[b];
  const int base = b*2048 + threadIdx.x*8;
  #pragma unroll
  for (int j=0;j<8;j++) outA[base+j] += off;
}

// all per-layer weight-fragment conversions in ONE dispatch (j-pair cols).
// EU W1 FOLDED: row r<128 = W1[r]+W1[r+128]; row r>=128 = W1[r+128].
__global__ void k_wfrag_all(const float* __restrict__ luw1, const float* __restrict__ luw2,
                            const float* __restrict__ euw1, const float* __restrict__ euw2,
                            u16* __restrict__ lw1h, u16* __restrict__ lw2h,
                            u16* __restrict__ ew1h, u16* __restrict__ ew2h){
  int l = blockIdx.x / 72, r = blockIdx.x % 72;
  const float* W; u16* out; int N, total, lb; bool fold = false;
  if (r < 16){      W = luw1 + (size_t)l*256*128; out = lw1h + (size_t)l*32768; N=128; total=4096;  lb = r; }
  else if (r < 24){ W = luw2 + (size_t)l*128*128; out = lw2h + (size_t)l*16384; N=128; total=2048;  lb = r-16; }
  else if (r < 56){ W = euw1 + (size_t)l*384*256; out = ew1h + (size_t)l*65536; N=256; total=8192;  lb = r-24; fold = true; }
  else {            W = euw2 + (size_t)l*256*128; out = ew2h + (size_t)l*32768; N=128; total=4096;  lb = r-56; }
  int i = lb*256 + threadIdx.x;
  if (i >= total) return;
  int lane = i & 63;
  int frag = i >> 6;
  int NT = N >> 4;
  int ntg = frag % NT;
  int kt = frag / NT;
  int half = NT >> 1;
  int colh = ntg / half, j = ntg % half;
  int col  = colh*(half<<4) + ((j>>1)<<5) + 2*(lane&15) + (j&1);
  int row0 = kt*32 + (lane>>4)*8;
  uint4 v; uint* vp = (uint*)&v;
  #pragma unroll
  for (int p=0;p<4;p++){
    int ra = row0+2*p, rb = row0+2*p+1;
    float fa, fb;
    if (fold){
      fa = (ra < 128) ? W[(size_t)ra*N + col] + W[(size_t)(ra+128)*N + col]
                      : W[(size_t)(ra+128)*N + col];
      fb = (rb < 128) ? W[(size_t)rb*N + col] + W[(size_t)(rb+128)*N + col]
                      : W[(size_t)(rb+128)*N + col];
    } else {
      fa = W[(size_t)ra*N + col];
      fb = W[(size_t)rb*N + col];
    }
    vp[p] = (uint)f2h(fa) | ((uint)f2h(fb)<<16);
  }
  *(uint4*)(out + (size_t)i*8) = v;
}

// rbf weights -> fragments: w1 [50][128] zero-padded to K=64; w2 [128][128].
__global__ void k_rbf_wfrag(const float* __restrict__ rw1, const float* __restrict__ rw2,
                            u16* __restrict__ w1p, u16* __restrict__ w2p){
  int r = blockIdx.x;
  const float* W; u16* out; int K, total;
  if (r < 4){ W = rw1; out = w1p; K = 50;  total = 1024; }
  else      { W = rw2; out = w2p; K = 128; total = 2048; r -= 4; }
  int i = r*256 + threadIdx.x;
  if (i >= total) return;
  int lane = i & 63, frag = i >> 6;
  int ntg = frag % 8, kt = frag / 8;
  int colh = ntg / 4, j = ntg % 4;
  int col  = colh*64 + ((j>>1)<<5) + 2*(lane&15) + (j&1);
  int row0 = kt*32 + (lane>>4)*8;
  uint4 v; uint* vp = (uint*)&v;
  #pragma unroll
  for (int p=0;p<4;p++){
    int ra = row0+2*p, rb = row0+2*p+1;
    u16 a = (ra < K) ? f2h(W[(size_t)ra*128 + col]) : (u16)0;
    u16 b = (rb < K) ? f2h(W[(size_t)rb*128 + col]) : (u16)0;
    vp[p] = (uint)a | ((uint)b<<16);
  }
  *(uint4*)(out + (size_t)i*8) = v;
}

// ---------------- init ----------------

__global__ void k_node_init(const int* __restrict__ an, const float* __restrict__ tab, float* __restrict__ node){
  int i = blockIdx.x*256 + threadIdx.x;          // NN*DM threads
  int n = i >> 7, d = i & 127;
  node[i] = tab[(an[n]-1)*DM + d];
}

__global__ void k_line_init(const float* __restrict__ ang, const float* __restrict__ w,
                            const float* __restrict__ b, const int* __restrict__ perm1,
                            u16* __restrict__ line){
  int i = blockIdx.x*256 + threadIdx.x;          // NL*64 threads (2 cols each)
  int r = i >> 6; int c2 = (i & 63)*2;
  float a = ang[perm1[r]];
  ushort2 v;
  v.x = f2h(a*w[c2  ] + b[c2  ]);
  v.y = f2h(a*w[c2+1] + b[c2+1]);
  ((ushort2*)line)[i] = v;
}

// MFMA edge embedding: 32 edges/block; rbf f16 [32][64-pad]; two MFMA GEMMs.
#define EB_RS 72    // 64+8 halves
#define EB_HS 136   // 128+8 halves

__global__ __launch_bounds__(256) void k_edge_embed2(
    const float* __restrict__ pos, const int* __restrict__ eidx,
    const int* __restrict__ eperm,
    const u16* __restrict__ W1p, const float* __restrict__ B1,
    const u16* __restrict__ W2p, const float* __restrict__ B2,
    u16* __restrict__ edge){
  __shared__ __align__(16) u16 rs[32*EB_RS];
  __shared__ __align__(16) u16 hs[32*EB_HS];
  __shared__ float dsh[32];
  const int t = threadIdx.x;
  const int e0 = blockIdx.x*32;
  if (t < 32){
    int eo = eperm[e0 + t];
    int s = eidx[eo], d = eidx[NE + eo];
    float dx = pos[d*3+0]-pos[s*3+0];
    float dy = pos[d*3+1]-pos[s*3+1];
    float dz = pos[d*3+2]-pos[s*3+2];
    dsh[t] = sqrtf(dx*dx+dy*dy+dz*dz);
  }
  __syncthreads();
  for (int q = t; q < 32*64; q += 256){
    int m = q >> 6, k = q & 63;
    float d = dsh[m];
    float v = 0.f;
    if (k < 50){
      float c = 8.0f*(float)k/49.0f;
      float g = __expf(-(d-c)*(d-c)*19.53125f);
      float cut = (d < 8.0f) ? 0.5f*(__cosf(d*0.39269908169872414f)+1.0f) : 0.0f;
      v = g*cut;
    }
    rs[m*EB_RS + k] = f2h(v);
  }
  __syncthreads();

  const int lane = t & 63, w = t >> 6;
  const int band = w >> 1, colh = w & 1;
  const int arow = band*16 + (lane & 15);
  const int kgrp = (lane >> 4)*8;
  const int q2 = 2*(lane & 15);

  {
    f32x4 acc[4];
    #pragma unroll
    for (int nt=0; nt<4; ++nt){
      float bv = B1[colh*64 + (nt>>1)*32 + q2 + (nt&1)];
      acc[nt][0]=bv; acc[nt][1]=bv; acc[nt][2]=bv; acc[nt][3]=bv;
    }
    #pragma unroll
    for (int kt=0; kt<2; ++kt){
      f16x8 a = *(const f16x8*)(rs + arow*EB_RS + kt*32 + kgrp);
      #pragma unroll
      for (int nt=0; nt<4; ++nt){
        int ntg = colh*4 + nt;
        f16x8 b = *(const f16x8*)(W1p + ((size_t)(kt*8 + ntg)*64 + lane)*8);
        acc[nt] = __builtin_amdgcn_mfma_f32_16x16x32_f16(a, b, acc[nt], 0, 0, 0);
      }
    }
    #pragma unroll
    for (int p=0; p<2; ++p){
      int colb = colh*64 + p*32 + q2;
      #pragma unroll
      for (int r=0; r<4; ++r){
        int row = band*16 + (lane>>4)*4 + r;
        *(uint*)(hs + row*EB_HS + colb) = pk2h(siluf(acc[2*p][r]), siluf(acc[2*p+1][r]));
      }
    }
  }
  __syncthreads();
  {
    f32x4 acc[4];
    #pragma unroll
    for (int nt=0; nt<4; ++nt){
      float bv = B2[colh*64 + (nt>>1)*32 + q2 + (nt&1)];
      acc[nt][0]=bv; acc[nt][1]=bv; acc[nt][2]=bv; acc[nt][3]=bv;
    }
    #pragma unroll
    for (int kt=0; kt<4; ++kt){
      f16x8 a = *(const f16x8*)(hs + arow*EB_HS + kt*32 + kgrp);
      #pragma unroll
      for (int nt=0; nt<4; ++nt){
        int ntg = colh*4 + nt;
        f16x8 b = *(const f16x8*)(W2p + ((size_t)(kt*8 + ntg)*64 + lane)*8);
        acc[nt] = __builtin_amdgcn_mfma_f32_16x16x32_f16(a, b, acc[nt], 0, 0, 0);
      }
    }
    #pragma unroll
    for (int p=0; p<2; ++p){
      int colb = colh*64 + p*32 + q2;
      #pragma unroll
      for (int r=0; r<4; ++r){
        int row = band*16 + (lane>>4)*4 + r;
        *(uint*)(edge + (size_t)(e0+row)*DM + colb) = pk2h(acc[2*p][r], acc[2*p+1][r]);
      }
    }
  }
}

// ---------------- CSR build (merged dispatches) ----------------

__global__ void k_hist2(const int* __restrict__ idxA, int* __restrict__ histA,
                        const int* __restrict__ idxB, int* __restrict__ histB, int nblkA){
  int t = threadIdx.x;
  if ((int)blockIdx.x < nblkA){
    int i = blockIdx.x*256 + t;
    atomicAdd(&histA[idxA[i]], 1);
  } else {
    int i = (blockIdx.x - nblkA)*256 + t;
    atomicAdd(&histB[idxB[i]], 1);
  }
}

__global__ void k_perm2k(const int* __restrict__ idxA, const int* __restrict__ baseA,
                         int* __restrict__ curA, int* __restrict__ permA,
                         const int* __restrict__ idxB, const int* __restrict__ baseB,
                         int* __restrict__ curB, int* __restrict__ permB, int nblkA){
  int t = threadIdx.x;
  if ((int)blockIdx.x < nblkA){
    int i = blockIdx.x*256 + t;
    int e = idxA[i];
    int p = atomicAdd(&curA[e], 1);
    permA[baseA[e] + p] = i;
  } else {
    int i = (blockIdx.x - nblkA)*256 + t;
    int e = idxB[i];
    int p = atomicAdd(&curB[e], 1);
    permB[baseB[e] + p] = i;
  }
}

// ---------------- LU precompute: A = edge@W1top, Bm = edge@W1bot ----------------

#define PE_XS 136

__global__ __launch_bounds__(256) void k_pre_lu(
    const u16* __restrict__ edge, const u16* __restrict__ W1h,
    u16* __restrict__ A16, u16* __restrict__ Bm16){
  __shared__ __align__(16) u16 xs[32*PE_XS];
  const int t = threadIdx.x;
  const int r0 = blockIdx.x*32;
  #pragma unroll
  for (int it=0; it<2; ++it){
    int idx = it*256 + t;
    int m = idx >> 4, c = idx & 15;
    uint4 v = *(const uint4*)(edge + (size_t)(r0+m)*DM + c*8);
    *(uint4*)(xs + m*PE_XS + c*8) = v;
  }
  __syncthreads();
  const int lane = t & 63, w = t >> 6;
  const int band = w >> 1, colh = w & 1;
  const int arow = band*16 + (lane & 15);
  const int kgrp = (lane >> 4)*8;
  const int q2 = 2*(lane & 15);
  #pragma unroll
  for (int half=0; half<2; ++half){
    f32x4 acc[4];
    #pragma unroll
    for (int nt=0; nt<4; ++nt){ acc[nt][0]=0.f; acc[nt][1]=0.f; acc[nt][2]=0.f; acc[nt][3]=0.f; }
    #pragma unroll
    for (int kt=0; kt<4; ++kt){
      f16x8 a = *(const f16x8*)(xs + arow*PE_XS + kt*32 + kgrp);
      #pragma unroll
      for (int nt=0; nt<4; ++nt){
        int ntg = colh*4 + nt;
        f16x8 b = *(const f16x8*)(W1h + ((size_t)((kt + half*4)*8 + ntg)*64 + lane)*8);
        acc[nt] = __builtin_amdgcn_mfma_f32_16x16x32_f16(a, b, acc[nt], 0, 0, 0);
      }
    }
    u16* out = half ? Bm16 : A16;
    #pragma unroll
    for (int p=0; p<2; ++p){
      int colb = colh*64 + p*32 + q2;
      #pragma unroll
      for (int r=0; r<4; ++r){
        int row = band*16 + (lane>>4)*4 + r;
        *(uint*)(out + (size_t)(r0+row)*DM + colb) = pk2h(acc[2*p][r], acc[2*p+1][r]);
      }
    }
  }
}

// ---------------- LU: h = silu(A[src]+Bm[dst]+b1); line = LN(line + h@W2+b2) ----------------

#define LU_HS 136   // halves (H overlay in smem)
#define LU_OS 132   // floats

__global__ __launch_bounds__(256) void k_lu2(
    const u16* __restrict__ A16, const u16* __restrict__ Bm16,
    const int* __restrict__ lsrc2, const int* __restrict__ ldst2,
    const float* __restrict__ B1,
    const u16* __restrict__ W2h, const float* __restrict__ B2,
    const float* __restrict__ lg, const float* __restrict__ lb,
    u16* __restrict__ line){
  __shared__ __align__(16) float smem[32*LU_OS];
  u16* hs = (u16*)smem;
  const int t = threadIdx.x;
  const int r0 = blockIdx.x*32;

  {                                              // gather-fuse: packed f16 adds
    int m = t >> 3, c8 = t & 7;
    int r = r0 + m;
    const u16* ap = A16  + (size_t)lsrc2[r]*DM;
    const u16* bp = Bm16 + (size_t)ldst2[r]*DM;
    #pragma unroll
    for (int cc0=0; cc0<2; ++cc0){
      int cc = c8 + cc0*8;
      uint4 av = *(const uint4*)(ap + cc*8);
      uint4 bv = *(const uint4*)(bp + cc*8);
      const __half2* ah = (const __half2*)&av;
      const __half2* bh = (const __half2*)&bv;
      uint outw[4];
      #pragma unroll
      for (int p=0;p<4;p++){
        int col = cc*8 + 2*p;
        __half2 b1v = __floats2half2_rn(B1[col], B1[col+1]);   // uniform, hoisted
        __half2 x2 = __hadd2(__hadd2(ah[p], bh[p]), b1v);
        float x0 = __half2float(__low2half(x2));
        float x1 = __half2float(__high2half(x2));
        outw[p] = pk2h(siluf(x0), siluf(x1));
      }
      *(uint4*)(hs + m*LU_HS + cc*8) = *(uint4*)outw;
    }
  }
  __syncthreads();

  const int lane = t & 63, w = t >> 6;
  const int band = w >> 1, colh = w & 1;
  const int arow = band*16 + (lane & 15);
  const int kgrp = (lane >> 4)*8;
  const int q2 = 2*(lane & 15);

  f32x4 acc[4];
  #pragma unroll
  for (int nt=0; nt<4; ++nt){
    float bv = B2[colh*64 + (nt>>1)*32 + q2 + (nt&1)];
    acc[nt][0]=bv; acc[nt][1]=bv; acc[nt][2]=bv; acc[nt][3]=bv;
  }
  #pragma unroll
  for (int kt=0; kt<4; ++kt){
    f16x8 a = *(const f16x8*)(hs + arow*LU_HS + kt*32 + kgrp);
    #pragma unroll
    for (int nt=0; nt<4; ++nt){
      int ntg = colh*4 + nt;
      f16x8 b = *(const f16x8*)(W2h + ((size_t)(kt*8 + ntg)*64 + lane)*8);
      acc[nt] = __builtin_amdgcn_mfma_f32_16x16x32_f16(a, b, acc[nt], 0, 0, 0);
    }
  }
  __syncthreads();
  #pragma unroll
  for (int p=0; p<2; ++p){
    int colb = colh*64 + p*32 + q2;
    #pragma unroll
    for (int r=0; r<4; ++r){
      int row = band*16 + (lane>>4)*4 + r;
      *(float2*)(smem + row*LU_OS + colb) = make_float2(acc[2*p][r], acc[2*p+1][r]);
    }
  }
  __syncthreads();
  {
    const float* outp = (const float*)smem;
    int row = t >> 3, li = t & 7;
    size_t rb = (size_t)(r0 + row)*DM;
    uint rw[8];
    *(uint4*)&rw[0] = *(const uint4*)(line + rb + li*16);
    *(uint4*)&rw[4] = *(const uint4*)(line + rb + li*16 + 8);
    float x[16];
    float s=0.f, q=0.f;
    #pragma unroll
    for (int j=0;j<16;j++){
      float res = h2f((u16)((j&1) ? (rw[j>>1]>>16) : (rw[j>>1]&0xffffu)));
      x[j] = outp[row*LU_OS + li*16 + j] + res;
      s += x[j]; q += x[j]*x[j];
    }
    #pragma unroll
    for (int off=1; off<8; off<<=1){ s += __shfl_xor(s,off); q += __shfl_xor(q,off); }
    float mean = s*(1.f/128.f);
    float rstd = rsqrtf(fmaxf(q*(1.f/128.f) - mean*mean, 0.f) + 1e-5f);
    #pragma unroll
    for (int half=0; half<2; ++half){
      uint4 wv; uint* wp = (uint*)&wv;
      #pragma unroll
      for (int p=0;p<4;p++){
        int j = half*8 + 2*p;
        int c0 = li*16 + j;
        wp[p] = pk2h((x[j  ]-mean)*rstd*lg[c0  ] + lb[c0  ],
                     (x[j+1]-mean)*rstd*lg[c0+1] + lb[c0+1]);
      }
      *(uint4*)(line + rb + li*16 + half*8) = wv;
    }
  }
}

// ---------------- MFMA edge update (FOLDED W1: K=256) ----------------

#define EU_XS 264   // 256+8 halves
#define EU_HS 264   // 256+8 halves
#define EU_OS 132   // 128+4 floats

__global__ __launch_bounds__(256) void k_eu_mfma(
    const u16* __restrict__ W1h, const float* __restrict__ B1,
    const u16* __restrict__ W2h, const float* __restrict__ B2,
    const float* __restrict__ g, const float* __restrict__ bb,
    u16* __restrict__ edge, const u16* __restrict__ line,
    const int* __restrict__ lbase, const int* __restrict__ eperm){
  __shared__ __align__(16) u16 xs[32*EU_XS];
  __shared__ __align__(16) u16 hs[32*EU_HS];
  const int t = threadIdx.x;
  const int r0 = blockIdx.x*32;

  for (int it=0; it<2; ++it){
    int idx = it*256 + t;
    int m = idx >> 4, c = idx & 15;
    uint4 v = *(const uint4*)(edge + (size_t)(r0+m)*DM + c*8);
    *(uint4*)(xs + m*EU_XS + c*8) = v;
  }
  {
    int m = t >> 3, c0 = (t & 7)*16;
    int eo = eperm[r0 + m];
    int b0 = lbase[eo], b1 = lbase[eo+1];
    float s[16];
    #pragma unroll
    for (int k=0;k<16;k++) s[k]=0.f;
    for (int j=b0;j<b1;++j){
      const u16* lp = line + (size_t)j*DM + c0;
      uint rw[8];
      *(uint4*)&rw[0] = *(const uint4*)lp;
      *(uint4*)&rw[4] = *(const uint4*)(lp + 8);
      #pragma unroll
      for (int k=0;k<16;k++)
        s[k] += h2f((u16)((k&1) ? (rw[k>>1]>>16) : (rw[k>>1]&0xffffu)));
    }
    int n = b1 - b0;
    float inv = 1.f/(float)(n > 0 ? n : 1);
    #pragma unroll
    for (int half=0; half<2; ++half){
      uint4 wv; uint* wp = (uint*)&wv;
      #pragma unroll
      for (int p=0;p<4;p++){
        int k = half*8 + 2*p;
        wp[p] = pk2h(s[k]*inv, s[k+1]*inv);
      }
      *(uint4*)(xs + m*EU_XS + 128 + c0 + half*8) = wv;
    }
  }
  __syncthreads();

  const int lane = t & 63, w = t >> 6;
  const int band = w >> 1, colh = w & 1;
  const int arow = band*16 + (lane & 15);
  const int kgrp = (lane >> 4)*8;
  const int q2 = 2*(lane & 15);

  {
    f32x4 acc[8];
    #pragma unroll
    for (int nt=0; nt<8; ++nt){
      float bv = B1[colh*128 + (nt>>1)*32 + q2 + (nt&1)];
      acc[nt][0]=bv; acc[nt][1]=bv; acc[nt][2]=bv; acc[nt][3]=bv;
    }
    #pragma unroll
    for (int kt=0; kt<8; ++kt){
      f16x8 a = *(const f16x8*)(xs + arow*EU_XS + kt*32 + kgrp);
      #pragma unroll
      for (int nt=0; nt<8; ++nt){
        int ntg = colh*8 + nt;
        f16x8 b = *(const f16x8*)(W1h + ((size_t)(kt*16 + ntg)*64 + lane)*8);
        acc[nt] = __builtin_amdgcn_mfma_f32_16x16x32_f16(a, b, acc[nt], 0, 0, 0);
      }
    }
    #pragma unroll
    for (int p=0; p<4; ++p){
      int colb = colh*128 + p*32 + q2;
      #pragma unroll
      for (int r=0; r<4; ++r){
        int row = band*16 + (lane>>4)*4 + r;
        *(uint*)(hs + row*EU_HS + colb) = pk2h(siluf(acc[2*p][r]), siluf(acc[2*p+1][r]));
      }
    }
  }
  __syncthreads();
  {
    f32x4 acc[4];
    #pragma unroll
    for (int nt=0; nt<4; ++nt){
      float bv = B2[colh*64 + (nt>>1)*32 + q2 + (nt&1)];
      acc[nt][0]=bv; acc[nt][1]=bv; acc[nt][2]=bv; acc[nt][3]=bv;
    }
    #pragma unroll
    for (int kt=0; kt<8; ++kt){
      f16x8 a = *(const f16x8*)(hs + arow*EU_HS + kt*32 + kgrp);
      #pragma unroll
      for (int nt=0; nt<4; ++nt){
        int ntg = colh*4 + nt;
        f16x8 b = *(const f16x8*)(W2h + ((size_t)(kt*8 + ntg)*64 + lane)*8);
        acc[nt] = __builtin_amdgcn_mfma_f32_16x16x32_f16(a, b, acc[nt], 0, 0, 0);
      }
    }
    float* outp = (float*)xs;
    #pragma unroll
    for (int p=0; p<2; ++p){
      int colb = colh*64 + p*32 + q2;
      #pragma unroll
      for (int r=0; r<4; ++r){
        int row = band*16 + (lane>>4)*4 + r;
        *(float2*)(outp + row*EU_OS + colb) = make_float2(acc[2*p][r], acc[2*p+1][r]);
      }
    }
  }
  __syncthreads();
  {
    const float* outp = (const float*)xs;
    int row = t >> 3, li = t & 7;
    size_t rb = (size_t)(r0 + row)*DM;
    uint rw[8];
    *(uint4*)&rw[0] = *(const uint4*)(edge + rb + li*16);
    *(uint4*)&rw[4] = *(const uint4*)(edge + rb + li*16 + 8);
    float x[16];
    float s=0.f, q=0.f;
    #pragma unroll
    for (int j=0;j<16;j++){
      float res = h2f((u16)((j&1) ? (rw[j>>1]>>16) : (rw[j>>1]&0xffffu)));
      x[j] = outp[row*EU_OS + li*16 + j] + res;
      s += x[j]; q += x[j]*x[j];
    }
    #pragma unroll
    for (int off=1; off<8; off<<=1){ s += __shfl_xor(s,off); q += __shfl_xor(q,off); }
    float mean = s*(1.f/128.f);
    float rstd = rsqrtf(fmaxf(q*(1.f/128.f) - mean*mean, 0.f) + 1e-5f);
    #pragma unroll
    for (int half=0; half<2; ++half){
      uint4 wv; uint* wp = (uint*)&wv;
      #pragma unroll
      for (int p=0;p<4;p++){
        int j = half*8 + 2*p;
        int c0 = li*16 + j;
        wp[p] = pk2h((x[j  ]-mean)*rstd*g[c0  ] + bb[c0  ],
                     (x[j+1]-mean)*rstd*g[c0+1] + bb[c0+1]);
      }
      *(uint4*)(edge + rb + li*16 + half*8) = wv;
    }
  }
}

// ---------------- NU: fused 16-row MLP+LN (contiguous naggr walk) ----------------

template<int KIN>
__global__ __launch_bounds__(256) void k_nu(
    const float* __restrict__ W1, const float* __restrict__ B1,
    const float* __restrict__ W2, const float* __restrict__ B2,
    const float* __restrict__ g, const float* __restrict__ bb,
    float* __restrict__ node_io, const u16* __restrict__ edge,
    const int* __restrict__ nbase){
  __shared__ __align__(16) float xsf[16*KIN];
  __shared__ __align__(16) float hsf[16*256];
  const int t = threadIdx.x;
  const int r0 = blockIdx.x*16;

  {
    int m = t >> 4, c0 = (t & 15)*8;
    int n = r0 + m;
    float4 a = ld4(node_io + (size_t)n*DM + c0);
    float4 b = ld4(node_io + (size_t)n*DM + c0 + 4);
    float* xd = &xsf[m*KIN + c0];
    xd[0]=a.x; xd[1]=a.y; xd[2]=a.z; xd[3]=a.w;
    xd[4]=b.x; xd[5]=b.y; xd[6]=b.z; xd[7]=b.w;
    int b0 = nbase[n], b1e = nbase[n+1];
    float s[8];
    #pragma unroll
    for (int k=0;k<8;k++) s[k]=0.f;
    for (int j=b0;j<b1e;++j){
      uint4 v = *(const uint4*)(edge + (size_t)j*DM + c0);
      s[0]+=h2f((u16)(v.x&0xffff)); s[1]+=h2f((u16)(v.x>>16));
      s[2]+=h2f((u16)(v.y&0xffff)); s[3]+=h2f((u16)(v.y>>16));
      s[4]+=h2f((u16)(v.z&0xffff)); s[5]+=h2f((u16)(v.z>>16));
      s[6]+=h2f((u16)(v.w&0xffff)); s[7]+=h2f((u16)(v.w>>16));
    }
    int nn = b1e - b0;
    float inv = 1.f/(float)(nn > 0 ? nn : 1);
    #pragma unroll
    for (int k=0;k<8;k++) xsf[m*KIN + 128 + c0 + k] = s[k]*inv;
  }
  __syncthreads();
  {
    const int c4 = (t & 63)*4, mg = t >> 6;
    float acc[4][4];
    float4 bv = ld4(B1 + c4);
    #pragma unroll
    for (int i=0;i<4;i++){ acc[i][0]=bv.x; acc[i][1]=bv.y; acc[i][2]=bv.z; acc[i][3]=bv.w; }
    for (int k=0;k<KIN;k+=4){
      float4 w0 = ld4(W1 + (k  )*256 + c4);
      float4 w1 = ld4(W1 + (k+1)*256 + c4);
      float4 w2 = ld4(W1 + (k+2)*256 + c4);
      float4 w3 = ld4(W1 + (k+3)*256 + c4);
      #pragma unroll
      for (int i=0;i<4;i++){
        float4 x = *(const float4*)&xsf[(mg*4+i)*KIN + k];
        fma44(acc[i], x, w0, w1, w2, w3);
      }
    }
    #pragma unroll
    for (int i=0;i<4;i++)
      #pragma unroll
      for (int j=0;j<4;j++)
        hsf[(mg*4+i)*256 + c4 + j] = siluf(acc[i][j]);
  }
  __syncthreads();
  const int c4b = (t & 31)*4, mgb = t >> 5;
  float acc2[2][4];
  {
    float4 bv = ld4(B2 + c4b);
    #pragma unroll
    for (int i=0;i<2;i++){ acc2[i][0]=bv.x; acc2[i][1]=bv.y; acc2[i][2]=bv.z; acc2[i][3]=bv.w; }
    for (int k=0;k<256;k+=4){
      float4 w0 = ld4(W2 + (k  )*128 + c4b);
      float4 w1 = ld4(W2 + (k+1)*128 + c4b);
      float4 w2 = ld4(W2 + (k+2)*128 + c4b);
      float4 w3 = ld4(W2 + (k+3)*128 + c4b);
      #pragma unroll
      for (int i=0;i<2;i++){
        float4 x = *(const float4*)&hsf[(mgb*2+i)*256 + k];
        fma44(acc2[i], x, w0, w1, w2, w3);
      }
    }
  }
  __syncthreads();
  #pragma unroll
  for (int i=0;i<2;i++){
    int m = mgb*2 + i;
    #pragma unroll
    for (int j=0;j<4;j++)
      hsf[m*128 + c4b + j] = acc2[i][j] + xsf[m*KIN + c4b + j];
  }
  __syncthreads();
  {
    int row = t >> 4, li = t & 15;
    const float* o = &hsf[row*128];
    float s=0.f, q=0.f;
    #pragma unroll
    for (int j=0;j<8;j++){ float x = o[li*8+j]; s += x; q += x*x; }
    #pragma unroll
    for (int off=1; off<16; off<<=1){ s += __shfl_xor(s,off); q += __shfl_xor(q,off); }
    float mean = s*(1.f/128.f);
    float rstd = rsqrtf(fmaxf(q*(1.f/128.f) - mean*mean, 0.f) + 1e-5f);
    size_t rb = (size_t)(r0 + row)*DM;
    #pragma unroll
    for (int j=0;j<8;j++){
      int c = li*8 + j;
      node_io[rb + c] = (o[c]-mean)*rstd*g[c] + bb[c];
    }
  }
}

// ---------------- attention ----------------

__global__ void k_qkv_split(const float* __restrict__ node, const float* __restrict__ W,
                            const float* __restrict__ B, float* __restrict__ Q,
                            u16* __restrict__ K4, u16* __restrict__ V4){
  int i = blockIdx.x*256 + threadIdx.x;          // NN*384 threads
  int n = i / 384, c = i % 384;
  float acc = B[c];
  const float* nr = node + (size_t)n*DM;
  for (int k=0;k<128;k+=4){
    acc += nr[k  ]*W[(k  )*384+c];
    acc += nr[k+1]*W[(k+1)*384+c];
    acc += nr[k+2]*W[(k+2)*384+c];
    acc += nr[k+3]*W[(k+3)*384+c];
  }
  if (c < 128){
    Q[(size_t)n*128 + c] = acc;
  } else if (c < 256){
    int h = (c-128) >> 5, d = (c-128) & 31;
    K4[((size_t)h*NN + n)*32 + d] = f2h(acc);
  } else {
    int h = (c-256) >> 5, d = (c-256) & 31;
    V4[((size_t)h*NN + n)*32 + d] = f2h(acc);
  }
}

// 4 waves = 8 queries x 1 head; 128-key f16 tiles, double-buffered LDS.
// fdot2 QK + merged-half online softmax (one rescale per 2 keys).
#define AT_TK 128
#define AT_RU 17

__global__ __launch_bounds__(256) void k_attn3(
    const float* __restrict__ Q, const u16* __restrict__ K4,
    const u16* __restrict__ V4, float* __restrict__ attno){
  __shared__ uint kls[2][AT_TK*AT_RU];
  __shared__ uint vls[2][AT_TK*AT_RU];
  const int t = threadIdx.x, lane = t & 63;
  const int h = blockIdx.x >> 8;
  const int q0 = (blockIdx.x & 255)*8 + (t >> 6)*2;
  const float scale = 0.17677669529663687f;
  const uint* Kg = (const uint*)(K4 + (size_t)h*NN*32);
  const uint* Vg = (const uint*)(V4 + (size_t)h*NN*32);
  const int ca = t*2, cb = t*2+1;
  const int ka_ = ca>>2, pa_ = (ca&3)*4;
  const int kb_ = cb>>2, pb_ = (cb&3)*4;
  uint4 kr0, kr1, vr0, vr1;

  f16x2 qh[2][16];                               // Q pre-scaled, packed f16
  #pragma unroll
  for (int j=0;j<2;j++){
    const float* qr = Q + (size_t)(q0+j)*128 + h*32;
    #pragma unroll
    for (int u=0;u<16;u++){
      union { uint u32; f16x2 h2; } cv;
      cv.u32 = pk2h(qr[2*u]*scale, qr[2*u+1]*scale);
      qh[j][u] = cv.h2;
    }
  }
  float mx = -1e30f, s0 = 0.f, s1 = 0.f;
  float o0[32], o1[32];
  #pragma unroll
  for (int d=0;d<32;d++){ o0[d]=0.f; o1[d]=0.f; }

  {
    const uint* kg = Kg; const uint* vg = Vg;
    kr0 = *(const uint4*)(kg + ca*4); kr1 = *(const uint4*)(kg + cb*4);
    vr0 = *(const uint4*)(vg + ca*4); vr1 = *(const uint4*)(vg + cb*4);
    uint* kd = kls[0]; uint* vd = vls[0];
    kd[ka_*AT_RU+pa_  ]=kr0.x; kd[ka_*AT_RU+pa_+1]=kr0.y; kd[ka_*AT_RU+pa_+2]=kr0.z; kd[ka_*AT_RU+pa_+3]=kr0.w;
    kd[kb_*AT_RU+pb_  ]=kr1.x; kd[kb_*AT_RU+pb_+1]=kr1.y; kd[kb_*AT_RU+pb_+2]=kr1.z; kd[kb_*AT_RU+pb_+3]=kr1.w;
    vd[ka_*AT_RU+pa_  ]=vr0.x; vd[ka_*AT_RU+pa_+1]=vr0.y; vd[ka_*AT_RU+pa_+2]=vr0.z; vd[ka_*AT_RU+pa_+3]=vr0.w;
    vd[kb_*AT_RU+pb_  ]=vr1.x; vd[kb_*AT_RU+pb_+1]=vr1.y; vd[kb_*AT_RU+pb_+2]=vr1.z; vd[kb_*AT_RU+pb_+3]=vr1.w;
  }
  __syncthreads();

  const int NT = NN / AT_TK;
  for (int kt=0; kt<NT; ++kt){
    if (kt+1 < NT){
      const uint* kg = Kg + (size_t)(kt+1)*AT_TK*16;
      const uint* vg = Vg + (size_t)(kt+1)*AT_TK*16;
      kr0 = *(const uint4*)(kg + ca*4); kr1 = *(const uint4*)(kg + cb*4);
      vr0 = *(const uint4*)(vg + ca*4); vr1 = *(const uint4*)(vg + cb*4);
    }
    {
      const uint* kb = kls[kt&1];
      const uint* vb = vls[kt&1];
      const uint* krA = kb + lane*AT_RU;               // key = lane
      const uint* krB = kb + (lane+64)*AT_RU;          // key = lane+64
      float dA0=0.f, dA1=0.f, dB0=0.f, dB1=0.f;
      #pragma unroll
      for (int u=0;u<16;u++){
        union { uint u32; f16x2 h2; } ka, kbv;
        ka.u32  = krA[u];
        kbv.u32 = krB[u];
        dA0 = __builtin_amdgcn_fdot2(ka.h2,  qh[0][u], dA0, false);
        dA1 = __builtin_amdgcn_fdot2(ka.h2,  qh[1][u], dA1, false);
        dB0 = __builtin_amdgcn_fdot2(kbv.h2, qh[0][u], dB0, false);
        dB1 = __builtin_amdgcn_fdot2(kbv.h2, qh[1][u], dB1, false);
      }
      float nm = fmaxf(mx, fmaxf(fmaxf(dA0,dA1), fmaxf(dB0,dB1)));
      float r  = __expf(mx - nm);
      mx = nm;
      float eA0 = __expf(dA0 - nm), eA1 = __expf(dA1 - nm);
      float eB0 = __expf(dB0 - nm), eB1 = __expf(dB1 - nm);
      s0 = s0*r + eA0 + eB0;
      s1 = s1*r + eA1 + eB1;
      const uint* vrA = vb + lane*AT_RU;
      const uint* vrB = vb + (lane+64)*AT_RU;
      #pragma unroll
      for (int u=0;u<16;u++){
        uint wA = vrA[u], wB = vrB[u];
        float aA = h2f((u16)(wA&0xffffu)), bA = h2f((u16)(wA>>16));
        float aB = h2f((u16)(wB&0xffffu)), bB = h2f((u16)(wB>>16));
        o0[2*u  ] = o0[2*u  ]*r + eA0*aA + eB0*aB;
        o0[2*u+1] = o0[2*u+1]*r + eA0*bA + eB0*bB;
        o1[2*u  ] = o1[2*u  ]*r + eA1*aA + eB1*aB;
        o1[2*u+1] = o1[2*u+1]*r + eA1*bA + eB1*bB;
      }
    }
    __syncthreads();
    if (kt+1 < NT){
      uint* kd = kls[(kt+1)&1]; uint* vd = vls[(kt+1)&1];
      kd[ka_*AT_RU+pa_  ]=kr0.x; kd[ka_*AT_RU+pa_+1]=kr0.y; kd[ka_*AT_RU+pa_+2]=kr0.z; kd[ka_*AT_RU+pa_+3]=kr0.w;
      kd[kb_*AT_RU+pb_  ]=kr1.x; kd[kb_*AT_RU+pb_+1]=kr1.y; kd[kb_*AT_RU+pb_+2]=kr1.z; kd[kb_*AT_RU+pb_+3]=kr1.w;
      vd[ka_*AT_RU+pa_  ]=vr0.x; vd[ka_*AT_RU+pa_+1]=vr0.y; vd[ka_*AT_RU+pa_+2]=vr0.z; vd[ka_*AT_RU+pa_+3]=vr0.w;
      vd[kb_*AT_RU+pb_  ]=vr1.x; vd[kb_*AT_RU+pb_+1]=vr1.y; vd[kb_*AT_RU+pb_+2]=vr1.z; vd[kb_*AT_RU+pb_+3]=vr1.w;
      __syncthreads();
    }
  }

  #pragma unroll
  for (int off=1; off<64; off<<=1){
    float m2  = __shfl_xor(mx, off);
    float s02 = __shfl_xor(s0, off);
    float s12 = __shfl_xor(s1, off);
    float nm = fmaxf(mx, m2);
    float ra = __expf(mx - nm), rb = __expf(m2 - nm);
    s0 = s0*ra + s02*rb;
    s1 = s1*ra + s12*rb;
    #pragma unroll
    for (int d=0;d<32;d++){
      float a0 = __shfl_xor(o0[d], off);
      float a1 = __shfl_xor(o1[d], off);
      o0[d] = o0[d]*ra + a0*rb;
      o1[d] = o1[d]*ra + a1*rb;
    }
    mx = nm;
  }
  float inv0 = 1.f/s0, inv1 = 1.f/s1;
  if (lane == 0){
    #pragma unroll
    for (int d=0;d<32;d++){
      attno[(size_t)(q0  )*DM + h*32 + d] = o0[d]*inv0;
      attno[(size_t)(q0+1)*DM + h*32 + d] = o1[d]*inv1;
    }
  }
}

__global__ void k_wo(const float* __restrict__ attno, const float* __restrict__ W,
                     const float* __restrict__ B, float* __restrict__ node){
  int i = blockIdx.x*256 + threadIdx.x;          // NN*DM
  int n = i >> 7, c = i & 127;
  float acc = B[c];
  const float* ar = attno + (size_t)n*DM;
  for (int k=0;k<128;k+=4){
    acc += ar[k  ]*W[(k  )*128+c];
    acc += ar[k+1]*W[(k+1)*128+c];
    acc += ar[k+2]*W[(k+2)*128+c];
    acc += ar[k+3]*W[(k+3)*128+c];
  }
  node[i] = acc;
}

// ---------------- readout ----------------

__global__ __launch_bounds__(256) void k_readout(
    const float* __restrict__ node,
    const float* __restrict__ w1, const float* __restrict__ b1,
    const float* __restrict__ w2, const float* __restrict__ b2,
    const float* __restrict__ w3, const float* __restrict__ b3,
    float* __restrict__ out){
  __shared__ float gs[128], h1[128], h2[64];
  const int t = threadIdx.x;
  if (t < 128){
    float s = 0.f;
    for (int r=0;r<NN;r++) s += node[(size_t)r*DM + t];
    gs[t] = s*(1.f/2048.f);
  }
  __syncthreads();
  if (t < 128){
    float acc = b1[t];
    for (int k=0;k<128;k++) acc += gs[k]*w1[k*128+t];
    h1[t] = siluf(acc);
  }
  __syncthreads();
  if (t < 64){
    float acc = b2[t];
    for (int k=0;k<128;k++) acc += h1[k]*w2[k*64+t];
    h2[t] = siluf(acc);
  }
  __syncthreads();
  if (t == 0){
    float acc = b3[0];
    for (int k=0;k<64;k++) acc += h2[k]*w3[k];
    out[0] = acc;                                // f32 output
  }
}

// ---------------- host launch ----------------

extern "C" void kernel_launch(void* const* d_in, const int* in_sizes, int n_in,
                              void* d_out, int out_size, void* d_ws, size_t ws_size,
                              hipStream_t stream) {
  (void)in_sizes; (void)n_in; (void)out_size;
  const int*   an    = (const int*)  d_in[0];
  const float* pos   = (const float*)d_in[1];
  const int*   eidx  = (const int*)  d_in[2];
  const int*   lidx  = (const int*)  d_in[3];
  const float* lang  = (const float*)d_in[4];
  const float* atab  = (const float*)d_in[5];
  const float* rw1   = (const float*)d_in[6];
  const float* rb1   = (const float*)d_in[7];
  const float* rw2   = (const float*)d_in[8];
  const float* rb2   = (const float*)d_in[9];
  const float* lew   = (const float*)d_in[10];
  const float* leb   = (const float*)d_in[11];
  const float* euw1  = (const float*)d_in[12];
  const float* eub1  = (const float*)d_in[13];
  const float* euw2  = (const float*)d_in[14];
  const float* eub2  = (const float*)d_in[15];
  const float* luw1  = (const float*)d_in[16];
  const float* lub1  = (const float*)d_in[17];
  const float* luw2  = (const float*)d_in[18];
  const float* lub2  = (const float*)d_in[19];
  const float* nuw1  = (const float*)d_in[20];
  const float* nub1  = (const float*)d_in[21];
  const float* nuw2  = (const float*)d_in[22];
  const float* nub2  = (const float*)d_in[23];
  const float* wqkv  = (const float*)d_in[24];
  const float* bqkv  = (const float*)d_in[25];
  const float* wo    = (const float*)d_in[26];
  const float* bo    = (const float*)d_in[27];
  const float* nng   = (const float*)d_in[28];
  const float* nnb   = (const float*)d_in[29];
  const float* eng   = (const float*)d_in[30];
  const float* enb   = (const float*)d_in[31];
  const float* lng   = (const float*)d_in[32];
  const float* lnb   = (const float*)d_in[33];
  const float* row1  = (const float*)d_in[34];
  const float* rob1  = (const float*)d_in[35];
  const float* row2  = (const float*)d_in[36];
  const float* rob2  = (const float*)d_in[37];
  const float* row3  = (const float*)d_in[38];
  const float* rob3  = (const float*)d_in[39];

  // workspace layout (~247 MB; sentinel reveals ws_MB if short)
  char* p = (char*)d_ws;
  auto bump = [&](size_t bytes)->char*{ char* q = p; p += (bytes + 255) & ~(size_t)255; return q; };
  float* node  = (float*)bump((size_t)NN*DM*4);
  float* Q     = (float*)bump((size_t)NN*128*4);
  u16*   K4    = (u16*)  bump((size_t)4*NN*32*2);
  u16*   V4    = (u16*)  bump((size_t)4*NN*32*2);
  float* attno = (float*)bump((size_t)NN*DM*4);
  u16*   edge  = (u16*)  bump((size_t)NE*DM*2);     // perm2 (dst-sorted) order
  u16*   line  = (u16*)  bump((size_t)NL*DM*2);     // perm1 (ldst-sorted) order
  u16*   A16   = (u16*)  bump((size_t)NE*DM*2);
  u16*   Bm16  = (u16*)  bump((size_t)NE*DM*2);
  int*   base1 = (int*)  bump((size_t)(NE+1)*4);
  int*   base2 = (int*)  bump((size_t)(NN+1)*4);
  int*   cur1  = (int*)  bump((size_t)NE*4);
  int*   cur2  = (int*)  bump((size_t)NN*4);
  int*   perm1 = (int*)  bump((size_t)NL*4);
  int*   perm2 = (int*)  bump((size_t)NE*4);
  int*   einv  = (int*)  bump((size_t)NE*4);
  int*   lsrc2 = (int*)  bump((size_t)NL*4);
  int*   ldst2 = (int*)  bump((size_t)NL*4);
  int*   bsumA = (int*)  bump((size_t)64*4);
  int*   bsumB = (int*)  bump((size_t)4);
  u16*   lw1h  = (u16*)  bump((size_t)4*32768*2);
  u16*   lw2h  = (u16*)  bump((size_t)4*16384*2);
  u16*   ew1h  = (u16*)  bump((size_t)4*65536*2);   // FOLDED EU W1 (256x256)
  u16*   ew2h  = (u16*)  bump((size_t)4*32768*2);
  u16*   rw1p  = (u16*)  bump((size_t)8192*2);
  u16*   rw2p  = (u16*)  bump((size_t)16384*2);
  size_t needed = (size_t)(p - (char*)d_ws);
  if (needed > ws_size){
    k_sentinel<<<1, 1, 0, stream>>>((float*)d_out, (float)(ws_size >> 20));
    return;
  }

  const int* lsrc = lidx;
  const int* ldst = lidx + NL;
  const int* dst  = eidx + NE;

  // CSR builds (merged dispatches; index structure is layer-invariant)
  const int nblkA = NL/256, nblkB = NE/256;
  k_zero2<<<(NE+NN+255)/256, 256, 0, stream>>>(cur1, NE, cur2, NN);
  k_hist2<<<nblkA+nblkB, 256, 0, stream>>>(ldst, cur1, dst, cur2, nblkA);
  k_scanp1<<<65, 256, 0, stream>>>(cur1, base1, cur2, base2, bsumA, bsumB);
  k_scanp2<<<1, 64, 0, stream>>>(bsumA, base1, NE, bsumB, base2, NN);
  k_scanp3<<<64, 256, 0, stream>>>(base1, bsumA);
  k_zero2<<<(NE+NN+255)/256, 256, 0, stream>>>(cur1, NE, cur2, NN);
  k_perm2k<<<nblkA+nblkB, 256, 0, stream>>>(ldst, base1, cur1, perm1,
                                            dst,  base2, cur2, perm2, nblkA);
  k_einv<<<(NE+255)/256, 256, 0, stream>>>(perm2, einv, NE);
  k_lidx2<<<(NL+255)/256, 256, 0, stream>>>(lsrc, ldst, perm1, einv, lsrc2, ldst2, NL);

  // weight fragment conversion (72 blocks/layer; EU W1 folded)
  k_wfrag_all<<<4*72, 256, 0, stream>>>(luw1, luw2, euw1, euw2, lw1h, lw2h, ew1h, ew2h);
  k_rbf_wfrag<<<12, 256, 0, stream>>>(rw1, rw2, rw1p, rw2p);

  // embeddings (sorted storage orders)
  k_node_init<<<NN*DM/256, 256, 0, stream>>>(an, atab, node);
  k_line_init<<<NL*64/256, 256, 0, stream>>>(lang, lew, leb, perm1, line);
  k_edge_embed2<<<NE/32, 256, 0, stream>>>(pos, eidx, perm2, rw1p, rb1, rw2p, rb2, edge);

  for (int l=0; l<4; ++l){
    k_pre_lu<<<NE/32, 256, 0, stream>>>(edge, lw1h + (size_t)l*32768, A16, Bm16);
    k_lu2<<<NL/32, 256, 0, stream>>>(A16, Bm16, lsrc2, ldst2,
        lub1 + l*128, lw2h + (size_t)l*16384, lub2 + l*128,
        lng + l*128, lnb + l*128, line);
    k_eu_mfma<<<NE/32, 256, 0, stream>>>(
        ew1h + (size_t)l*65536, eub1 + l*256,
        ew2h + (size_t)l*32768, eub2 + l*128,
        eng + l*128, enb + l*128, edge, line, base1, perm2);
    k_nu<256><<<NN/16, 256, 0, stream>>>(
        nuw1 + (size_t)l*256*256, nub1 + l*256, nuw2 + (size_t)l*256*128, nub2 + l*128,
        nng + l*128, nnb + l*128, node, edge, base2);
    k_qkv_split<<<NN*384/256, 256, 0, stream>>>(node, wqkv + (size_t)l*128*384, bqkv + l*384,
        Q, K4, V4);
    k_attn3<<<1024, 256, 0, stream>>>(Q, K4, V4, attno);
    k_wo<<<NN*DM/256, 256, 0, stream>>>(attno, wo + (size_t)l*128*128, bo + l*128, node);
  }

  k_readout<<<1, 256, 0, stream>>>(node, row1, rob1, row2, rob2, row3, rob3, (float*)d_out);
}

// Round 22
// 1747.444 us; speedup vs baseline: 1.1151x; 1.0494x over previous
//
#include <hip/hip_runtime.h>
#include <hip/hip_fp16.h>

// ALIGNN forward on MI355X. Round 22: horizontal-fusion software pipeline.
// Profile is flat (lu2 116, eu 114, attn ~90, pre_lu ~65 ...), all mixed-bound.
// Merge independent kernels across layers into single dispatches:
//   k_qp = qkv(l) || pre_lu(l+1)   (VALU || MFMA)
//   k_la = attn(l) || lu2(l+1)     (VALU || latency/BW)  <- the big pair
//   k_we = eu(l+1) || wo(l)
// Hazards audited: all buffer pairs disjoint; cross-layer uses serialized by
// dispatch order. Round-21 baseline 1834us. Math identical to round 21.

#define NN 2048      // nodes
#define NE 131072    // edges
#define NL 524288    // line edges
#define DM 128       // feature dim

typedef unsigned short u16;
typedef unsigned int uint;
typedef __attribute__((ext_vector_type(8))) _Float16 f16x8;
typedef __attribute__((ext_vector_type(2))) _Float16 f16x2;
typedef __attribute__((ext_vector_type(4))) float f32x4;

__device__ __forceinline__ float h2f(u16 u){ return __half2float(__ushort_as_half(u)); }
__device__ __forceinline__ u16 f2h(float f){ return __half_as_ushort(__float2half(f)); } // RNE
__device__ __forceinline__ uint pk2h(float a, float b){   // packed f32x2 -> f16x2 (RTZ)
  union { decltype(__builtin_amdgcn_cvt_pkrtz(0.f,0.f)) h2; uint u; } cv;
  cv.h2 = __builtin_amdgcn_cvt_pkrtz(a, b);
  return cv.u;
}
__device__ __forceinline__ float siluf(float x){ return x/(1.f+__expf(-x)); }
__device__ __forceinline__ float4 ld4(const float* p){ return *(const float4*)p; }
__device__ __forceinline__ void fma44(float (&a)[4], float4 x, float4 w0, float4 w1, float4 w2, float4 w3){
  a[0] += x.x*w0.x + x.y*w1.x + x.z*w2.x + x.w*w3.x;
  a[1] += x.x*w0.y + x.y*w1.y + x.z*w2.y + x.w*w3.y;
  a[2] += x.x*w0.z + x.y*w1.z + x.z*w2.z + x.w*w3.z;
  a[3] += x.x*w0.w + x.y*w1.w + x.z*w2.w + x.w*w3.w;
}

// ---------------- util ----------------

__global__ void k_zero2(int* __restrict__ a, int na, int* __restrict__ b, int nb){
  int i = blockIdx.x*256 + threadIdx.x;
  if (i < na) a[i] = 0;
  else if (i - na < nb) b[i - na] = 0;
}

__global__ void k_sentinel(float* out, float wsmb){ out[0] = 1000000.0f + wsmb; }

__global__ void k_einv(const int* __restrict__ perm2, int* __restrict__ einv, int n){
  int i = blockIdx.x*256 + threadIdx.x;
  if (i < n) einv[perm2[i]] = i;
}

__global__ void k_lidx2(const int* __restrict__ lsrc, const int* __restrict__ ldst,
                        const int* __restrict__ perm1, const int* __restrict__ einv,
                        int* __restrict__ lsrc2, int* __restrict__ ldst2, int n){
  int i = blockIdx.x*256 + threadIdx.x;
  if (i < n){
    int o = perm1[i];
    lsrc2[i] = einv[lsrc[o]];
    ldst2[i] = einv[ldst[o]];
  }
}

// ---------------- parallel 3-pass exclusive scan ----------------

__global__ __launch_bounds__(256) void k_scanp1(
    const int* __restrict__ inA, int* __restrict__ outA,
    const int* __restrict__ inB, int* __restrict__ outB,
    int* __restrict__ bsumA, int* __restrict__ bsumB){
  __shared__ int wsum[4];
  const int b = blockIdx.x, t = threadIdx.x;
  const int* in;  int* out;  int* bsum;  int base;
  if (b < 64){ in = inA; out = outA; bsum = bsumA + b; base = b*2048; }
  else       { in = inB; out = outB; bsum = bsumB;     base = 0; }
  int v[8];
  int s = 0;
  #pragma unroll
  for (int j=0;j<8;j++){ v[j] = in[base + t*8 + j]; s += v[j]; }
  const int lane = t & 63, wid = t >> 6;
  int x = s;
  #pragma unroll
  for (int off=1; off<64; off<<=1){
    int u = __shfl_up(x, off);
    if (lane >= off) x += u;
  }
  if (lane == 63) wsum[wid] = x;
  __syncthreads();
  int woff = 0;
  #pragma unroll
  for (int i=0;i<3;i++) if (i < wid) woff += wsum[i];
  int run = woff + x - s;
  #pragma unroll
  for (int j=0;j<8;j++){ out[base + t*8 + j] = run; run += v[j]; }
  if (t == 255) *bsum = woff + x;
}

__global__ void k_scanp2(int* __restrict__ bsumA, int* __restrict__ outA, int nA,
                         const int* __restrict__ bsumB, int* __restrict__ outB, int nB){
  __shared__ int sh[64];
  const int t = threadIdx.x;
  if (t < 64) sh[t] = bsumA[t];
  __syncthreads();
  if (t == 0){
    int run = 0;
    for (int i=0;i<64;i++){ int v = sh[i]; sh[i] = run; run += v; }
    outA[nA] = run;
    outB[nB] = bsumB[0];
  }
  __syncthreads();
  if (t < 64) bsumA[t] = sh[t];
}

__global__ __launch_bounds__(256) void k_scanp3(int* __restrict__ outA, const int* __restrict__ bsumA){
  const int b = blockIdx.x;
  const int off = bsumA[b];
  const int base = b*2048 + threadIdx.x*8;
  #pragma unroll
  for (int j=0;j<8;j++) outA[base+j] += off;
}

// all per-layer weight-fragment conversions in ONE dispatch (j-pair cols).
// EU W1 FOLDED: row r<128 = W1[r]+W1[r+128]; row r>=128 = W1[r+128].
__global__ void k_wfrag_all(const float* __restrict__ luw1, const float* __restrict__ luw2,
                            const float* __restrict__ euw1, const float* __restrict__ euw2,
                            u16* __restrict__ lw1h, u16* __restrict__ lw2h,
                            u16* __restrict__ ew1h, u16* __restrict__ ew2h){
  int l = blockIdx.x / 72, r = blockIdx.x % 72;
  const float* W; u16* out; int N, total, lb; bool fold = false;
  if (r < 16){      W = luw1 + (size_t)l*256*128; out = lw1h + (size_t)l*32768; N=128; total=4096;  lb = r; }
  else if (r < 24){ W = luw2 + (size_t)l*128*128; out = lw2h + (size_t)l*16384; N=128; total=2048;  lb = r-16; }
  else if (r < 56){ W = euw1 + (size_t)l*384*256; out = ew1h + (size_t)l*65536; N=256; total=8192;  lb = r-24; fold = true; }
  else {            W = euw2 + (size_t)l*256*128; out = ew2h + (size_t)l*32768; N=128; total=4096;  lb = r-56; }
  int i = lb*256 + threadIdx.x;
  if (i >= total) return;
  int lane = i & 63;
  int frag = i >> 6;
  int NT = N >> 4;
  int ntg = frag % NT;
  int kt = frag / NT;
  int half = NT >> 1;
  int colh = ntg / half, j = ntg % half;
  int col  = colh*(half<<4) + ((j>>1)<<5) + 2*(lane&15) + (j&1);
  int row0 = kt*32 + (lane>>4)*8;
  uint4 v; uint* vp = (uint*)&v;
  #pragma unroll
  for (int p=0;p<4;p++){
    int ra = row0+2*p, rb = row0+2*p+1;
    float fa, fb;
    if (fold){
      fa = (ra < 128) ? W[(size_t)ra*N + col] + W[(size_t)(ra+128)*N + col]
                      : W[(size_t)(ra+128)*N + col];
      fb = (rb < 128) ? W[(size_t)rb*N + col] + W[(size_t)(rb+128)*N + col]
                      : W[(size_t)(rb+128)*N + col];
    } else {
      fa = W[(size_t)ra*N + col];
      fb = W[(size_t)rb*N + col];
    }
    vp[p] = (uint)f2h(fa) | ((uint)f2h(fb)<<16);
  }
  *(uint4*)(out + (size_t)i*8) = v;
}

// rbf weights -> fragments: w1 [50][128] zero-padded to K=64; w2 [128][128].
__global__ void k_rbf_wfrag(const float* __restrict__ rw1, const float* __restrict__ rw2,
                            u16* __restrict__ w1p, u16* __restrict__ w2p){
  int r = blockIdx.x;
  const float* W; u16* out; int K, total;
  if (r < 4){ W = rw1; out = w1p; K = 50;  total = 1024; }
  else      { W = rw2; out = w2p; K = 128; total = 2048; r -= 4; }
  int i = r*256 + threadIdx.x;
  if (i >= total) return;
  int lane = i & 63, frag = i >> 6;
  int ntg = frag % 8, kt = frag / 8;
  int colh = ntg / 4, j = ntg % 4;
  int col  = colh*64 + ((j>>1)<<5) + 2*(lane&15) + (j&1);
  int row0 = kt*32 + (lane>>4)*8;
  uint4 v; uint* vp = (uint*)&v;
  #pragma unroll
  for (int p=0;p<4;p++){
    int ra = row0+2*p, rb = row0+2*p+1;
    u16 a = (ra < K) ? f2h(W[(size_t)ra*128 + col]) : (u16)0;
    u16 b = (rb < K) ? f2h(W[(size_t)rb*128 + col]) : (u16)0;
    vp[p] = (uint)a | ((uint)b<<16);
  }
  *(uint4*)(out + (size_t)i*8) = v;
}

// ---------------- init ----------------

__global__ void k_node_init(const int* __restrict__ an, const float* __restrict__ tab, float* __restrict__ node){
  int i = blockIdx.x*256 + threadIdx.x;          // NN*DM threads
  int n = i >> 7, d = i & 127;
  node[i] = tab[(an[n]-1)*DM + d];
}

__global__ void k_line_init(const float* __restrict__ ang, const float* __restrict__ w,
                            const float* __restrict__ b, const int* __restrict__ perm1,
                            u16* __restrict__ line){
  int i = blockIdx.x*256 + threadIdx.x;          // NL*64 threads (2 cols each)
  int r = i >> 6; int c2 = (i & 63)*2;
  float a = ang[perm1[r]];
  ushort2 v;
  v.x = f2h(a*w[c2  ] + b[c2  ]);
  v.y = f2h(a*w[c2+1] + b[c2+1]);
  ((ushort2*)line)[i] = v;
}

// MFMA edge embedding: 32 edges/block; rbf f16 [32][64-pad]; two MFMA GEMMs.
#define EB_RS 72    // 64+8 halves
#define EB_HS 136   // 128+8 halves

__global__ __launch_bounds__(256) void k_edge_embed2(
    const float* __restrict__ pos, const int* __restrict__ eidx,
    const int* __restrict__ eperm,
    const u16* __restrict__ W1p, const float* __restrict__ B1,
    const u16* __restrict__ W2p, const float* __restrict__ B2,
    u16* __restrict__ edge){
  __shared__ __align__(16) u16 rs[32*EB_RS];
  __shared__ __align__(16) u16 hs[32*EB_HS];
  __shared__ float dsh[32];
  const int t = threadIdx.x;
  const int e0 = blockIdx.x*32;
  if (t < 32){
    int eo = eperm[e0 + t];
    int s = eidx[eo], d = eidx[NE + eo];
    float dx = pos[d*3+0]-pos[s*3+0];
    float dy = pos[d*3+1]-pos[s*3+1];
    float dz = pos[d*3+2]-pos[s*3+2];
    dsh[t] = sqrtf(dx*dx+dy*dy+dz*dz);
  }
  __syncthreads();
  for (int q = t; q < 32*64; q += 256){
    int m = q >> 6, k = q & 63;
    float d = dsh[m];
    float v = 0.f;
    if (k < 50){
      float c = 8.0f*(float)k/49.0f;
      float g = __expf(-(d-c)*(d-c)*19.53125f);
      float cut = (d < 8.0f) ? 0.5f*(__cosf(d*0.39269908169872414f)+1.0f) : 0.0f;
      v = g*cut;
    }
    rs[m*EB_RS + k] = f2h(v);
  }
  __syncthreads();

  const int lane = t & 63, w = t >> 6;
  const int band = w >> 1, colh = w & 1;
  const int arow = band*16 + (lane & 15);
  const int kgrp = (lane >> 4)*8;
  const int q2 = 2*(lane & 15);

  {
    f32x4 acc[4];
    #pragma unroll
    for (int nt=0; nt<4; ++nt){
      float bv = B1[colh*64 + (nt>>1)*32 + q2 + (nt&1)];
      acc[nt][0]=bv; acc[nt][1]=bv; acc[nt][2]=bv; acc[nt][3]=bv;
    }
    #pragma unroll
    for (int kt=0; kt<2; ++kt){
      f16x8 a = *(const f16x8*)(rs + arow*EB_RS + kt*32 + kgrp);
      #pragma unroll
      for (int nt=0; nt<4; ++nt){
        int ntg = colh*4 + nt;
        f16x8 b = *(const f16x8*)(W1p + ((size_t)(kt*8 + ntg)*64 + lane)*8);
        acc[nt] = __builtin_amdgcn_mfma_f32_16x16x32_f16(a, b, acc[nt], 0, 0, 0);
      }
    }
    #pragma unroll
    for (int p=0; p<2; ++p){
      int colb = colh*64 + p*32 + q2;
      #pragma unroll
      for (int r=0; r<4; ++r){
        int row = band*16 + (lane>>4)*4 + r;
        *(uint*)(hs + row*EB_HS + colb) = pk2h(siluf(acc[2*p][r]), siluf(acc[2*p+1][r]));
      }
    }
  }
  __syncthreads();
  {
    f32x4 acc[4];
    #pragma unroll
    for (int nt=0; nt<4; ++nt){
      float bv = B2[colh*64 + (nt>>1)*32 + q2 + (nt&1)];
      acc[nt][0]=bv; acc[nt][1]=bv; acc[nt][2]=bv; acc[nt][3]=bv;
    }
    #pragma unroll
    for (int kt=0; kt<4; ++kt){
      f16x8 a = *(const f16x8*)(hs + arow*EB_HS + kt*32 + kgrp);
      #pragma unroll
      for (int nt=0; nt<4; ++nt){
        int ntg = colh*4 + nt;
        f16x8 b = *(const f16x8*)(W2p + ((size_t)(kt*8 + ntg)*64 + lane)*8);
        acc[nt] = __builtin_amdgcn_mfma_f32_16x16x32_f16(a, b, acc[nt], 0, 0, 0);
      }
    }
    #pragma unroll
    for (int p=0; p<2; ++p){
      int colb = colh*64 + p*32 + q2;
      #pragma unroll
      for (int r=0; r<4; ++r){
        int row = band*16 + (lane>>4)*4 + r;
        *(uint*)(edge + (size_t)(e0+row)*DM + colb) = pk2h(acc[2*p][r], acc[2*p+1][r]);
      }
    }
  }
}

// ---------------- CSR build (merged dispatches) ----------------

__global__ void k_hist2(const int* __restrict__ idxA, int* __restrict__ histA,
                        const int* __restrict__ idxB, int* __restrict__ histB, int nblkA){
  int t = threadIdx.x;
  if ((int)blockIdx.x < nblkA){
    int i = blockIdx.x*256 + t;
    atomicAdd(&histA[idxA[i]], 1);
  } else {
    int i = (blockIdx.x - nblkA)*256 + t;
    atomicAdd(&histB[idxB[i]], 1);
  }
}

__global__ void k_perm2k(const int* __restrict__ idxA, const int* __restrict__ baseA,
                         int* __restrict__ curA, int* __restrict__ permA,
                         const int* __restrict__ idxB, const int* __restrict__ baseB,
                         int* __restrict__ curB, int* __restrict__ permB, int nblkA){
  int t = threadIdx.x;
  if ((int)blockIdx.x < nblkA){
    int i = blockIdx.x*256 + t;
    int e = idxA[i];
    int p = atomicAdd(&curA[e], 1);
    permA[baseA[e] + p] = i;
  } else {
    int i = (blockIdx.x - nblkA)*256 + t;
    int e = idxB[i];
    int p = atomicAdd(&curB[e], 1);
    permB[baseB[e] + p] = i;
  }
}

// ================ device bodies (shared by standalone + merged kernels) ================

// ---- pre_lu: A = edge@W1top, Bm = edge@W1bot ----
#define PE_XS 136
#define PE_SMEM (32*PE_XS*2)     // 8704 B

__device__ __forceinline__ void dev_pre_lu(int bid,
    const u16* __restrict__ edge, const u16* __restrict__ W1h,
    u16* __restrict__ A16, u16* __restrict__ Bm16, u16* xs){
  const int t = threadIdx.x;
  const int r0 = bid*32;
  #pragma unroll
  for (int it=0; it<2; ++it){
    int idx = it*256 + t;
    int m = idx >> 4, c = idx & 15;
    uint4 v = *(const uint4*)(edge + (size_t)(r0+m)*DM + c*8);
    *(uint4*)(xs + m*PE_XS + c*8) = v;
  }
  __syncthreads();
  const int lane = t & 63, w = t >> 6;
  const int band = w >> 1, colh = w & 1;
  const int arow = band*16 + (lane & 15);
  const int kgrp = (lane >> 4)*8;
  const int q2 = 2*(lane & 15);
  #pragma unroll
  for (int half=0; half<2; ++half){
    f32x4 acc[4];
    #pragma unroll
    for (int nt=0; nt<4; ++nt){ acc[nt][0]=0.f; acc[nt][1]=0.f; acc[nt][2]=0.f; acc[nt][3]=0.f; }
    #pragma unroll
    for (int kt=0; kt<4; ++kt){
      f16x8 a = *(const f16x8*)(xs + arow*PE_XS + kt*32 + kgrp);
      #pragma unroll
      for (int nt=0; nt<4; ++nt){
        int ntg = colh*4 + nt;
        f16x8 b = *(const f16x8*)(W1h + ((size_t)((kt + half*4)*8 + ntg)*64 + lane)*8);
        acc[nt] = __builtin_amdgcn_mfma_f32_16x16x32_f16(a, b, acc[nt], 0, 0, 0);
      }
    }
    u16* out = half ? Bm16 : A16;
    #pragma unroll
    for (int p=0; p<2; ++p){
      int colb = colh*64 + p*32 + q2;
      #pragma unroll
      for (int r=0; r<4; ++r){
        int row = band*16 + (lane>>4)*4 + r;
        *(uint*)(out + (size_t)(r0+row)*DM + colb) = pk2h(acc[2*p][r], acc[2*p+1][r]);
      }
    }
  }
}

// ---- lu2: h = silu(A[src]+Bm[dst]+b1); line = LN(line + h@W2+b2) ----
#define LU_HS 136   // halves (H overlay in smem)
#define LU_OS 132   // floats
#define LU_SMEM (32*LU_OS*4)     // 16896 B

__device__ __forceinline__ void dev_lu2(int bid,
    const u16* __restrict__ A16, const u16* __restrict__ Bm16,
    const int* __restrict__ lsrc2, const int* __restrict__ ldst2,
    const float* __restrict__ B1,
    const u16* __restrict__ W2h, const float* __restrict__ B2,
    const float* __restrict__ lg, const float* __restrict__ lb,
    u16* __restrict__ line, float* smem){
  u16* hs = (u16*)smem;
  const int t = threadIdx.x;
  const int r0 = bid*32;

  {                                              // gather-fuse: packed f16 adds
    int m = t >> 3, c8 = t & 7;
    int r = r0 + m;
    const u16* ap = A16  + (size_t)lsrc2[r]*DM;
    const u16* bp = Bm16 + (size_t)ldst2[r]*DM;
    #pragma unroll
    for (int cc0=0; cc0<2; ++cc0){
      int cc = c8 + cc0*8;
      uint4 av = *(const uint4*)(ap + cc*8);
      uint4 bv = *(const uint4*)(bp + cc*8);
      const __half2* ah = (const __half2*)&av;
      const __half2* bh = (const __half2*)&bv;
      uint outw[4];
      #pragma unroll
      for (int p=0;p<4;p++){
        int col = cc*8 + 2*p;
        __half2 b1v = __floats2half2_rn(B1[col], B1[col+1]);
        __half2 x2 = __hadd2(__hadd2(ah[p], bh[p]), b1v);
        float x0 = __half2float(__low2half(x2));
        float x1 = __half2float(__high2half(x2));
        outw[p] = pk2h(siluf(x0), siluf(x1));
      }
      *(uint4*)(hs + m*LU_HS + cc*8) = *(uint4*)outw;
    }
  }
  __syncthreads();

  const int lane = t & 63, w = t >> 6;
  const int band = w >> 1, colh = w & 1;
  const int arow = band*16 + (lane & 15);
  const int kgrp = (lane >> 4)*8;
  const int q2 = 2*(lane & 15);

  f32x4 acc[4];
  #pragma unroll
  for (int nt=0; nt<4; ++nt){
    float bv = B2[colh*64 + (nt>>1)*32 + q2 + (nt&1)];
    acc[nt][0]=bv; acc[nt][1]=bv; acc[nt][2]=bv; acc[nt][3]=bv;
  }
  #pragma unroll
  for (int kt=0; kt<4; ++kt){
    f16x8 a = *(const f16x8*)(hs + arow*LU_HS + kt*32 + kgrp);
    #pragma unroll
    for (int nt=0; nt<4; ++nt){
      int ntg = colh*4 + nt;
      f16x8 b = *(const f16x8*)(W2h + ((size_t)(kt*8 + ntg)*64 + lane)*8);
      acc[nt] = __builtin_amdgcn_mfma_f32_16x16x32_f16(a, b, acc[nt], 0, 0, 0);
    }
  }
  __syncthreads();
  #pragma unroll
  for (int p=0; p<2; ++p){
    int colb = colh*64 + p*32 + q2;
    #pragma unroll
    for (int r=0; r<4; ++r){
      int row = band*16 + (lane>>4)*4 + r;
      *(float2*)(smem + row*LU_OS + colb) = make_float2(acc[2*p][r], acc[2*p+1][r]);
    }
  }
  __syncthreads();
  {
    const float* outp = (const float*)smem;
    int row = t >> 3, li = t & 7;
    size_t rb = (size_t)(r0 + row)*DM;
    uint rw[8];
    *(uint4*)&rw[0] = *(const uint4*)(line + rb + li*16);
    *(uint4*)&rw[4] = *(const uint4*)(line + rb + li*16 + 8);
    float x[16];
    float s=0.f, q=0.f;
    #pragma unroll
    for (int j=0;j<16;j++){
      float res = h2f((u16)((j&1) ? (rw[j>>1]>>16) : (rw[j>>1]&0xffffu)));
      x[j] = outp[row*LU_OS + li*16 + j] + res;
      s += x[j]; q += x[j]*x[j];
    }
    #pragma unroll
    for (int off=1; off<8; off<<=1){ s += __shfl_xor(s,off); q += __shfl_xor(q,off); }
    float mean = s*(1.f/128.f);
    float rstd = rsqrtf(fmaxf(q*(1.f/128.f) - mean*mean, 0.f) + 1e-5f);
    #pragma unroll
    for (int half=0; half<2; ++half){
      uint4 wv; uint* wp = (uint*)&wv;
      #pragma unroll
      for (int p=0;p<4;p++){
        int j = half*8 + 2*p;
        int c0 = li*16 + j;
        wp[p] = pk2h((x[j  ]-mean)*rstd*lg[c0  ] + lb[c0  ],
                     (x[j+1]-mean)*rstd*lg[c0+1] + lb[c0+1]);
      }
      *(uint4*)(line + rb + li*16 + half*8) = wv;
    }
  }
}

// ---- eu: edge update (FOLDED W1: K=256) ----
#define EU_XS 264   // 256+8 halves
#define EU_HS 264   // 256+8 halves
#define EU_OS 132   // 128+4 floats
#define EU_SMEM (32*EU_XS*2 + 32*EU_HS*2)   // 33792 B

__device__ __forceinline__ void dev_eu(int bid,
    const u16* __restrict__ W1h, const float* __restrict__ B1,
    const u16* __restrict__ W2h, const float* __restrict__ B2,
    const float* __restrict__ g, const float* __restrict__ bb,
    u16* __restrict__ edge, const u16* __restrict__ line,
    const int* __restrict__ lbase, const int* __restrict__ eperm,
    u16* xs, u16* hs){
  const int t = threadIdx.x;
  const int r0 = bid*32;

  for (int it=0; it<2; ++it){
    int idx = it*256 + t;
    int m = idx >> 4, c = idx & 15;
    uint4 v = *(const uint4*)(edge + (size_t)(r0+m)*DM + c*8);
    *(uint4*)(xs + m*EU_XS + c*8) = v;
  }
  {
    int m = t >> 3, c0 = (t & 7)*16;
    int eo = eperm[r0 + m];
    int b0 = lbase[eo], b1 = lbase[eo+1];
    float s[16];
    #pragma unroll
    for (int k=0;k<16;k++) s[k]=0.f;
    for (int j=b0;j<b1;++j){
      const u16* lp = line + (size_t)j*DM + c0;
      uint rw[8];
      *(uint4*)&rw[0] = *(const uint4*)lp;
      *(uint4*)&rw[4] = *(const uint4*)(lp + 8);
      #pragma unroll
      for (int k=0;k<16;k++)
        s[k] += h2f((u16)((k&1) ? (rw[k>>1]>>16) : (rw[k>>1]&0xffffu)));
    }
    int n = b1 - b0;
    float inv = 1.f/(float)(n > 0 ? n : 1);
    #pragma unroll
    for (int half=0; half<2; ++half){
      uint4 wv; uint* wp = (uint*)&wv;
      #pragma unroll
      for (int p=0;p<4;p++){
        int k = half*8 + 2*p;
        wp[p] = pk2h(s[k]*inv, s[k+1]*inv);
      }
      *(uint4*)(xs + m*EU_XS + 128 + c0 + half*8) = wv;
    }
  }
  __syncthreads();

  const int lane = t & 63, w = t >> 6;
  const int band = w >> 1, colh = w & 1;
  const int arow = band*16 + (lane & 15);
  const int kgrp = (lane >> 4)*8;
  const int q2 = 2*(lane & 15);

  {
    f32x4 acc[8];
    #pragma unroll
    for (int nt=0; nt<8; ++nt){
      float bv = B1[colh*128 + (nt>>1)*32 + q2 + (nt&1)];
      acc[nt][0]=bv; acc[nt][1]=bv; acc[nt][2]=bv; acc[nt][3]=bv;
    }
    #pragma unroll
    for (int kt=0; kt<8; ++kt){
      f16x8 a = *(const f16x8*)(xs + arow*EU_XS + kt*32 + kgrp);
      #pragma unroll
      for (int nt=0; nt<8; ++nt){
        int ntg = colh*8 + nt;
        f16x8 b = *(const f16x8*)(W1h + ((size_t)(kt*16 + ntg)*64 + lane)*8);
        acc[nt] = __builtin_amdgcn_mfma_f32_16x16x32_f16(a, b, acc[nt], 0, 0, 0);
      }
    }
    #pragma unroll
    for (int p=0; p<4; ++p){
      int colb = colh*128 + p*32 + q2;
      #pragma unroll
      for (int r=0; r<4; ++r){
        int row = band*16 + (lane>>4)*4 + r;
        *(uint*)(hs + row*EU_HS + colb) = pk2h(siluf(acc[2*p][r]), siluf(acc[2*p+1][r]));
      }
    }
  }
  __syncthreads();
  {
    f32x4 acc[4];
    #pragma unroll
    for (int nt=0; nt<4; ++nt){
      float bv = B2[colh*64 + (nt>>1)*32 + q2 + (nt&1)];
      acc[nt][0]=bv; acc[nt][1]=bv; acc[nt][2]=bv; acc[nt][3]=bv;
    }
    #pragma unroll
    for (int kt=0; kt<8; ++kt){
      f16x8 a = *(const f16x8*)(hs + arow*EU_HS + kt*32 + kgrp);
      #pragma unroll
      for (int nt=0; nt<4; ++nt){
        int ntg = colh*4 + nt;
        f16x8 b = *(const f16x8*)(W2h + ((size_t)(kt*8 + ntg)*64 + lane)*8);
        acc[nt] = __builtin_amdgcn_mfma_f32_16x16x32_f16(a, b, acc[nt], 0, 0, 0);
      }
    }
    float* outp = (float*)xs;
    #pragma unroll
    for (int p=0; p<2; ++p){
      int colb = colh*64 + p*32 + q2;
      #pragma unroll
      for (int r=0; r<4; ++r){
        int row = band*16 + (lane>>4)*4 + r;
        *(float2*)(outp + row*EU_OS + colb) = make_float2(acc[2*p][r], acc[2*p+1][r]);
      }
    }
  }
  __syncthreads();
  {
    const float* outp = (const float*)xs;
    int row = t >> 3, li = t & 7;
    size_t rb = (size_t)(r0 + row)*DM;
    uint rw[8];
    *(uint4*)&rw[0] = *(const uint4*)(edge + rb + li*16);
    *(uint4*)&rw[4] = *(const uint4*)(edge + rb + li*16 + 8);
    float x[16];
    float s=0.f, q=0.f;
    #pragma unroll
    for (int j=0;j<16;j++){
      float res = h2f((u16)((j&1) ? (rw[j>>1]>>16) : (rw[j>>1]&0xffffu)));
      x[j] = outp[row*EU_OS + li*16 + j] + res;
      s += x[j]; q += x[j]*x[j];
    }
    #pragma unroll
    for (int off=1; off<8; off<<=1){ s += __shfl_xor(s,off); q += __shfl_xor(q,off); }
    float mean = s*(1.f/128.f);
    float rstd = rsqrtf(fmaxf(q*(1.f/128.f) - mean*mean, 0.f) + 1e-5f);
    #pragma unroll
    for (int half=0; half<2; ++half){
      uint4 wv; uint* wp = (uint*)&wv;
      #pragma unroll
      for (int p=0;p<4;p++){
        int j = half*8 + 2*p;
        int c0 = li*16 + j;
        wp[p] = pk2h((x[j  ]-mean)*rstd*g[c0  ] + bb[c0  ],
                     (x[j+1]-mean)*rstd*g[c0+1] + bb[c0+1]);
      }
      *(uint4*)(edge + rb + li*16 + half*8) = wv;
    }
  }
}

// ---- qkv projection ----
__device__ __forceinline__ void dev_qkv(int bid,
    const float* __restrict__ node, const float* __restrict__ W,
    const float* __restrict__ B, float* __restrict__ Q,
    u16* __restrict__ K4, u16* __restrict__ V4){
  int i = bid*256 + threadIdx.x;                 // NN*384 threads
  int n = i / 384, c = i % 384;
  float acc = B[c];
  const float* nr = node + (size_t)n*DM;
  for (int k=0;k<128;k+=4){
    acc += nr[k  ]*W[(k  )*384+c];
    acc += nr[k+1]*W[(k+1)*384+c];
    acc += nr[k+2]*W[(k+2)*384+c];
    acc += nr[k+3]*W[(k+3)*384+c];
  }
  if (c < 128){
    Q[(size_t)n*128 + c] = acc;
  } else if (c < 256){
    int h = (c-128) >> 5, d = (c-128) & 31;
    K4[((size_t)h*NN + n)*32 + d] = f2h(acc);
  } else {
    int h = (c-256) >> 5, d = (c-256) & 31;
    V4[((size_t)h*NN + n)*32 + d] = f2h(acc);
  }
}

// ---- attention (fdot2 + merged-half rescale) ----
#define AT_TK 128
#define AT_RU 17
#define AT_SMEM (4*AT_TK*AT_RU*4)   // 34816 B (kls[2]+vls[2])

__device__ __forceinline__ void dev_attn(int bid,
    const float* __restrict__ Q, const u16* __restrict__ K4,
    const u16* __restrict__ V4, float* __restrict__ attno,
    uint* kls, uint* vls){
  const int t = threadIdx.x, lane = t & 63;
  const int h = bid >> 8;
  const int q0 = (bid & 255)*8 + (t >> 6)*2;
  const float scale = 0.17677669529663687f;
  const uint* Kg = (const uint*)(K4 + (size_t)h*NN*32);
  const uint* Vg = (const uint*)(V4 + (size_t)h*NN*32);
  const int ca = t*2, cb = t*2+1;
  const int ka_ = ca>>2, pa_ = (ca&3)*4;
  const int kb_ = cb>>2, pb_ = (cb&3)*4;
  uint4 kr0, kr1, vr0, vr1;

  f16x2 qh[2][16];
  #pragma unroll
  for (int j=0;j<2;j++){
    const float* qr = Q + (size_t)(q0+j)*128 + h*32;
    #pragma unroll
    for (int u=0;u<16;u++){
      union { uint u32; f16x2 h2; } cv;
      cv.u32 = pk2h(qr[2*u]*scale, qr[2*u+1]*scale);
      qh[j][u] = cv.h2;
    }
  }
  float mx = -1e30f, s0 = 0.f, s1 = 0.f;
  float o0[32], o1[32];
  #pragma unroll
  for (int d=0;d<32;d++){ o0[d]=0.f; o1[d]=0.f; }

  {
    const uint* kg = Kg; const uint* vg = Vg;
    kr0 = *(const uint4*)(kg + ca*4); kr1 = *(const uint4*)(kg + cb*4);
    vr0 = *(const uint4*)(vg + ca*4); vr1 = *(const uint4*)(vg + cb*4);
    uint* kd = kls; uint* vd = vls;
    kd[ka_*AT_RU+pa_  ]=kr0.x; kd[ka_*AT_RU+pa_+1]=kr0.y; kd[ka_*AT_RU+pa_+2]=kr0.z; kd[ka_*AT_RU+pa_+3]=kr0.w;
    kd[kb_*AT_RU+pb_  ]=kr1.x; kd[kb_*AT_RU+pb_+1]=kr1.y; kd[kb_*AT_RU+pb_+2]=kr1.z; kd[kb_*AT_RU+pb_+3]=kr1.w;
    vd[ka_*AT_RU+pa_  ]=vr0.x; vd[ka_*AT_RU+pa_+1]=vr0.y; vd[ka_*AT_RU+pa_+2]=vr0.z; vd[ka_*AT_RU+pa_+3]=vr0.w;
    vd[kb_*AT_RU+pb_  ]=vr1.x; vd[kb_*AT_RU+pb_+1]=vr1.y; vd[kb_*AT_RU+pb_+2]=vr1.z; vd[kb_*AT_RU+pb_+3]=vr1.w;
  }
  __syncthreads();

  const int NT = NN / AT_TK;
  for (int kt=0; kt<NT; ++kt){
    if (kt+1 < NT){
      const uint* kg = Kg + (size_t)(kt+1)*AT_TK*16;
      const uint* vg = Vg + (size_t)(kt+1)*AT_TK*16;
      kr0 = *(const uint4*)(kg + ca*4); kr1 = *(const uint4*)(kg + cb*4);
      vr0 = *(const uint4*)(vg + ca*4); vr1 = *(const uint4*)(vg + cb*4);
    }
    {
      const uint* kb = kls + (kt&1)*AT_TK*AT_RU;
      const uint* vb = vls + (kt&1)*AT_TK*AT_RU;
      const uint* krA = kb + lane*AT_RU;
      const uint* krB = kb + (lane+64)*AT_RU;
      float dA0=0.f, dA1=0.f, dB0=0.f, dB1=0.f;
      #pragma unroll
      for (int u=0;u<16;u++){
        union { uint u32; f16x2 h2; } ka, kbv;
        ka.u32  = krA[u];
        kbv.u32 = krB[u];
        dA0 = __builtin_amdgcn_fdot2(ka.h2,  qh[0][u], dA0, false);
        dA1 = __builtin_amdgcn_fdot2(ka.h2,  qh[1][u], dA1, false);
        dB0 = __builtin_amdgcn_fdot2(kbv.h2, qh[0][u], dB0, false);
        dB1 = __builtin_amdgcn_fdot2(kbv.h2, qh[1][u], dB1, false);
      }
      float nm = fmaxf(mx, fmaxf(fmaxf(dA0,dA1), fmaxf(dB0,dB1)));
      float r  = __expf(mx - nm);
      mx = nm;
      float eA0 = __expf(dA0 - nm), eA1 = __expf(dA1 - nm);
      float eB0 = __expf(dB0 - nm), eB1 = __expf(dB1 - nm);
      s0 = s0*r + eA0 + eB0;
      s1 = s1*r + eA1 + eB1;
      const uint* vrA = vb + lane*AT_RU;
      const uint* vrB = vb + (lane+64)*AT_RU;
      #pragma unroll
      for (int u=0;u<16;u++){
        uint wA = vrA[u], wB = vrB[u];
        float aA = h2f((u16)(wA&0xffffu)), bA = h2f((u16)(wA>>16));
        float aB = h2f((u16)(wB&0xffffu)), bB = h2f((u16)(wB>>16));
        o0[2*u  ] = o0[2*u  ]*r + eA0*aA + eB0*aB;
        o0[2*u+1] = o0[2*u+1]*r + eA0*bA + eB0*bB;
        o1[2*u  ] = o1[2*u  ]*r + eA1*aA + eB1*aB;
        o1[2*u+1] = o1[2*u+1]*r + eA1*bA + eB1*bB;
      }
    }
    __syncthreads();
    if (kt+1 < NT){
      uint* kd = kls + ((kt+1)&1)*AT_TK*AT_RU;
      uint* vd = vls + ((kt+1)&1)*AT_TK*AT_RU;
      kd[ka_*AT_RU+pa_  ]=kr0.x; kd[ka_*AT_RU+pa_+1]=kr0.y; kd[ka_*AT_RU+pa_+2]=kr0.z; kd[ka_*AT_RU+pa_+3]=kr0.w;
      kd[kb_*AT_RU+pb_  ]=kr1.x; kd[kb_*AT_RU+pb_+1]=kr1.y; kd[kb_*AT_RU+pb_+2]=kr1.z; kd[kb_*AT_RU+pb_+3]=kr1.w;
      vd[ka_*AT_RU+pa_  ]=vr0.x; vd[ka_*AT_RU+pa_+1]=vr0.y; vd[ka_*AT_RU+pa_+2]=vr0.z; vd[ka_*AT_RU+pa_+3]=vr0.w;
      vd[kb_*AT_RU+pb_  ]=vr1.x; vd[kb_*AT_RU+pb_+1]=vr1.y; vd[kb_*AT_RU+pb_+2]=vr1.z; vd[kb_*AT_RU+pb_+3]=vr1.w;
      __syncthreads();
    }
  }

  #pragma unroll
  for (int off=1; off<64; off<<=1){
    float m2  = __shfl_xor(mx, off);
    float s02 = __shfl_xor(s0, off);
    float s12 = __shfl_xor(s1, off);
    float nm = fmaxf(mx, m2);
    float ra = __expf(mx - nm), rb = __expf(m2 - nm);
    s0 = s0*ra + s02*rb;
    s1 = s1*ra + s12*rb;
    #pragma unroll
    for (int d=0;d<32;d++){
      float a0 = __shfl_xor(o0[d], off);
      float a1 = __shfl_xor(o1[d], off);
      o0[d] = o0[d]*ra + a0*rb;
      o1[d] = o1[d]*ra + a1*rb;
    }
    mx = nm;
  }
  float inv0 = 1.f/s0, inv1 = 1.f/s1;
  if (lane == 0){
    #pragma unroll
    for (int d=0;d<32;d++){
      attno[(size_t)(q0  )*DM + h*32 + d] = o0[d]*inv0;
      attno[(size_t)(q0+1)*DM + h*32 + d] = o1[d]*inv1;
    }
  }
}

// ---- wo projection ----
__device__ __forceinline__ void dev_wo(int bid,
    const float* __restrict__ attno, const float* __restrict__ W,
    const float* __restrict__ B, float* __restrict__ node){
  int i = bid*256 + threadIdx.x;                 // NN*DM
  int n = i >> 7, c = i & 127;
  float acc = B[c];
  const float* ar = attno + (size_t)n*DM;
  for (int k=0;k<128;k+=4){
    acc += ar[k  ]*W[(k  )*128+c];
    acc += ar[k+1]*W[(k+1)*128+c];
    acc += ar[k+2]*W[(k+2)*128+c];
    acc += ar[k+3]*W[(k+3)*128+c];
  }
  node[i] = acc;
}

// ================ standalone kernels ================

__global__ __launch_bounds__(256) void k_pre_lu(
    const u16* __restrict__ edge, const u16* __restrict__ W1h,
    u16* __restrict__ A16, u16* __restrict__ Bm16){
  __shared__ __align__(16) u16 xs[32*PE_XS];
  dev_pre_lu(blockIdx.x, edge, W1h, A16, Bm16, xs);
}

__global__ __launch_bounds__(256) void k_lu2(
    const u16* __restrict__ A16, const u16* __restrict__ Bm16,
    const int* __restrict__ lsrc2, const int* __restrict__ ldst2,
    const float* __restrict__ B1,
    const u16* __restrict__ W2h, const float* __restrict__ B2,
    const float* __restrict__ lg, const float* __restrict__ lb,
    u16* __restrict__ line){
  __shared__ __align__(16) float smem[32*LU_OS];
  dev_lu2(blockIdx.x, A16, Bm16, lsrc2, ldst2, B1, W2h, B2, lg, lb, line, smem);
}

__global__ __launch_bounds__(256) void k_eu_mfma(
    const u16* __restrict__ W1h, const float* __restrict__ B1,
    const u16* __restrict__ W2h, const float* __restrict__ B2,
    const float* __restrict__ g, const float* __restrict__ bb,
    u16* __restrict__ edge, const u16* __restrict__ line,
    const int* __restrict__ lbase, const int* __restrict__ eperm){
  __shared__ __align__(16) u16 xs[32*EU_XS];
  __shared__ __align__(16) u16 hs[32*EU_HS];
  dev_eu(blockIdx.x, W1h, B1, W2h, B2, g, bb, edge, line, lbase, eperm, xs, hs);
}

__global__ void k_qkv_split(const float* __restrict__ node, const float* __restrict__ W,
                            const float* __restrict__ B, float* __restrict__ Q,
                            u16* __restrict__ K4, u16* __restrict__ V4){
  dev_qkv(blockIdx.x, node, W, B, Q, K4, V4);
}

__global__ __launch_bounds__(256) void k_attn3(
    const float* __restrict__ Q, const u16* __restrict__ K4,
    const u16* __restrict__ V4, float* __restrict__ attno){
  __shared__ __align__(16) uint kls[2*AT_TK*AT_RU];
  __shared__ __align__(16) uint vls[2*AT_TK*AT_RU];
  dev_attn(blockIdx.x, Q, K4, V4, attno, kls, vls);
}

__global__ void k_wo(const float* __restrict__ attno, const float* __restrict__ W,
                     const float* __restrict__ B, float* __restrict__ node){
  dev_wo(blockIdx.x, attno, W, B, node);
}

// ================ merged pipeline kernels ================

// qkv(l) || pre_lu(l+1): 4096 pre_lu blocks first, then 3072 qkv blocks
__global__ __launch_bounds__(256) void k_qp(
    const float* __restrict__ node, const float* __restrict__ Wq,
    const float* __restrict__ Bq, float* __restrict__ Q,
    u16* __restrict__ K4, u16* __restrict__ V4,
    const u16* __restrict__ edge, const u16* __restrict__ W1h,
    u16* __restrict__ A16, u16* __restrict__ Bm16){
  __shared__ __align__(16) u16 xs[32*PE_XS];
  int bid = blockIdx.x;
  if (bid < NE/32) dev_pre_lu(bid, edge, W1h, A16, Bm16, xs);
  else             dev_qkv(bid - NE/32, node, Wq, Bq, Q, K4, V4);
}

// attn(l) || lu2(l+1): 1024 attn blocks first (long), then 16384 lu2 blocks
__global__ __launch_bounds__(256) void k_la(
    const float* __restrict__ Q, const u16* __restrict__ K4,
    const u16* __restrict__ V4, float* __restrict__ attno,
    const u16* __restrict__ A16, const u16* __restrict__ Bm16,
    const int* __restrict__ lsrc2, const int* __restrict__ ldst2,
    const float* __restrict__ B1,
    const u16* __restrict__ W2h, const float* __restrict__ B2,
    const float* __restrict__ lg, const float* __restrict__ lb,
    u16* __restrict__ line){
  __shared__ __align__(16) char smem[AT_SMEM];   // 34816 >= LU_SMEM
  int bid = blockIdx.x;
  if (bid < 1024){
    uint* kls = (uint*)smem;
    uint* vls = kls + 2*AT_TK*AT_RU;
    dev_attn(bid, Q, K4, V4, attno, kls, vls);
  } else {
    dev_lu2(bid - 1024, A16, Bm16, lsrc2, ldst2, B1, W2h, B2, lg, lb, line, (float*)smem);
  }
}

// eu(l+1) || wo(l): 4096 eu blocks first, then 1024 wo blocks
__global__ __launch_bounds__(256) void k_we(
    const u16* __restrict__ W1h, const float* __restrict__ B1,
    const u16* __restrict__ W2h, const float* __restrict__ B2,
    const float* __restrict__ g, const float* __restrict__ bb,
    u16* __restrict__ edge, const u16* __restrict__ line,
    const int* __restrict__ lbase, const int* __restrict__ eperm,
    const float* __restrict__ attno, const float* __restrict__ Wo,
    const float* __restrict__ Bo, float* __restrict__ node){
  __shared__ __align__(16) char smem[EU_SMEM];   // 33792
  int bid = blockIdx.x;
  if (bid < NE/32){
    u16* xs = (u16*)smem;
    u16* hs = xs + 32*EU_XS;
    dev_eu(bid, W1h, B1, W2h, B2, g, bb, edge, line, lbase, eperm, xs, hs);
  } else {
    dev_wo(bid - NE/32, attno, Wo, Bo, node);
  }
}

// ---------------- NU: fused 16-row MLP+LN (contiguous naggr walk) ----------------

template<int KIN>
__global__ __launch_bounds__(256) void k_nu(
    const float* __restrict__ W1, const float* __restrict__ B1,
    const float* __restrict__ W2, const float* __restrict__ B2,
    const float* __restrict__ g, const float* __restrict__ bb,
    float* __restrict__ node_io, const u16* __restrict__ edge,
    const int* __restrict__ nbase){
  __shared__ __align__(16) float xsf[16*KIN];
  __shared__ __align__(16) float hsf[16*256];
  const int t = threadIdx.x;
  const int r0 = blockIdx.x*16;

  {
    int m = t >> 4, c0 = (t & 15)*8;
    int n = r0 + m;
    float4 a = ld4(node_io + (size_t)n*DM + c0);
    float4 b = ld4(node_io + (size_t)n*DM + c0 + 4);
    float* xd = &xsf[m*KIN + c0];
    xd[0]=a.x; xd[1]=a.y; xd[2]=a.z; xd[3]=a.w;
    xd[4]=b.x; xd[5]=b.y; xd[6]=b.z; xd[7]=b.w;
    int b0 = nbase[n], b1e = nbase[n+1];
    float s[8];
    #pragma unroll
    for (int k=0;k<8;k++) s[k]=0.f;
    for (int j=b0;j<b1e;++j){
      uint4 v = *(const uint4*)(edge + (size_t)j*DM + c0);
      s[0]+=h2f((u16)(v.x&0xffff)); s[1]+=h2f((u16)(v.x>>16));
      s[2]+=h2f((u16)(v.y&0xffff)); s[3]+=h2f((u16)(v.y>>16));
      s[4]+=h2f((u16)(v.z&0xffff)); s[5]+=h2f((u16)(v.z>>16));
      s[6]+=h2f((u16)(v.w&0xffff)); s[7]+=h2f((u16)(v.w>>16));
    }
    int nn = b1e - b0;
    float inv = 1.f/(float)(nn > 0 ? nn : 1);
    #pragma unroll
    for (int k=0;k<8;k++) xsf[m*KIN + 128 + c0 + k] = s[k]*inv;
  }
  __syncthreads();
  {
    const int c4 = (t & 63)*4, mg = t >> 6;
    float acc[4][4];
    float4 bv = ld4(B1 + c4);
    #pragma unroll
    for (int i=0;i<4;i++){ acc[i][0]=bv.x; acc[i][1]=bv.y; acc[i][2]=bv.z; acc[i][3]=bv.w; }
    for (int k=0;k<KIN;k+=4){
      float4 w0 = ld4(W1 + (k  )*256 + c4);
      float4 w1 = ld4(W1 + (k+1)*256 + c4);
      float4 w2 = ld4(W1 + (k+2)*256 + c4);
      float4 w3 = ld4(W1 + (k+3)*256 + c4);
      #pragma unroll
      for (int i=0;i<4;i++){
        float4 x = *(const float4*)&xsf[(mg*4+i)*KIN + k];
        fma44(acc[i], x, w0, w1, w2, w3);
      }
    }
    #pragma unroll
    for (int i=0;i<4;i++)
      #pragma unroll
      for (int j=0;j<4;j++)
        hsf[(mg*4+i)*256 + c4 + j] = siluf(acc[i][j]);
  }
  __syncthreads();
  const int c4b = (t & 31)*4, mgb = t >> 5;
  float acc2[2][4];
  {
    float4 bv = ld4(B2 + c4b);
    #pragma unroll
    for (int i=0;i<2;i++){ acc2[i][0]=bv.x; acc2[i][1]=bv.y; acc2[i][2]=bv.z; acc2[i][3]=bv.w; }
    for (int k=0;k<256;k+=4){
      float4 w0 = ld4(W2 + (k  )*128 + c4b);
      float4 w1 = ld4(W2 + (k+1)*128 + c4b);
      float4 w2 = ld4(W2 + (k+2)*128 + c4b);
      float4 w3 = ld4(W2 + (k+3)*128 + c4b);
      #pragma unroll
      for (int i=0;i<2;i++){
        float4 x = *(const float4*)&hsf[(mgb*2+i)*256 + k];
        fma44(acc2[i], x, w0, w1, w2, w3);
      }
    }
  }
  __syncthreads();
  #pragma unroll
  for (int i=0;i<2;i++){
    int m = mgb*2 + i;
    #pragma unroll
    for (int j=0;j<4;j++)
      hsf[m*128 + c4b + j] = acc2[i][j] + xsf[m*KIN + c4b + j];
  }
  __syncthreads();
  {
    int row = t >> 4, li = t & 15;
    const float* o = &hsf[row*128];
    float s=0.f, q=0.f;
    #pragma unroll
    for (int j=0;j<8;j++){ float x = o[li*8+j]; s += x; q += x*x; }
    #pragma unroll
    for (int off=1; off<16; off<<=1){ s += __shfl_xor(s,off); q += __shfl_xor(q,off); }
    float mean = s*(1.f/128.f);
    float rstd = rsqrtf(fmaxf(q*(1.f/128.f) - mean*mean, 0.f) + 1e-5f);
    size_t rb = (size_t)(r0 + row)*DM;
    #pragma unroll
    for (int j=0;j<8;j++){
      int c = li*8 + j;
      node_io[rb + c] = (o[c]-mean)*rstd*g[c] + bb[c];
    }
  }
}

// ---------------- readout ----------------

__global__ __launch_bounds__(256) void k_readout(
    const float* __restrict__ node,
    const float* __restrict__ w1, const float* __restrict__ b1,
    const float* __restrict__ w2, const float* __restrict__ b2,
    const float* __restrict__ w3, const float* __restrict__ b3,
    float* __restrict__ out){
  __shared__ float gs[128], h1[128], h2[64];
  const int t = threadIdx.x;
  if (t < 128){
    float s = 0.f;
    for (int r=0;r<NN;r++) s += node[(size_t)r*DM + t];
    gs[t] = s*(1.f/2048.f);
  }
  __syncthreads();
  if (t < 128){
    float acc = b1[t];
    for (int k=0;k<128;k++) acc += gs[k]*w1[k*128+t];
    h1[t] = siluf(acc);
  }
  __syncthreads();
  if (t < 64){
    float acc = b2[t];
    for (int k=0;k<128;k++) acc += h1[k]*w2[k*64+t];
    h2[t] = siluf(acc);
  }
  __syncthreads();
  if (t == 0){
    float acc = b3[0];
    for (int k=0;k<64;k++) acc += h2[k]*w3[k];
    out[0] = acc;                                // f32 output
  }
}

// ---------------- host launch ----------------

extern "C" void kernel_launch(void* const* d_in, const int* in_sizes, int n_in,
                              void* d_out, int out_size, void* d_ws, size_t ws_size,
                              hipStream_t stream) {
  (void)in_sizes; (void)n_in; (void)out_size;
  const int*   an    = (const int*)  d_in[0];
  const float* pos   = (const float*)d_in[1];
  const int*   eidx  = (const int*)  d_in[2];
  const int*   lidx  = (const int*)  d_in[3];
  const float* lang  = (const float*)d_in[4];
  const float* atab  = (const float*)d_in[5];
  const float* rw1   = (const float*)d_in[6];
  const float* rb1   = (const float*)d_in[7];
  const float* rw2   = (const float*)d_in[8];
  const float* rb2   = (const float*)d_in[9];
  const float* lew   = (const float*)d_in[10];
  const float* leb   = (const float*)d_in[11];
  const float* euw1  = (const float*)d_in[12];
  const float* eub1  = (const float*)d_in[13];
  const float* euw2  = (const float*)d_in[14];
  const float* eub2  = (const float*)d_in[15];
  const float* luw1  = (const float*)d_in[16];
  const float* lub1  = (const float*)d_in[17];
  const float* luw2  = (const float*)d_in[18];
  const float* lub2  = (const float*)d_in[19];
  const float* nuw1  = (const float*)d_in[20];
  const float* nub1  = (const float*)d_in[21];
  const float* nuw2  = (const float*)d_in[22];
  const float* nub2  = (const float*)d_in[23];
  const float* wqkv  = (const float*)d_in[24];
  const float* bqkv  = (const float*)d_in[25];
  const float* wo    = (const float*)d_in[26];
  const float* bo    = (const float*)d_in[27];
  const float* nng   = (const float*)d_in[28];
  const float* nnb   = (const float*)d_in[29];
  const float* eng   = (const float*)d_in[30];
  const float* enb   = (const float*)d_in[31];
  const float* lng   = (const float*)d_in[32];
  const float* lnb   = (const float*)d_in[33];
  const float* row1  = (const float*)d_in[34];
  const float* rob1  = (const float*)d_in[35];
  const float* row2  = (const float*)d_in[36];
  const float* rob2  = (const float*)d_in[37];
  const float* row3  = (const float*)d_in[38];
  const float* rob3  = (const float*)d_in[39];

  // workspace layout (~247 MB; sentinel reveals ws_MB if short)
  char* p = (char*)d_ws;
  auto bump = [&](size_t bytes)->char*{ char* q = p; p += (bytes + 255) & ~(size_t)255; return q; };
  float* node  = (float*)bump((size_t)NN*DM*4);
  float* Q     = (float*)bump((size_t)NN*128*4);
  u16*   K4    = (u16*)  bump((size_t)4*NN*32*2);
  u16*   V4    = (u16*)  bump((size_t)4*NN*32*2);
  float* attno = (float*)bump((size_t)NN*DM*4);
  u16*   edge  = (u16*)  bump((size_t)NE*DM*2);     // perm2 (dst-sorted) order
  u16*   line  = (u16*)  bump((size_t)NL*DM*2);     // perm1 (ldst-sorted) order
  u16*   A16   = (u16*)  bump((size_t)NE*DM*2);
  u16*   Bm16  = (u16*)  bump((size_t)NE*DM*2);
  int*   base1 = (int*)  bump((size_t)(NE+1)*4);
  int*   base2 = (int*)  bump((size_t)(NN+1)*4);
  int*   cur1  = (int*)  bump((size_t)NE*4);
  int*   cur2  = (int*)  bump((size_t)NN*4);
  int*   perm1 = (int*)  bump((size_t)NL*4);
  int*   perm2 = (int*)  bump((size_t)NE*4);
  int*   einv  = (int*)  bump((size_t)NE*4);
  int*   lsrc2 = (int*)  bump((size_t)NL*4);
  int*   ldst2 = (int*)  bump((size_t)NL*4);
  int*   bsumA = (int*)  bump((size_t)64*4);
  int*   bsumB = (int*)  bump((size_t)4);
  u16*   lw1h  = (u16*)  bump((size_t)4*32768*2);
  u16*   lw2h  = (u16*)  bump((size_t)4*16384*2);
  u16*   ew1h  = (u16*)  bump((size_t)4*65536*2);   // FOLDED EU W1 (256x256)
  u16*   ew2h  = (u16*)  bump((size_t)4*32768*2);
  u16*   rw1p  = (u16*)  bump((size_t)8192*2);
  u16*   rw2p  = (u16*)  bump((size_t)16384*2);
  size_t needed = (size_t)(p - (char*)d_ws);
  if (needed > ws_size){
    k_sentinel<<<1, 1, 0, stream>>>((float*)d_out, (float)(ws_size >> 20));
    return;
  }

  const int* lsrc = lidx;
  const int* ldst = lidx + NL;
  const int* dst  = eidx + NE;

  // CSR builds (merged dispatches; index structure is layer-invariant)
  const int nblkA = NL/256, nblkB = NE/256;
  k_zero2<<<(NE+NN+255)/256, 256, 0, stream>>>(cur1, NE, cur2, NN);
  k_hist2<<<nblkA+nblkB, 256, 0, stream>>>(ldst, cur1, dst, cur2, nblkA);
  k_scanp1<<<65, 256, 0, stream>>>(cur1, base1, cur2, base2, bsumA, bsumB);
  k_scanp2<<<1, 64, 0, stream>>>(bsumA, base1, NE, bsumB, base2, NN);
  k_scanp3<<<64, 256, 0, stream>>>(base1, bsumA);
  k_zero2<<<(NE+NN+255)/256, 256, 0, stream>>>(cur1, NE, cur2, NN);
  k_perm2k<<<nblkA+nblkB, 256, 0, stream>>>(ldst, base1, cur1, perm1,
                                            dst,  base2, cur2, perm2, nblkA);
  k_einv<<<(NE+255)/256, 256, 0, stream>>>(perm2, einv, NE);
  k_lidx2<<<(NL+255)/256, 256, 0, stream>>>(lsrc, ldst, perm1, einv, lsrc2, ldst2, NL);

  // weight fragment conversion (72 blocks/layer; EU W1 folded)
  k_wfrag_all<<<4*72, 256, 0, stream>>>(luw1, luw2, euw1, euw2, lw1h, lw2h, ew1h, ew2h);
  k_rbf_wfrag<<<12, 256, 0, stream>>>(rw1, rw2, rw1p, rw2p);

  // embeddings (sorted storage orders)
  k_node_init<<<NN*DM/256, 256, 0, stream>>>(an, atab, node);
  k_line_init<<<NL*64/256, 256, 0, stream>>>(lang, lew, leb, perm1, line);
  k_edge_embed2<<<NE/32, 256, 0, stream>>>(pos, eidx, perm2, rw1p, rb1, rw2p, rb2, edge);

  // pipeline prologue: P(0), L(0), E(0)
  k_pre_lu<<<NE/32, 256, 0, stream>>>(edge, lw1h, A16, Bm16);
  k_lu2<<<NL/32, 256, 0, stream>>>(A16, Bm16, lsrc2, ldst2,
      lub1, lw2h, lub2, lng, lnb, line);
  k_eu_mfma<<<NE/32, 256, 0, stream>>>(ew1h, eub1, ew2h, eub2,
      eng, enb, edge, line, base1, perm2);

  // steady-state: per layer l -> N(l), [Q(l)||P(l+1)], [A(l)||L(l+1)], [W(l)||E(l+1)]
  for (int l=0; l<4; ++l){
    k_nu<256><<<NN/16, 256, 0, stream>>>(
        nuw1 + (size_t)l*256*256, nub1 + l*256, nuw2 + (size_t)l*256*128, nub2 + l*128,
        nng + l*128, nnb + l*128, node, edge, base2);
    if (l < 3){
      int lp = l + 1;
      k_qp<<<NE/32 + NN*384/256, 256, 0, stream>>>(
          node, wqkv + (size_t)l*128*384, bqkv + l*384, Q, K4, V4,
          edge, lw1h + (size_t)lp*32768, A16, Bm16);
      k_la<<<1024 + NL/32, 256, 0, stream>>>(
          Q, K4, V4, attno,
          A16, Bm16, lsrc2, ldst2,
          lub1 + lp*128, lw2h + (size_t)lp*16384, lub2 + lp*128,
          lng + lp*128, lnb + lp*128, line);
      k_we<<<NE/32 + NN*DM/256, 256, 0, stream>>>(
          ew1h + (size_t)lp*65536, eub1 + lp*256,
          ew2h + (size_t)lp*32768, eub2 + lp*128,
          eng + lp*128, enb + lp*128, edge, line, base1, perm2,
          attno, wo + (size_t)l*128*128, bo + l*128, node);
    } else {
      k_qkv_split<<<NN*384/256, 256, 0, stream>>>(node, wqkv + (size_t)l*128*384,
          bqkv + l*384, Q, K4, V4);
      k_attn3<<<1024, 256, 0, stream>>>(Q, K4, V4, attno);
      k_wo<<<NN*DM/256, 256, 0, stream>>>(attno, wo + (size_t)l*128*128, bo + l*128, node);
    }
  }

  k_readout<<<1, 256, 0, stream>>>(node, row1, rob1, row2, rob2, row3, rob3, (float*)d_out);
}